// Round 1
// baseline (865.320 us; speedup 1.0000x reference)
//
#include <hip/hip_runtime.h>

#define N_NODES 100000
#define N_EDGES 800000
#define F_IN    75
#define HID     100
#define BN_EPS  1e-5f

// ---------------- graph preprocessing ----------------

__global__ void k_count(const int* __restrict__ ei, int* __restrict__ counts) {
    int e = blockIdx.x * 256 + threadIdx.x;
    if (e < N_EDGES) atomicAdd(&counts[ei[N_EDGES + e]], 1);
}

// per-block (2048 elems) exclusive scan + block sums
__global__ void k_scan1(const int* __restrict__ counts, int* __restrict__ part,
                        int* __restrict__ bsums) {
    __shared__ int sh[4];
    int tid = threadIdx.x;
    int base = blockIdx.x * 2048 + tid * 8;
    int v[8]; int run = 0;
#pragma unroll
    for (int j = 0; j < 8; j++) {
        int idx = base + j;
        int c = (idx < N_NODES) ? counts[idx] : 0;
        v[j] = run; run += c;
    }
    int lane = tid & 63, wid = tid >> 6;
    int x = run;
#pragma unroll
    for (int off = 1; off < 64; off <<= 1) {
        int y = __shfl_up(x, off);
        if (lane >= off) x += y;
    }
    if (lane == 63) sh[wid] = x;
    __syncthreads();
    int woff = 0;
    for (int w = 0; w < wid; w++) woff += sh[w];
    int excl = woff + x - run;
#pragma unroll
    for (int j = 0; j < 8; j++) {
        int idx = base + j;
        if (idx < N_NODES) part[idx] = excl + v[j];
    }
    if (tid == 255) bsums[blockIdx.x] = woff + x;
}

__global__ void k_scan2(int* bsums, int nb) {
    int tid = threadIdx.x;
    int x = (tid < nb) ? bsums[tid] : 0;
    int orig = x;
    for (int off = 1; off < 64; off <<= 1) {
        int y = __shfl_up(x, off);
        if (tid >= off) x += y;
    }
    if (tid < nb) bsums[tid] = x - orig;
}

__global__ void k_scan3(const int* __restrict__ part, const int* __restrict__ bsums,
                        const int* __restrict__ counts,
                        int* __restrict__ rowp, int* __restrict__ cursor,
                        float* __restrict__ dinv) {
    int i = blockIdx.x * 256 + threadIdx.x;
    if (i < N_NODES) {
        int rp = part[i] + bsums[i >> 11];
        rowp[i] = rp;
        cursor[i] = rp;
        dinv[i] = rsqrtf((float)(counts[i] + 1));  // self-loop => deg >= 1
    }
    if (i == 0) rowp[N_NODES] = N_EDGES;
}

__global__ void k_fill(const int* __restrict__ ei, int* __restrict__ cursor,
                       int* __restrict__ csr) {
    int e = blockIdx.x * 256 + threadIdx.x;
    if (e < N_EDGES) {
        int pos = atomicAdd(&cursor[ei[N_EDGES + e]], 1);
        csr[pos] = ei[e];
    }
}

// ---------------- GEMM: out[N,100] = A[N,K] @ W[K,100] (+ epilogue) ----------------
// MODE 0: out = (A@W) * dinv[row]            (pre-scaled GCN hidden)
// MODE 1: out = relu(BN(A@W + bias))         (dense head layers)
// block (64,4): thread = 8 rows x 2 cols. A addresses wave-uniform -> scalar loads.

template <int K, int MODE>
__global__ __launch_bounds__(256) void k_gemm(
    const float* __restrict__ A, const float* __restrict__ W,
    const float* __restrict__ dinv,
    const float* __restrict__ bias, const float* __restrict__ gam,
    const float* __restrict__ bet, const float* __restrict__ mu,
    const float* __restrict__ var,
    float* __restrict__ out) {
    int tx = threadIdx.x;                       // 0..63 -> column pair
    int ty = threadIdx.y;                       // 0..3  -> row group
    int rb = __builtin_amdgcn_readfirstlane(blockIdx.x * 32 + ty * 8);
    bool active = (tx < 50);                    // 50 lanes cover 100 cols
    int c0 = active ? 2 * tx : 98;              // clamp keeps W reads in-bounds

    float2 acc[8];
#pragma unroll
    for (int r = 0; r < 8; r++) acc[r] = make_float2(0.f, 0.f);

#pragma unroll 4
    for (int k = 0; k < K; k++) {
        float2 w = *(const float2*)&W[k * HID + c0];
#pragma unroll
        for (int r = 0; r < 8; r++) {
            float a = A[(rb + r) * K + k];      // wave-uniform -> s_load
            acc[r].x += a * w.x;
            acc[r].y += a * w.y;
        }
    }

    if (!active) return;

    if (MODE == 0) {
#pragma unroll
        for (int r = 0; r < 8; r++) {
            float dv = dinv[rb + r];
            *(float2*)&out[(rb + r) * HID + c0] =
                make_float2(acc[r].x * dv, acc[r].y * dv);
        }
    } else {
        float s0 = gam[c0] * rsqrtf(var[c0] + BN_EPS);
        float s1 = gam[c0 + 1] * rsqrtf(var[c0 + 1] + BN_EPS);
        float t0 = bet[c0] - mu[c0] * s0;
        float t1 = bet[c0 + 1] - mu[c0 + 1] * s1;
        float b0 = bias[c0], b1 = bias[c0 + 1];
#pragma unroll
        for (int r = 0; r < 8; r++) {
            float z0 = (acc[r].x + b0) * s0 + t0;
            float z1 = (acc[r].y + b1) * s1 + t1;
            *(float2*)&out[(rb + r) * HID + c0] =
                make_float2(fmaxf(z0, 0.f), fmaxf(z1, 0.f));
        }
    }
}

// ---------------- aggregation + bias + relu + BN ----------------
// out[n,c] = BN(relu(dinv[n] * (hs[n,c] + sum_{src in-edges} hs[src,c]) + bias[c]))

__global__ __launch_bounds__(128) void k_agg(
    const float* __restrict__ hs, const int* __restrict__ rowp,
    const int* __restrict__ csr, const float* __restrict__ dinv,
    const float* __restrict__ bias, const float* __restrict__ gam,
    const float* __restrict__ bet, const float* __restrict__ mu,
    const float* __restrict__ var, float* __restrict__ out) {
    int n = blockIdx.x;
    int c = threadIdx.x;
    if (c >= HID) return;
    int beg = rowp[n], end = rowp[n + 1];
    float acc = hs[n * HID + c];                // self-loop term
    for (int e = beg; e < end; ++e) {
        int s = csr[e];
        acc += hs[s * HID + c];
    }
    float z = acc * dinv[n] + bias[c];
    z = fmaxf(z, 0.f);
    float sc = gam[c] * rsqrtf(var[c] + BN_EPS);
    out[n * HID + c] = z * sc + (bet[c] - mu[c] * sc);
}

// ---------------- final 100 -> 3 layer: out = relu(h @ fW3 + fb3) ----------------

__global__ __launch_bounds__(256) void k_head3(
    const float* __restrict__ h, const float* __restrict__ W,
    const float* __restrict__ b, float* __restrict__ out) {
    int lane = threadIdx.x & 63;
    int row = blockIdx.x * 4 + (threadIdx.x >> 6);
    if (row >= N_NODES) return;
    float a0 = h[row * HID + lane];
    float a1 = (lane < 36) ? h[row * HID + 64 + lane] : 0.f;
    float r0, r1, r2;
    {
        float p0 = a0 * W[lane * 3 + 0];
        float p1 = a0 * W[lane * 3 + 1];
        float p2 = a0 * W[lane * 3 + 2];
        if (lane < 36) {
            p0 += a1 * W[(64 + lane) * 3 + 0];
            p1 += a1 * W[(64 + lane) * 3 + 1];
            p2 += a1 * W[(64 + lane) * 3 + 2];
        }
#pragma unroll
        for (int off = 32; off; off >>= 1) {
            p0 += __shfl_xor(p0, off);
            p1 += __shfl_xor(p1, off);
            p2 += __shfl_xor(p2, off);
        }
        r0 = p0; r1 = p1; r2 = p2;
    }
    if (lane == 0) {
        out[row * 3 + 0] = fmaxf(r0 + b[0], 0.f);
        out[row * 3 + 1] = fmaxf(r1 + b[1], 0.f);
        out[row * 3 + 2] = fmaxf(r2 + b[2], 0.f);
    }
}

// ---------------- launcher ----------------

extern "C" void kernel_launch(void* const* d_in, const int* in_sizes, int n_in,
                              void* d_out, int out_size, void* d_ws, size_t ws_size,
                              hipStream_t stream) {
    const float* x  = (const float*)d_in[0];
    const int*   ei = (const int*)d_in[1];
    const float* W1 = (const float*)d_in[2];  const float* b1 = (const float*)d_in[3];
    const float* g1 = (const float*)d_in[4];  const float* be1 = (const float*)d_in[5];
    const float* m1 = (const float*)d_in[6];  const float* v1 = (const float*)d_in[7];
    const float* W2 = (const float*)d_in[8];  const float* b2 = (const float*)d_in[9];
    const float* g2 = (const float*)d_in[10]; const float* be2 = (const float*)d_in[11];
    const float* m2 = (const float*)d_in[12]; const float* v2 = (const float*)d_in[13];
    const float* W3 = (const float*)d_in[14]; const float* b3 = (const float*)d_in[15];
    const float* g3 = (const float*)d_in[16]; const float* be3 = (const float*)d_in[17];
    const float* m3 = (const float*)d_in[18]; const float* v3 = (const float*)d_in[19];
    const float* fW1 = (const float*)d_in[20]; const float* fb1 = (const float*)d_in[21];
    const float* fg1 = (const float*)d_in[22]; const float* fbe1 = (const float*)d_in[23];
    const float* fm1 = (const float*)d_in[24]; const float* fv1 = (const float*)d_in[25];
    const float* fW2 = (const float*)d_in[26]; const float* fb2 = (const float*)d_in[27];
    const float* fg2 = (const float*)d_in[28]; const float* fbe2 = (const float*)d_in[29];
    const float* fm2 = (const float*)d_in[30]; const float* fv2 = (const float*)d_in[31];
    const float* fW3 = (const float*)d_in[32]; const float* fb3 = (const float*)d_in[33];
    float* out = (float*)d_out;

    char* w = (char*)d_ws;
    float* bufA  = (float*)(w);                    // N*100 f32 = 40,000,000 B
    float* bufB  = (float*)(w + 40000000);         // 40,000,000 B
    int*   cnts  = (int*)  (w + 80000000);         // 400,000 B
    int*   part  = (int*)  (w + 80400000);         // 400,000 B
    int*   rowp  = (int*)  (w + 80800000);         // 400,004 B (pad to 400,256)
    int*   curs  = (int*)  (w + 81200256);         // 400,000 B
    int*   bsums = (int*)  (w + 81600256);         // 256 B
    float* dinv  = (float*)(w + 81600512);         // 400,000 B
    int*   csr   = (int*)  (w + 82000512);         // 3,200,000 B  (total ~85.2 MB)

    const int SCAN_NB = (N_NODES + 2047) / 2048;   // 49

    // graph preprocessing
    hipMemsetAsync(cnts, 0, N_NODES * sizeof(int), stream);
    k_count<<<(N_EDGES + 255) / 256, 256, 0, stream>>>(ei, cnts);
    k_scan1<<<SCAN_NB, 256, 0, stream>>>(cnts, part, bsums);
    k_scan2<<<1, 64, 0, stream>>>(bsums, SCAN_NB);
    k_scan3<<<(N_NODES + 255) / 256, 256, 0, stream>>>(part, bsums, cnts, rowp, curs, dinv);
    k_fill<<<(N_EDGES + 255) / 256, 256, 0, stream>>>(ei, curs, csr);

    dim3 gblk(64, 4);
    int ggrid = N_NODES / 32;                      // 3125

    // GCN layer 1
    k_gemm<F_IN, 0><<<ggrid, gblk, 0, stream>>>(x, W1, dinv, nullptr, nullptr, nullptr, nullptr, nullptr, bufA);
    k_agg<<<N_NODES, 128, 0, stream>>>(bufA, rowp, csr, dinv, b1, g1, be1, m1, v1, bufB);
    // GCN layer 2
    k_gemm<HID, 0><<<ggrid, gblk, 0, stream>>>(bufB, W2, dinv, nullptr, nullptr, nullptr, nullptr, nullptr, bufA);
    k_agg<<<N_NODES, 128, 0, stream>>>(bufA, rowp, csr, dinv, b2, g2, be2, m2, v2, bufB);
    // GCN layer 3
    k_gemm<HID, 0><<<ggrid, gblk, 0, stream>>>(bufB, W3, dinv, nullptr, nullptr, nullptr, nullptr, nullptr, bufA);
    k_agg<<<N_NODES, 128, 0, stream>>>(bufA, rowp, csr, dinv, b3, g3, be3, m3, v3, bufB);
    // dense head
    k_gemm<HID, 1><<<ggrid, gblk, 0, stream>>>(bufB, fW1, nullptr, fb1, fg1, fbe1, fm1, fv1, bufA);
    k_gemm<HID, 1><<<ggrid, gblk, 0, stream>>>(bufA, fW2, nullptr, fb2, fg2, fbe2, fm2, fv2, bufB);
    k_head3<<<(N_NODES + 3) / 4, 256, 0, stream>>>(bufB, fW3, fb3, out);
}

// Round 2
// 695.975 us; speedup vs baseline: 1.2433x; 1.2433x over previous
//
#include <hip/hip_runtime.h>

#define N_NODES 100000
#define N_EDGES 800000
#define F_IN    75
#define HID     100
#define BN_EPS  1e-5f

// ---------------- graph preprocessing ----------------

__global__ void k_count(const int* __restrict__ ei, int* __restrict__ counts) {
    int e = blockIdx.x * 256 + threadIdx.x;
    if (e < N_EDGES) atomicAdd(&counts[ei[N_EDGES + e]], 1);
}

// per-block (2048 elems) exclusive scan + block sums
__global__ void k_scan1(const int* __restrict__ counts, int* __restrict__ part,
                        int* __restrict__ bsums) {
    __shared__ int sh[4];
    int tid = threadIdx.x;
    int base = blockIdx.x * 2048 + tid * 8;
    int v[8]; int run = 0;
#pragma unroll
    for (int j = 0; j < 8; j++) {
        int idx = base + j;
        int c = (idx < N_NODES) ? counts[idx] : 0;
        v[j] = run; run += c;
    }
    int lane = tid & 63, wid = tid >> 6;
    int x = run;
#pragma unroll
    for (int off = 1; off < 64; off <<= 1) {
        int y = __shfl_up(x, off);
        if (lane >= off) x += y;
    }
    if (lane == 63) sh[wid] = x;
    __syncthreads();
    int woff = 0;
    for (int w = 0; w < wid; w++) woff += sh[w];
    int excl = woff + x - run;
#pragma unroll
    for (int j = 0; j < 8; j++) {
        int idx = base + j;
        if (idx < N_NODES) part[idx] = excl + v[j];
    }
    if (tid == 255) bsums[blockIdx.x] = woff + x;
}

__global__ void k_scan2(int* bsums, int nb) {
    int tid = threadIdx.x;
    int x = (tid < nb) ? bsums[tid] : 0;
    int orig = x;
    for (int off = 1; off < 64; off <<= 1) {
        int y = __shfl_up(x, off);
        if (tid >= off) x += y;
    }
    if (tid < nb) bsums[tid] = x - orig;
}

__global__ void k_scan3(const int* __restrict__ part, const int* __restrict__ bsums,
                        const int* __restrict__ counts,
                        int* __restrict__ rowp, int* __restrict__ cursor,
                        float* __restrict__ dinv) {
    int i = blockIdx.x * 256 + threadIdx.x;
    if (i < N_NODES) {
        int rp = part[i] + bsums[i >> 11];
        rowp[i] = rp;
        cursor[i] = rp;
        dinv[i] = rsqrtf((float)(counts[i] + 1));  // self-loop => deg >= 1
    }
    if (i == 0) rowp[N_NODES] = N_EDGES;
}

__global__ void k_fill(const int* __restrict__ ei, int* __restrict__ cursor,
                       int* __restrict__ csr) {
    int e = blockIdx.x * 256 + threadIdx.x;
    if (e < N_EDGES) {
        int pos = atomicAdd(&cursor[ei[N_EDGES + e]], 1);
        csr[pos] = ei[e];
    }
}

// ---------------- GEMM: out[N,100] = A[N,K] @ W[K,100] (+ epilogue) ----------------
// MODE 0: out = (A@W) * dinv[row]            (pre-scaled GCN hidden)
// MODE 1: out = relu(BN(A@W + bias))         (dense head layers)
// block (64,4): 32-row A tile staged in LDS (contiguous coalesced copy),
// compute reads A via broadcast ds_read_b128 (uniform address = conflict-free).
// Thread = 8 rows x 2 cols, k-step 4 -> 64 FMA per step per thread.

template <int K, int MODE>
__global__ __launch_bounds__(256) void k_gemm(
    const float* __restrict__ A, const float* __restrict__ W,
    const float* __restrict__ dinv,
    const float* __restrict__ bias, const float* __restrict__ gam,
    const float* __restrict__ bet, const float* __restrict__ mu,
    const float* __restrict__ var,
    float* __restrict__ out) {
    constexpr int KP = (K % 4 == 0) ? K : (K + (4 - K % 4));   // pad row stride to x4
    __shared__ __align__(16) float As[32 * KP];

    int tx = threadIdx.x;                       // 0..63 -> column pair
    int ty = threadIdx.y;                       // 0..3  -> row group (8 rows)
    int tid = ty * 64 + tx;
    int rowbase = blockIdx.x * 32;

    // cooperative stage: rows rowbase..rowbase+31 are contiguous in A
    const float* src = A + (size_t)rowbase * K;
    for (int i = tid; i < 32 * K; i += 256) {
        int r = i / K, c = i % K;               // constexpr K -> magic mul
        As[r * KP + c] = src[i];
    }
    __syncthreads();

    bool active = (tx < 50);                    // 50 lanes cover 100 cols
    int c0 = active ? 2 * tx : 98;              // clamp keeps W reads in-bounds

    float2 acc[8];
#pragma unroll
    for (int r = 0; r < 8; r++) acc[r] = make_float2(0.f, 0.f);

    int k = 0;
    for (; k + 3 < K; k += 4) {
        float2 w0 = *(const float2*)&W[(k + 0) * HID + c0];
        float2 w1 = *(const float2*)&W[(k + 1) * HID + c0];
        float2 w2 = *(const float2*)&W[(k + 2) * HID + c0];
        float2 w3 = *(const float2*)&W[(k + 3) * HID + c0];
#pragma unroll
        for (int r = 0; r < 8; r++) {
            float4 a = *(const float4*)&As[(ty * 8 + r) * KP + k];
            acc[r].x = fmaf(a.x, w0.x, acc[r].x);
            acc[r].y = fmaf(a.x, w0.y, acc[r].y);
            acc[r].x = fmaf(a.y, w1.x, acc[r].x);
            acc[r].y = fmaf(a.y, w1.y, acc[r].y);
            acc[r].x = fmaf(a.z, w2.x, acc[r].x);
            acc[r].y = fmaf(a.z, w2.y, acc[r].y);
            acc[r].x = fmaf(a.w, w3.x, acc[r].x);
            acc[r].y = fmaf(a.w, w3.y, acc[r].y);
        }
    }
    for (; k < K; ++k) {                        // tail (K=75: 3 iters)
        float2 w0 = *(const float2*)&W[k * HID + c0];
#pragma unroll
        for (int r = 0; r < 8; r++) {
            float a = As[(ty * 8 + r) * KP + k];
            acc[r].x = fmaf(a, w0.x, acc[r].x);
            acc[r].y = fmaf(a, w0.y, acc[r].y);
        }
    }

    if (!active) return;
    int rb = rowbase + ty * 8;

    if (MODE == 0) {
#pragma unroll
        for (int r = 0; r < 8; r++) {
            float dv = dinv[rb + r];
            *(float2*)&out[(size_t)(rb + r) * HID + c0] =
                make_float2(acc[r].x * dv, acc[r].y * dv);
        }
    } else {
        float s0 = gam[c0] * rsqrtf(var[c0] + BN_EPS);
        float s1 = gam[c0 + 1] * rsqrtf(var[c0 + 1] + BN_EPS);
        float t0 = bet[c0] - mu[c0] * s0;
        float t1 = bet[c0 + 1] - mu[c0 + 1] * s1;
        float b0 = bias[c0], b1 = bias[c0 + 1];
#pragma unroll
        for (int r = 0; r < 8; r++) {
            float z0 = (acc[r].x + b0) * s0 + t0;
            float z1 = (acc[r].y + b1) * s1 + t1;
            *(float2*)&out[(size_t)(rb + r) * HID + c0] =
                make_float2(fmaxf(z0, 0.f), fmaxf(z1, 0.f));
        }
    }
}

// ---------------- aggregation + bias + relu + BN ----------------
// out[n,c] = BN(relu(dinv[n] * (hs[n,c] + sum_{src in-edges} hs[src,c]) + bias[c]))
// block (64,4): one wave per node, lane = float2 column pair, 4-edge ILP.

__global__ __launch_bounds__(256) void k_agg(
    const float* __restrict__ hs, const int* __restrict__ rowp,
    const int* __restrict__ csr, const float* __restrict__ dinv,
    const float* __restrict__ bias, const float* __restrict__ gam,
    const float* __restrict__ bet, const float* __restrict__ mu,
    const float* __restrict__ var, float* __restrict__ out) {
    int n = blockIdx.x * 4 + threadIdx.y;
    int c = threadIdx.x;
    bool act = (c < 50);
    int c0 = act ? 2 * c : 98;
    int beg = rowp[n], end = rowp[n + 1];

    float2 a0 = *(const float2*)&hs[(size_t)n * HID + c0];   // self-loop term
    float2 a1 = make_float2(0.f, 0.f);
    float2 a2 = make_float2(0.f, 0.f);
    float2 a3 = make_float2(0.f, 0.f);

    int e = beg;
    for (; e + 4 <= end; e += 4) {
        int s0 = csr[e], s1 = csr[e + 1], s2 = csr[e + 2], s3 = csr[e + 3];
        float2 v0 = *(const float2*)&hs[(size_t)s0 * HID + c0];
        float2 v1 = *(const float2*)&hs[(size_t)s1 * HID + c0];
        float2 v2 = *(const float2*)&hs[(size_t)s2 * HID + c0];
        float2 v3 = *(const float2*)&hs[(size_t)s3 * HID + c0];
        a0.x += v0.x; a0.y += v0.y;
        a1.x += v1.x; a1.y += v1.y;
        a2.x += v2.x; a2.y += v2.y;
        a3.x += v3.x; a3.y += v3.y;
    }
    for (; e < end; ++e) {
        int s = csr[e];
        float2 v = *(const float2*)&hs[(size_t)s * HID + c0];
        a0.x += v.x; a0.y += v.y;
    }
    float2 acc = make_float2((a0.x + a1.x) + (a2.x + a3.x),
                             (a0.y + a1.y) + (a2.y + a3.y));

    if (!act) return;
    float dv = dinv[n];
    float sc0 = gam[c0] * rsqrtf(var[c0] + BN_EPS);
    float sc1 = gam[c0 + 1] * rsqrtf(var[c0 + 1] + BN_EPS);
    float z0 = fmaxf(acc.x * dv + bias[c0], 0.f);
    float z1 = fmaxf(acc.y * dv + bias[c0 + 1], 0.f);
    *(float2*)&out[(size_t)n * HID + c0] =
        make_float2(z0 * sc0 + (bet[c0] - mu[c0] * sc0),
                    z1 * sc1 + (bet[c0 + 1] - mu[c0 + 1] * sc1));
}

// ---------------- final 100 -> 3 layer: out = relu(h @ fW3 + fb3) ----------------

__global__ __launch_bounds__(256) void k_head3(
    const float* __restrict__ h, const float* __restrict__ W,
    const float* __restrict__ b, float* __restrict__ out) {
    int lane = threadIdx.x & 63;
    int row = blockIdx.x * 4 + (threadIdx.x >> 6);
    if (row >= N_NODES) return;
    float a0 = h[row * HID + lane];
    float a1 = (lane < 36) ? h[row * HID + 64 + lane] : 0.f;
    float p0 = a0 * W[lane * 3 + 0];
    float p1 = a0 * W[lane * 3 + 1];
    float p2 = a0 * W[lane * 3 + 2];
    if (lane < 36) {
        p0 += a1 * W[(64 + lane) * 3 + 0];
        p1 += a1 * W[(64 + lane) * 3 + 1];
        p2 += a1 * W[(64 + lane) * 3 + 2];
    }
#pragma unroll
    for (int off = 32; off; off >>= 1) {
        p0 += __shfl_xor(p0, off);
        p1 += __shfl_xor(p1, off);
        p2 += __shfl_xor(p2, off);
    }
    if (lane == 0) {
        out[row * 3 + 0] = fmaxf(p0 + b[0], 0.f);
        out[row * 3 + 1] = fmaxf(p1 + b[1], 0.f);
        out[row * 3 + 2] = fmaxf(p2 + b[2], 0.f);
    }
}

// ---------------- launcher ----------------

extern "C" void kernel_launch(void* const* d_in, const int* in_sizes, int n_in,
                              void* d_out, int out_size, void* d_ws, size_t ws_size,
                              hipStream_t stream) {
    const float* x  = (const float*)d_in[0];
    const int*   ei = (const int*)d_in[1];
    const float* W1 = (const float*)d_in[2];  const float* b1 = (const float*)d_in[3];
    const float* g1 = (const float*)d_in[4];  const float* be1 = (const float*)d_in[5];
    const float* m1 = (const float*)d_in[6];  const float* v1 = (const float*)d_in[7];
    const float* W2 = (const float*)d_in[8];  const float* b2 = (const float*)d_in[9];
    const float* g2 = (const float*)d_in[10]; const float* be2 = (const float*)d_in[11];
    const float* m2 = (const float*)d_in[12]; const float* v2 = (const float*)d_in[13];
    const float* W3 = (const float*)d_in[14]; const float* b3 = (const float*)d_in[15];
    const float* g3 = (const float*)d_in[16]; const float* be3 = (const float*)d_in[17];
    const float* m3 = (const float*)d_in[18]; const float* v3 = (const float*)d_in[19];
    const float* fW1 = (const float*)d_in[20]; const float* fb1 = (const float*)d_in[21];
    const float* fg1 = (const float*)d_in[22]; const float* fbe1 = (const float*)d_in[23];
    const float* fm1 = (const float*)d_in[24]; const float* fv1 = (const float*)d_in[25];
    const float* fW2 = (const float*)d_in[26]; const float* fb2 = (const float*)d_in[27];
    const float* fg2 = (const float*)d_in[28]; const float* fbe2 = (const float*)d_in[29];
    const float* fm2 = (const float*)d_in[30]; const float* fv2 = (const float*)d_in[31];
    const float* fW3 = (const float*)d_in[32]; const float* fb3 = (const float*)d_in[33];
    float* out = (float*)d_out;

    char* w = (char*)d_ws;
    float* bufA  = (float*)(w);                    // N*100 f32 = 40,000,000 B
    float* bufB  = (float*)(w + 40000000);         // 40,000,000 B
    int*   cnts  = (int*)  (w + 80000000);         // 400,000 B
    int*   part  = (int*)  (w + 80400000);         // 400,000 B
    int*   rowp  = (int*)  (w + 80800000);         // 400,004 B (pad to 400,256)
    int*   curs  = (int*)  (w + 81200256);         // 400,000 B
    int*   bsums = (int*)  (w + 81600256);         // 256 B
    float* dinv  = (float*)(w + 81600512);         // 400,000 B
    int*   csr   = (int*)  (w + 82000512);         // 3,200,000 B  (total ~85.2 MB)

    const int SCAN_NB = (N_NODES + 2047) / 2048;   // 49

    // graph preprocessing
    hipMemsetAsync(cnts, 0, N_NODES * sizeof(int), stream);
    k_count<<<(N_EDGES + 255) / 256, 256, 0, stream>>>(ei, cnts);
    k_scan1<<<SCAN_NB, 256, 0, stream>>>(cnts, part, bsums);
    k_scan2<<<1, 64, 0, stream>>>(bsums, SCAN_NB);
    k_scan3<<<(N_NODES + 255) / 256, 256, 0, stream>>>(part, bsums, cnts, rowp, curs, dinv);
    k_fill<<<(N_EDGES + 255) / 256, 256, 0, stream>>>(ei, curs, csr);

    dim3 gblk(64, 4);
    int ggrid = N_NODES / 32;                      // 3125
    int agrid = N_NODES / 4;                       // 25000

    // GCN layer 1
    k_gemm<F_IN, 0><<<ggrid, gblk, 0, stream>>>(x, W1, dinv, nullptr, nullptr, nullptr, nullptr, nullptr, bufA);
    k_agg<<<agrid, gblk, 0, stream>>>(bufA, rowp, csr, dinv, b1, g1, be1, m1, v1, bufB);
    // GCN layer 2
    k_gemm<HID, 0><<<ggrid, gblk, 0, stream>>>(bufB, W2, dinv, nullptr, nullptr, nullptr, nullptr, nullptr, bufA);
    k_agg<<<agrid, gblk, 0, stream>>>(bufA, rowp, csr, dinv, b2, g2, be2, m2, v2, bufB);
    // GCN layer 3
    k_gemm<HID, 0><<<ggrid, gblk, 0, stream>>>(bufB, W3, dinv, nullptr, nullptr, nullptr, nullptr, nullptr, bufA);
    k_agg<<<agrid, gblk, 0, stream>>>(bufA, rowp, csr, dinv, b3, g3, be3, m3, v3, bufB);
    // dense head
    k_gemm<HID, 1><<<ggrid, gblk, 0, stream>>>(bufB, fW1, nullptr, fb1, fg1, fbe1, fm1, fv1, bufA);
    k_gemm<HID, 1><<<ggrid, gblk, 0, stream>>>(bufA, fW2, nullptr, fb2, fg2, fbe2, fm2, fv2, bufB);
    k_head3<<<(N_NODES + 3) / 4, 256, 0, stream>>>(bufB, fW3, fb3, out);
}

// Round 3
// 660.141 us; speedup vs baseline: 1.3108x; 1.0543x over previous
//
#include <hip/hip_runtime.h>

#define N_NODES 100000
#define N_EDGES 800000
#define F_IN    75
#define HID     100
#define KP      128            // padded fp16 row stride for intermediates
#define BN_EPS  1e-5f

typedef _Float16 h2 __attribute__((ext_vector_type(2)));
typedef _Float16 h4 __attribute__((ext_vector_type(4)));
typedef _Float16 h8 __attribute__((ext_vector_type(8)));
typedef float    f4 __attribute__((ext_vector_type(4)));

// ---------------- graph preprocessing ----------------

__global__ void k_count(const int* __restrict__ ei, int* __restrict__ counts) {
    int e = blockIdx.x * 256 + threadIdx.x;
    if (e < N_EDGES) atomicAdd(&counts[ei[N_EDGES + e]], 1);
}

__global__ void k_scan1(const int* __restrict__ counts, int* __restrict__ part,
                        int* __restrict__ bsums) {
    __shared__ int sh[4];
    int tid = threadIdx.x;
    int base = blockIdx.x * 2048 + tid * 8;
    int v[8]; int run = 0;
#pragma unroll
    for (int j = 0; j < 8; j++) {
        int idx = base + j;
        int c = (idx < N_NODES) ? counts[idx] : 0;
        v[j] = run; run += c;
    }
    int lane = tid & 63, wid = tid >> 6;
    int x = run;
#pragma unroll
    for (int off = 1; off < 64; off <<= 1) {
        int y = __shfl_up(x, off);
        if (lane >= off) x += y;
    }
    if (lane == 63) sh[wid] = x;
    __syncthreads();
    int woff = 0;
    for (int w = 0; w < wid; w++) woff += sh[w];
    int excl = woff + x - run;
#pragma unroll
    for (int j = 0; j < 8; j++) {
        int idx = base + j;
        if (idx < N_NODES) part[idx] = excl + v[j];
    }
    if (tid == 255) bsums[blockIdx.x] = woff + x;
}

__global__ void k_scan2(int* bsums, int nb) {
    int tid = threadIdx.x;
    int x = (tid < nb) ? bsums[tid] : 0;
    int orig = x;
    for (int off = 1; off < 64; off <<= 1) {
        int y = __shfl_up(x, off);
        if (tid >= off) x += y;
    }
    if (tid < nb) bsums[tid] = x - orig;
}

__global__ void k_scan3(const int* __restrict__ part, const int* __restrict__ bsums,
                        const int* __restrict__ counts,
                        int* __restrict__ rowp, int* __restrict__ cursor,
                        float* __restrict__ dinv) {
    int i = blockIdx.x * 256 + threadIdx.x;
    if (i < N_NODES) {
        int rp = part[i] + bsums[i >> 11];
        rowp[i] = rp;
        cursor[i] = rp;
        dinv[i] = rsqrtf((float)(counts[i] + 1));
    }
    if (i == 0) rowp[N_NODES] = N_EDGES;
}

__global__ void k_fill(const int* __restrict__ ei, int* __restrict__ cursor,
                       int* __restrict__ csr) {
    int e = blockIdx.x * 256 + threadIdx.x;
    if (e < N_EDGES) {
        int pos = atomicAdd(&cursor[ei[N_EDGES + e]], 1);
        csr[pos] = ei[e];
    }
}

// ---------------- MFMA GEMM: out[N,100] = A[N,K] @ W[K,100] + epilogue ----------------
// v_mfma_f32_16x16x32_f16. Verified layouts:
//   A frag: lane holds A[m=lane&15][k=quad*8+j], j=0..7
//   B frag: lane holds B[k=quad*8+j][n=lane&15]
//   D frag: reg r holds D[row=quad*4+r][col=lane&15]
// Block = 256 thr = 4 waves, 64 rows. Wave w owns n-tiles {w, w+4} (w=3: only {3}).
// A loaded straight from global (16B/lane, 16 rows x 64B chunks). No LDS.
// MODE 0: out = (A@W)*dinv[row];  MODE 1: out = relu(BN(A@W+bias)).
// fp16 intermediates have row stride KP=128 with cols >=100 zeroed (so no K masking).

template <int K, bool AF32, int MODE>
__global__ __launch_bounds__(256) void k_gemm(
    const void* __restrict__ Av, const float* __restrict__ W,
    const float* __restrict__ dinv,
    const float* __restrict__ bias, const float* __restrict__ gam,
    const float* __restrict__ bet, const float* __restrict__ mu,
    const float* __restrict__ var,
    _Float16* __restrict__ out) {
    constexpr int KC = (K + 31) / 32;          // 75 -> 3, 100 -> 4
    const int tid = threadIdx.x;
    const int w = tid >> 6;
    const int l = tid & 63;
    const int m16 = l & 15;
    const int q = l >> 4;
    const int rowbase = blockIdx.x * 64;
    const int nt0 = w, nt1 = w + 4;
    const bool has2 = (w < 3);

    // ---- build B fragments from W (fp32, [K][100]) once per block ----
    h8 Bf[2][KC];
#pragma unroll
    for (int ti = 0; ti < 2; ++ti) {
        int t = ti ? nt1 : nt0;
        int n = t * 16 + m16;
        bool tok = (ti == 0) || has2;
#pragma unroll
        for (int kc = 0; kc < KC; ++kc) {
            h8 b;
#pragma unroll
            for (int j = 0; j < 8; ++j) {
                int k = kc * 32 + q * 8 + j;
                float v = (tok && k < K && n < HID) ? W[k * HID + n] : 0.f;
                b[j] = (_Float16)v;
            }
            Bf[ti][kc] = b;
        }
    }

    f4 acc[4][2];
#pragma unroll
    for (int mt = 0; mt < 4; ++mt)
#pragma unroll
        for (int ti = 0; ti < 2; ++ti)
            acc[mt][ti] = (f4){0.f, 0.f, 0.f, 0.f};

    // ---- K loop ----
#pragma unroll
    for (int kc = 0; kc < KC; ++kc) {
#pragma unroll
        for (int mt = 0; mt < 4; ++mt) {
            int row = rowbase + mt * 16 + m16;
            int k0 = kc * 32 + q * 8;
            h8 a;
            if (AF32) {
                const float* Af = (const float*)Av;
#pragma unroll
                for (int j = 0; j < 8; ++j) {
                    int k = k0 + j;
                    float v = (k < K && row < N_NODES) ? Af[(size_t)row * K + k] : 0.f;
                    a[j] = (_Float16)v;
                }
            } else {
                const _Float16* Ah = (const _Float16*)Av;
                a = *(const h8*)&Ah[(size_t)row * KP + k0];   // in-ws even for tail rows
            }
            acc[mt][0] = __builtin_amdgcn_mfma_f32_16x16x32_f16(a, Bf[0][kc], acc[mt][0], 0, 0, 0);
            if (has2)
                acc[mt][1] = __builtin_amdgcn_mfma_f32_16x16x32_f16(a, Bf[1][kc], acc[mt][1], 0, 0, 0);
        }
    }

    // ---- epilogue ----
    const int col0 = nt0 * 16 + m16;                 // always < 100
    const int col1 = nt1 * 16 + m16;                 // may be >= 100
    float s0 = 0.f, t0 = 0.f, s1 = 0.f, t1 = 0.f, bb0 = 0.f, bb1 = 0.f;
    if (MODE == 1) {
        s0 = gam[col0] * rsqrtf(var[col0] + BN_EPS);
        t0 = bet[col0] - mu[col0] * s0;
        bb0 = bias[col0];
        int c1 = (has2 && col1 < HID) ? col1 : 0;
        s1 = gam[c1] * rsqrtf(var[c1] + BN_EPS);
        t1 = bet[c1] - mu[c1] * s1;
        bb1 = bias[c1];
    }
#pragma unroll
    for (int mt = 0; mt < 4; ++mt) {
#pragma unroll
        for (int r = 0; r < 4; ++r) {
            int row = rowbase + mt * 16 + q * 4 + r;
            if (row >= N_NODES) continue;
            float v0 = acc[mt][0][r];
            float v1 = acc[mt][1][r];
            if (MODE == 0) {
                float dv = dinv[row];
                out[(size_t)row * KP + col0] = (_Float16)(v0 * dv);
                if (has2 && col1 < HID)
                    out[(size_t)row * KP + col1] = (_Float16)(v1 * dv);
            } else {
                float z0 = fmaxf((v0 + bb0) * s0 + t0, 0.f);
                out[(size_t)row * KP + col0] = (_Float16)z0;
                if (has2) {
                    // col1 in [100,112) gets acc==0 -> store raw zero-pad value
                    float z1 = (col1 < HID) ? fmaxf((v1 + bb1) * s1 + t1, 0.f) : 0.f;
                    out[(size_t)row * KP + col1] = (_Float16)z1;
                }
            }
        }
    }
    // zero pad cols 112..127 (cols 100..111 handled above: acc=0 in MODE0 path too)
    {
        int rr = tid >> 2;
        int cc = 112 + ((tid & 3) << 2);
        int row = rowbase + rr;
        if (row < N_NODES) {
            if (MODE == 0) {
                // MODE0 pads only matter if a GEMM ever reads this buffer; cheap, do it anyway
                *(h4*)&out[(size_t)row * KP + cc] = (h4){0, 0, 0, 0};
            } else {
                *(h4*)&out[(size_t)row * KP + cc] = (h4){0, 0, 0, 0};
            }
        }
    }
    if (MODE == 0) {
        // cols 100..111 for wave 3's missing tile-7? tiles cover 0..111; col1 stores in
        // MODE0 were masked col1<100 -> cols 100..111 unwritten. Zero them here.
        int rr = tid >> 2;
        int cc = 100 + (tid & 3) * 3;                // 100,103,106,109 — covers via 3-wide
        int row = rowbase + rr;
        if (row < N_NODES) {
            out[(size_t)row * KP + cc] = (_Float16)0.f;
            out[(size_t)row * KP + cc + 1] = (_Float16)0.f;
            out[(size_t)row * KP + cc + 2] = (_Float16)0.f;
        }
    }
}

// ---------------- aggregation + bias + relu + BN (fp16 in/out) ----------------

__global__ __launch_bounds__(256) void k_agg(
    const _Float16* __restrict__ hs, const int* __restrict__ rowp,
    const int* __restrict__ csr, const float* __restrict__ dinv,
    const float* __restrict__ bias, const float* __restrict__ gam,
    const float* __restrict__ bet, const float* __restrict__ mu,
    const float* __restrict__ var, _Float16* __restrict__ out) {
    int n = blockIdx.x * 4 + threadIdx.y;
    int c = threadIdx.x;
    bool act = (c < 50);
    int cl = act ? 2 * c : 98;                  // clamped col for loads
    int beg = rowp[n], end = rowp[n + 1];

    h2 sv = *(const h2*)&hs[(size_t)n * KP + cl];
    float2 a0 = make_float2((float)sv[0], (float)sv[1]);
    float2 a1 = make_float2(0.f, 0.f);
    float2 a2 = make_float2(0.f, 0.f);
    float2 a3 = make_float2(0.f, 0.f);

    int e = beg;
    for (; e + 4 <= end; e += 4) {
        int s0 = csr[e], s1 = csr[e + 1], s2 = csr[e + 2], s3 = csr[e + 3];
        h2 v0 = *(const h2*)&hs[(size_t)s0 * KP + cl];
        h2 v1 = *(const h2*)&hs[(size_t)s1 * KP + cl];
        h2 v2 = *(const h2*)&hs[(size_t)s2 * KP + cl];
        h2 v3 = *(const h2*)&hs[(size_t)s3 * KP + cl];
        a0.x += (float)v0[0]; a0.y += (float)v0[1];
        a1.x += (float)v1[0]; a1.y += (float)v1[1];
        a2.x += (float)v2[0]; a2.y += (float)v2[1];
        a3.x += (float)v3[0]; a3.y += (float)v3[1];
    }
    for (; e < end; ++e) {
        int s = csr[e];
        h2 v = *(const h2*)&hs[(size_t)s * KP + cl];
        a0.x += (float)v[0]; a0.y += (float)v[1];
    }

    if (act) {
        float x0 = (a0.x + a1.x) + (a2.x + a3.x);
        float x1 = (a0.y + a1.y) + (a2.y + a3.y);
        float dv = dinv[n];
        float sc0 = gam[cl] * rsqrtf(var[cl] + BN_EPS);
        float sc1 = gam[cl + 1] * rsqrtf(var[cl + 1] + BN_EPS);
        float z0 = fmaxf(x0 * dv + bias[cl], 0.f);
        float z1 = fmaxf(x1 * dv + bias[cl + 1], 0.f);
        h2 o; o[0] = (_Float16)(z0 * sc0 + (bet[cl] - mu[cl] * sc0));
        o[1] = (_Float16)(z1 * sc1 + (bet[cl + 1] - mu[cl + 1] * sc1));
        *(h2*)&out[(size_t)n * KP + cl] = o;
    } else {
        // zero the pad cols 100..127 so the next GEMM's unmasked K-loop reads zeros
        h2 z; z[0] = (_Float16)0.f; z[1] = (_Float16)0.f;
        *(h2*)&out[(size_t)n * KP + 2 * c] = z;   // 2c in [100,126]
    }
}

// ---------------- final 100 -> 3 layer ----------------

__global__ __launch_bounds__(256) void k_head3(
    const _Float16* __restrict__ h, const float* __restrict__ W,
    const float* __restrict__ b, float* __restrict__ out) {
    int lane = threadIdx.x & 63;
    int row = blockIdx.x * 4 + (threadIdx.x >> 6);
    if (row >= N_NODES) return;
    float p0 = 0.f, p1 = 0.f, p2 = 0.f;
    if (lane < 50) {
        h2 v = *(const h2*)&h[(size_t)row * KP + 2 * lane];
        float a0 = (float)v[0], a1 = (float)v[1];
        int c0 = 2 * lane;
        p0 = a0 * W[c0 * 3 + 0] + a1 * W[(c0 + 1) * 3 + 0];
        p1 = a0 * W[c0 * 3 + 1] + a1 * W[(c0 + 1) * 3 + 1];
        p2 = a0 * W[c0 * 3 + 2] + a1 * W[(c0 + 1) * 3 + 2];
    }
#pragma unroll
    for (int off = 32; off; off >>= 1) {
        p0 += __shfl_xor(p0, off);
        p1 += __shfl_xor(p1, off);
        p2 += __shfl_xor(p2, off);
    }
    if (lane == 0) {
        out[row * 3 + 0] = fmaxf(p0 + b[0], 0.f);
        out[row * 3 + 1] = fmaxf(p1 + b[1], 0.f);
        out[row * 3 + 2] = fmaxf(p2 + b[2], 0.f);
    }
}

// ---------------- launcher ----------------

extern "C" void kernel_launch(void* const* d_in, const int* in_sizes, int n_in,
                              void* d_out, int out_size, void* d_ws, size_t ws_size,
                              hipStream_t stream) {
    const float* x  = (const float*)d_in[0];
    const int*   ei = (const int*)d_in[1];
    const float* W1 = (const float*)d_in[2];  const float* b1 = (const float*)d_in[3];
    const float* g1 = (const float*)d_in[4];  const float* be1 = (const float*)d_in[5];
    const float* m1 = (const float*)d_in[6];  const float* v1 = (const float*)d_in[7];
    const float* W2 = (const float*)d_in[8];  const float* b2 = (const float*)d_in[9];
    const float* g2 = (const float*)d_in[10]; const float* be2 = (const float*)d_in[11];
    const float* m2 = (const float*)d_in[12]; const float* v2 = (const float*)d_in[13];
    const float* W3 = (const float*)d_in[14]; const float* b3 = (const float*)d_in[15];
    const float* g3 = (const float*)d_in[16]; const float* be3 = (const float*)d_in[17];
    const float* m3 = (const float*)d_in[18]; const float* v3 = (const float*)d_in[19];
    const float* fW1 = (const float*)d_in[20]; const float* fb1 = (const float*)d_in[21];
    const float* fg1 = (const float*)d_in[22]; const float* fbe1 = (const float*)d_in[23];
    const float* fm1 = (const float*)d_in[24]; const float* fv1 = (const float*)d_in[25];
    const float* fW2 = (const float*)d_in[26]; const float* fb2 = (const float*)d_in[27];
    const float* fg2 = (const float*)d_in[28]; const float* fbe2 = (const float*)d_in[29];
    const float* fm2 = (const float*)d_in[30]; const float* fv2 = (const float*)d_in[31];
    const float* fW3 = (const float*)d_in[32]; const float* fb3 = (const float*)d_in[33];
    float* out = (float*)d_out;

    char* w = (char*)d_ws;
    _Float16* bufA = (_Float16*)(w);                    // 100032*128*2 = 25,608,192 B
    _Float16* bufB = (_Float16*)(w + 25608192);         // 25,608,192 B
    int*   cnts  = (int*)  (w + 51216384);              // 400,000 B
    int*   part  = (int*)  (w + 51616384);              // 400,000 B
    int*   rowp  = (int*)  (w + 52016384);              // 400,004 -> pad 400,640
    int*   curs  = (int*)  (w + 52417024);              // 400,000 B
    int*   bsums = (int*)  (w + 52817024);              // 256 B
    float* dinv  = (float*)(w + 52817280);              // 400,000 B
    int*   csr   = (int*)  (w + 53217280);              // 3,200,000 B (end ~56.4 MB)

    const int SCAN_NB = (N_NODES + 2047) / 2048;        // 49

    hipMemsetAsync(cnts, 0, N_NODES * sizeof(int), stream);
    k_count<<<(N_EDGES + 255) / 256, 256, 0, stream>>>(ei, cnts);
    k_scan1<<<SCAN_NB, 256, 0, stream>>>(cnts, part, bsums);
    k_scan2<<<1, 64, 0, stream>>>(bsums, SCAN_NB);
    k_scan3<<<(N_NODES + 255) / 256, 256, 0, stream>>>(part, bsums, cnts, rowp, curs, dinv);
    k_fill<<<(N_EDGES + 255) / 256, 256, 0, stream>>>(ei, curs, csr);

    const int ggrid = (N_NODES + 63) / 64;              // 1563
    dim3 ablk(64, 4);
    const int agrid = N_NODES / 4;                      // 25000

    // GCN layer 1 (x is fp32, K=75)
    k_gemm<F_IN, true, 0><<<ggrid, 256, 0, stream>>>(x, W1, dinv, nullptr, nullptr, nullptr, nullptr, nullptr, bufA);
    k_agg<<<agrid, ablk, 0, stream>>>(bufA, rowp, csr, dinv, b1, g1, be1, m1, v1, bufB);
    // GCN layer 2
    k_gemm<HID, false, 0><<<ggrid, 256, 0, stream>>>(bufB, W2, dinv, nullptr, nullptr, nullptr, nullptr, nullptr, bufA);
    k_agg<<<agrid, ablk, 0, stream>>>(bufA, rowp, csr, dinv, b2, g2, be2, m2, v2, bufB);
    // GCN layer 3
    k_gemm<HID, false, 0><<<ggrid, 256, 0, stream>>>(bufB, W3, dinv, nullptr, nullptr, nullptr, nullptr, nullptr, bufA);
    k_agg<<<agrid, ablk, 0, stream>>>(bufA, rowp, csr, dinv, b3, g3, be3, m3, v3, bufB);
    // dense head
    k_gemm<HID, false, 1><<<ggrid, 256, 0, stream>>>(bufB, fW1, nullptr, fb1, fg1, fbe1, fm1, fv1, bufA);
    k_gemm<HID, false, 1><<<ggrid, 256, 0, stream>>>(bufA, fW2, nullptr, fb2, fg2, fbe2, fm2, fv2, bufB);
    k_head3<<<(N_NODES + 3) / 4, 256, 0, stream>>>(bufB, fW3, fb3, out);
}

// Round 4
// 547.694 us; speedup vs baseline: 1.5799x; 1.2053x over previous
//
#include <hip/hip_runtime.h>

#define N_NODES 100000
#define N_EDGES 800000
#define F_IN    75
#define HID     100
#define KP      128            // padded fp16 row stride
#define NROWS   100096         // rows padded to multiple of 128
#define BN_EPS  1e-5f

typedef _Float16 h2 __attribute__((ext_vector_type(2)));
typedef _Float16 h4 __attribute__((ext_vector_type(4)));
typedef _Float16 h8 __attribute__((ext_vector_type(8)));
typedef float    f4 __attribute__((ext_vector_type(4)));

// ---------------- graph preprocessing ----------------

__global__ void k_count(const int* __restrict__ ei, int* __restrict__ counts) {
    int e = blockIdx.x * 256 + threadIdx.x;
    if (e < N_EDGES) atomicAdd(&counts[ei[N_EDGES + e]], 1);
}

__global__ void k_scan1(const int* __restrict__ counts, int* __restrict__ part,
                        int* __restrict__ bsums) {
    __shared__ int sh[4];
    int tid = threadIdx.x;
    int base = blockIdx.x * 2048 + tid * 8;
    int v[8]; int run = 0;
#pragma unroll
    for (int j = 0; j < 8; j++) {
        int idx = base + j;
        int c = (idx < N_NODES) ? counts[idx] : 0;
        v[j] = run; run += c;
    }
    int lane = tid & 63, wid = tid >> 6;
    int x = run;
#pragma unroll
    for (int off = 1; off < 64; off <<= 1) {
        int y = __shfl_up(x, off);
        if (lane >= off) x += y;
    }
    if (lane == 63) sh[wid] = x;
    __syncthreads();
    int woff = 0;
    for (int w = 0; w < wid; w++) woff += sh[w];
    int excl = woff + x - run;
#pragma unroll
    for (int j = 0; j < 8; j++) {
        int idx = base + j;
        if (idx < N_NODES) part[idx] = excl + v[j];
    }
    if (tid == 255) bsums[blockIdx.x] = woff + x;
}

__global__ void k_scan2(int* bsums, int nb) {
    int tid = threadIdx.x;
    int x = (tid < nb) ? bsums[tid] : 0;
    int orig = x;
    for (int off = 1; off < 64; off <<= 1) {
        int y = __shfl_up(x, off);
        if (tid >= off) x += y;
    }
    if (tid < nb) bsums[tid] = x - orig;
}

__global__ void k_scan3(const int* __restrict__ part, const int* __restrict__ bsums,
                        const int* __restrict__ counts,
                        int* __restrict__ rowp, int* __restrict__ cursor,
                        float* __restrict__ dinv) {
    int i = blockIdx.x * 256 + threadIdx.x;
    if (i < N_NODES) {
        int rp = part[i] + bsums[i >> 11];
        rowp[i] = rp;
        cursor[i] = rp;
        dinv[i] = rsqrtf((float)(counts[i] + 1));
    }
    if (i == 0) rowp[N_NODES] = N_EDGES;
}

__global__ void k_fill(const int* __restrict__ ei, int* __restrict__ cursor,
                       int* __restrict__ csr) {
    int e = blockIdx.x * 256 + threadIdx.x;
    if (e < N_EDGES) {
        int pos = atomicAdd(&cursor[ei[N_EDGES + e]], 1);
        csr[pos] = ei[e];
    }
}

// ---------------- x -> fp16 padded (zero pad cols>=75 and rows>=N) ----------------

__global__ __launch_bounds__(256) void k_cvt(const float* __restrict__ x,
                                             _Float16* __restrict__ xh) {
    int tid = threadIdx.x;
    int r = blockIdx.x * 8 + (tid >> 5);
    int c = (tid & 31) * 4;
    h4 o = (h4){0, 0, 0, 0};
    if (r < N_NODES) {
        const float* xr = x + (size_t)r * F_IN;
#pragma unroll
        for (int j = 0; j < 4; ++j)
            if (c + j < F_IN) o[j] = (_Float16)xr[c + j];
    }
    *(h4*)&xh[(size_t)r * KP + c] = o;
}

// ---------------- weight swizzle: W -> MFMA B-fragment order, fp16 ----------------
// wsw[mat][tile=0..7][kc=0..3][lane=0..63] = h8 { W[kc*32+q*8+j][tile*16+m16] }
// mats 3,4 (head): fold BN scale into W columns, and bias' = b*s + t into bfold.

__global__ __launch_bounds__(128) void k_swz(
    const float* __restrict__ W1, const float* __restrict__ W2,
    const float* __restrict__ W3, const float* __restrict__ fW1,
    const float* __restrict__ fW2,
    const float* __restrict__ fb1, const float* __restrict__ fg1,
    const float* __restrict__ fbe1, const float* __restrict__ fm1,
    const float* __restrict__ fv1,
    const float* __restrict__ fb2, const float* __restrict__ fg2,
    const float* __restrict__ fbe2, const float* __restrict__ fm2,
    const float* __restrict__ fv2,
    h8* __restrict__ wsw, float* __restrict__ bfold) {
    int mat = blockIdx.x >> 3, tile = blockIdx.x & 7;
    int tid = threadIdx.x;
    const float* W; int K;
    const float *bb = nullptr, *gg = nullptr, *be = nullptr, *mm = nullptr, *vv = nullptr;
    switch (mat) {
        case 0: W = W1; K = F_IN; break;
        case 1: W = W2; K = HID; break;
        case 2: W = W3; K = HID; break;
        case 3: W = fW1; K = HID; bb = fb1; gg = fg1; be = fbe1; mm = fm1; vv = fv1; break;
        default: W = fW2; K = HID; bb = fb2; gg = fg2; be = fbe2; mm = fm2; vv = fv2; break;
    }
    if (tid < 64) {
        int m16 = tid & 15, q = tid >> 4;
        int n = tile * 16 + m16;
        float sn = 1.f;
        if (mat >= 3 && n < HID) sn = gg[n] * rsqrtf(vv[n] + BN_EPS);
        for (int kc = 0; kc < 4; ++kc) {
            h8 b;
#pragma unroll
            for (int j = 0; j < 8; ++j) {
                int k = kc * 32 + q * 8 + j;
                float v = (k < K && n < HID) ? W[k * HID + n] * sn : 0.f;
                b[j] = (_Float16)v;
            }
            wsw[((size_t)mat * 8 + tile) * 256 + kc * 64 + tid] = b;
        }
    }
    if (mat >= 3 && tile == 0) {
        int c = tid;            // 0..127
        float v = 0.f;
        if (c < HID) {
            float s = gg[c] * rsqrtf(vv[c] + BN_EPS);
            float t = be[c] - mm[c] * s;
            v = bb[c] * s + t;
        }
        bfold[(mat - 3) * 128 + c] = v;
    }
}

// ---------------- MFMA GEMM: out[r,c] = sum_k A[r,k]*B[k,c], fp16, stride KP ----------
// 256 thr = 4 waves; 128 rows/block (8 m-tiles of 16). Wave w owns n-tiles {w, w+4}.
// B-fragments: 8 coalesced h8 loads from pre-swizzled wsw. A: 16B/lane from global.
// MODE 0: out = acc * dinv[row]   (pad cols get 0 since B pad tiles are 0)
// MODE 1: out = relu(acc + bfold[col])   (BN pre-folded; bfold pad = 0)

template <int KC, int MODE>
__global__ __launch_bounds__(256) void k_gemm(
    const _Float16* __restrict__ A, const h8* __restrict__ Bsw,
    const float* __restrict__ dinv, const float* __restrict__ bfold,
    _Float16* __restrict__ out) {
    const int tid = threadIdx.x;
    const int w = tid >> 6, l = tid & 63;
    const int m16 = l & 15, q = l >> 4;
    const int rowbase = blockIdx.x * 128;

    h8 Bf[2][KC];
#pragma unroll
    for (int ti = 0; ti < 2; ++ti)
#pragma unroll
        for (int kc = 0; kc < KC; ++kc)
            Bf[ti][kc] = Bsw[((w + ti * 4) * 4 + kc) * 64 + l];

    f4 acc[8][2];
#pragma unroll
    for (int mt = 0; mt < 8; ++mt) {
        acc[mt][0] = (f4){0.f, 0.f, 0.f, 0.f};
        acc[mt][1] = (f4){0.f, 0.f, 0.f, 0.f};
    }

#pragma unroll
    for (int kc = 0; kc < KC; ++kc) {
#pragma unroll
        for (int mt = 0; mt < 8; ++mt) {
            h8 a = *(const h8*)&A[(size_t)(rowbase + mt * 16 + m16) * KP + kc * 32 + q * 8];
            acc[mt][0] = __builtin_amdgcn_mfma_f32_16x16x32_f16(a, Bf[0][kc], acc[mt][0], 0, 0, 0);
            if (w != 3)     // wave 3's second tile (cols 112..127) is all-zero pad
                acc[mt][1] = __builtin_amdgcn_mfma_f32_16x16x32_f16(a, Bf[1][kc], acc[mt][1], 0, 0, 0);
        }
    }

    const int col0 = w * 16 + m16;          // 0..63
    const int col1 = col0 + 64;             // 64..127
    float bf0 = 0.f, bf1 = 0.f;
    if (MODE == 1) { bf0 = bfold[col0]; bf1 = bfold[col1]; }

#pragma unroll
    for (int mt = 0; mt < 8; ++mt) {
#pragma unroll
        for (int r = 0; r < 4; ++r) {
            int row = rowbase + mt * 16 + q * 4 + r;
            float v0 = acc[mt][0][r], v1 = acc[mt][1][r];
            if (MODE == 0) {
                int dr = row < N_NODES ? row : N_NODES - 1;
                float dv = dinv[dr];
                out[(size_t)row * KP + col0] = (_Float16)(v0 * dv);
                out[(size_t)row * KP + col1] = (_Float16)(v1 * dv);
            } else {
                out[(size_t)row * KP + col0] = (_Float16)fmaxf(v0 + bf0, 0.f);
                out[(size_t)row * KP + col1] = (_Float16)fmaxf(v1 + bf1, 0.f);
            }
        }
    }
}

// ---------------- aggregation + bias + relu + BN (fp16 in/out) ----------------

__global__ __launch_bounds__(256) void k_agg(
    const _Float16* __restrict__ hs, const int* __restrict__ rowp,
    const int* __restrict__ csr, const float* __restrict__ dinv,
    const float* __restrict__ bias, const float* __restrict__ gam,
    const float* __restrict__ bet, const float* __restrict__ mu,
    const float* __restrict__ var, _Float16* __restrict__ out) {
    int n = blockIdx.x * 4 + threadIdx.y;
    int c = threadIdx.x;
    bool act = (c < 50);
    int cl = act ? 2 * c : 98;
    int beg = rowp[n], end = rowp[n + 1];

    h2 sv = *(const h2*)&hs[(size_t)n * KP + cl];
    float2 a0 = make_float2((float)sv[0], (float)sv[1]);
    float2 a1 = make_float2(0.f, 0.f);
    float2 a2 = make_float2(0.f, 0.f);
    float2 a3 = make_float2(0.f, 0.f);

    int e = beg;
    for (; e + 4 <= end; e += 4) {
        int s0 = csr[e], s1 = csr[e + 1], s2 = csr[e + 2], s3 = csr[e + 3];
        h2 v0 = *(const h2*)&hs[(size_t)s0 * KP + cl];
        h2 v1 = *(const h2*)&hs[(size_t)s1 * KP + cl];
        h2 v2 = *(const h2*)&hs[(size_t)s2 * KP + cl];
        h2 v3 = *(const h2*)&hs[(size_t)s3 * KP + cl];
        a0.x += (float)v0[0]; a0.y += (float)v0[1];
        a1.x += (float)v1[0]; a1.y += (float)v1[1];
        a2.x += (float)v2[0]; a2.y += (float)v2[1];
        a3.x += (float)v3[0]; a3.y += (float)v3[1];
    }
    for (; e < end; ++e) {
        int s = csr[e];
        h2 v = *(const h2*)&hs[(size_t)s * KP + cl];
        a0.x += (float)v[0]; a0.y += (float)v[1];
    }

    if (act) {
        float x0 = (a0.x + a1.x) + (a2.x + a3.x);
        float x1 = (a0.y + a1.y) + (a2.y + a3.y);
        float dv = dinv[n];
        float sc0 = gam[cl] * rsqrtf(var[cl] + BN_EPS);
        float sc1 = gam[cl + 1] * rsqrtf(var[cl + 1] + BN_EPS);
        float z0 = fmaxf(x0 * dv + bias[cl], 0.f);
        float z1 = fmaxf(x1 * dv + bias[cl + 1], 0.f);
        h2 o; o[0] = (_Float16)(z0 * sc0 + (bet[cl] - mu[cl] * sc0));
        o[1] = (_Float16)(z1 * sc1 + (bet[cl + 1] - mu[cl + 1] * sc1));
        *(h2*)&out[(size_t)n * KP + cl] = o;
    } else {
        h2 z; z[0] = (_Float16)0.f; z[1] = (_Float16)0.f;
        *(h2*)&out[(size_t)n * KP + 2 * c] = z;
    }
}

// ---------------- final 100 -> 3 layer ----------------

__global__ __launch_bounds__(256) void k_head3(
    const _Float16* __restrict__ h, const float* __restrict__ W,
    const float* __restrict__ b, float* __restrict__ out) {
    int lane = threadIdx.x & 63;
    int row = blockIdx.x * 4 + (threadIdx.x >> 6);
    if (row >= N_NODES) return;
    float p0 = 0.f, p1 = 0.f, p2 = 0.f;
    if (lane < 50) {
        h2 v = *(const h2*)&h[(size_t)row * KP + 2 * lane];
        float a0 = (float)v[0], a1 = (float)v[1];
        int c0 = 2 * lane;
        p0 = a0 * W[c0 * 3 + 0] + a1 * W[(c0 + 1) * 3 + 0];
        p1 = a0 * W[c0 * 3 + 1] + a1 * W[(c0 + 1) * 3 + 1];
        p2 = a0 * W[c0 * 3 + 2] + a1 * W[(c0 + 1) * 3 + 2];
    }
#pragma unroll
    for (int off = 32; off; off >>= 1) {
        p0 += __shfl_xor(p0, off);
        p1 += __shfl_xor(p1, off);
        p2 += __shfl_xor(p2, off);
    }
    if (lane == 0) {
        out[row * 3 + 0] = fmaxf(p0 + b[0], 0.f);
        out[row * 3 + 1] = fmaxf(p1 + b[1], 0.f);
        out[row * 3 + 2] = fmaxf(p2 + b[2], 0.f);
    }
}

// ---------------- launcher ----------------

extern "C" void kernel_launch(void* const* d_in, const int* in_sizes, int n_in,
                              void* d_out, int out_size, void* d_ws, size_t ws_size,
                              hipStream_t stream) {
    const float* x  = (const float*)d_in[0];
    const int*   ei = (const int*)d_in[1];
    const float* W1 = (const float*)d_in[2];  const float* b1 = (const float*)d_in[3];
    const float* g1 = (const float*)d_in[4];  const float* be1 = (const float*)d_in[5];
    const float* m1 = (const float*)d_in[6];  const float* v1 = (const float*)d_in[7];
    const float* W2 = (const float*)d_in[8];  const float* b2 = (const float*)d_in[9];
    const float* g2 = (const float*)d_in[10]; const float* be2 = (const float*)d_in[11];
    const float* m2 = (const float*)d_in[12]; const float* v2 = (const float*)d_in[13];
    const float* W3 = (const float*)d_in[14]; const float* b3 = (const float*)d_in[15];
    const float* g3 = (const float*)d_in[16]; const float* be3 = (const float*)d_in[17];
    const float* m3 = (const float*)d_in[18]; const float* v3 = (const float*)d_in[19];
    const float* fW1 = (const float*)d_in[20]; const float* fb1 = (const float*)d_in[21];
    const float* fg1 = (const float*)d_in[22]; const float* fbe1 = (const float*)d_in[23];
    const float* fm1 = (const float*)d_in[24]; const float* fv1 = (const float*)d_in[25];
    const float* fW2 = (const float*)d_in[26]; const float* fb2 = (const float*)d_in[27];
    const float* fg2 = (const float*)d_in[28]; const float* fbe2 = (const float*)d_in[29];
    const float* fm2 = (const float*)d_in[30]; const float* fv2 = (const float*)d_in[31];
    const float* fW3 = (const float*)d_in[32]; const float* fb3 = (const float*)d_in[33];
    float* out = (float*)d_out;

    char* w = (char*)d_ws;
    const size_t BUF = (size_t)NROWS * KP * 2;          // 25,624,576 B
    _Float16* bufA = (_Float16*)(w);
    _Float16* bufB = (_Float16*)(w + BUF);
    _Float16* xh   = (_Float16*)(w + 2 * BUF);
    h8*    wsw   = (h8*)   (w + 3 * BUF);               // 5*8*4*64*16 = 163,840 B
    float* bfold = (float*)(w + 3 * BUF + 163840);      // 1,024 B
    int*   cnts  = (int*)  (w + 3 * BUF + 164864);      // 400,000
    int*   part  = (int*)  (w + 3 * BUF + 564864);      // 400,000
    int*   rowp  = (int*)  (w + 3 * BUF + 964864);      // 400,128
    int*   curs  = (int*)  (w + 3 * BUF + 1364992);     // 400,000
    int*   bsums = (int*)  (w + 3 * BUF + 1764992);     // 256
    float* dinv  = (float*)(w + 3 * BUF + 1765248);     // 400,000
    int*   csr   = (int*)  (w + 3 * BUF + 2165248);     // 3,200,000  (end ~82.2 MB)

    const int SCAN_NB = (N_NODES + 2047) / 2048;        // 49

    hipMemsetAsync(cnts, 0, N_NODES * sizeof(int), stream);
    k_count<<<(N_EDGES + 255) / 256, 256, 0, stream>>>(ei, cnts);
    k_scan1<<<SCAN_NB, 256, 0, stream>>>(cnts, part, bsums);
    k_scan2<<<1, 64, 0, stream>>>(bsums, SCAN_NB);
    k_scan3<<<(N_NODES + 255) / 256, 256, 0, stream>>>(part, bsums, cnts, rowp, curs, dinv);
    k_fill<<<(N_EDGES + 255) / 256, 256, 0, stream>>>(ei, curs, csr);

    k_cvt<<<NROWS / 8, 256, 0, stream>>>(x, xh);
    k_swz<<<40, 128, 0, stream>>>(W1, W2, W3, fW1, fW2,
                                  fb1, fg1, fbe1, fm1, fv1,
                                  fb2, fg2, fbe2, fm2, fv2, wsw, bfold);

    const int ggrid = NROWS / 128;                      // 782
    dim3 ablk(64, 4);
    const int agrid = N_NODES / 4;                      // 25000

    k_gemm<3, 0><<<ggrid, 256, 0, stream>>>(xh,   wsw + 0 * 2048, dinv, nullptr, bufA);
    k_agg<<<agrid, ablk, 0, stream>>>(bufA, rowp, csr, dinv, b1, g1, be1, m1, v1, bufB);
    k_gemm<4, 0><<<ggrid, 256, 0, stream>>>(bufB, wsw + 1 * 2048, dinv, nullptr, bufA);
    k_agg<<<agrid, ablk, 0, stream>>>(bufA, rowp, csr, dinv, b2, g2, be2, m2, v2, bufB);
    k_gemm<4, 0><<<ggrid, 256, 0, stream>>>(bufB, wsw + 2 * 2048, dinv, nullptr, bufA);
    k_agg<<<agrid, ablk, 0, stream>>>(bufA, rowp, csr, dinv, b3, g3, be3, m3, v3, bufB);
    k_gemm<4, 1><<<ggrid, 256, 0, stream>>>(bufB, wsw + 3 * 2048, nullptr, bfold,       bufA);
    k_gemm<4, 1><<<ggrid, 256, 0, stream>>>(bufA, wsw + 4 * 2048, nullptr, bfold + 128, bufB);
    k_head3<<<(N_NODES + 3) / 4, 256, 0, stream>>>(bufB, fW3, fb3, out);
}

// Round 5
// 487.784 us; speedup vs baseline: 1.7740x; 1.1228x over previous
//
#include <hip/hip_runtime.h>

#define N_NODES 100000
#define N_EDGES 800000
#define F_IN    75
#define HID     100
#define KP      128            // padded fp16 row stride
#define NROWS   100096         // rows padded to multiple of 128
#define BN_EPS  1e-5f
#define LSTR    136            // LDS row stride (halves) in fused head

typedef _Float16 h2 __attribute__((ext_vector_type(2)));
typedef _Float16 h4 __attribute__((ext_vector_type(4)));
typedef _Float16 h8 __attribute__((ext_vector_type(8)));
typedef float    f4 __attribute__((ext_vector_type(4)));

// ---------------- merged: edge count (blocks 0..3124) + x->fp16 cvt ----------------

#define CNT_B 3125

__global__ __launch_bounds__(256) void k_pre(const int* __restrict__ ei,
                                             int* __restrict__ counts,
                                             const float* __restrict__ x,
                                             _Float16* __restrict__ xh) {
    int tid = threadIdx.x;
    if (blockIdx.x < CNT_B) {
        int e = blockIdx.x * 256 + tid;
        if (e < N_EDGES) atomicAdd(&counts[ei[N_EDGES + e]], 1);
    } else {
        int b = blockIdx.x - CNT_B;
        int r = b * 8 + (tid >> 5);
        int c = (tid & 31) * 4;
        h4 o = (h4){0, 0, 0, 0};
        if (r < N_NODES) {
            const float* xr = x + (size_t)r * F_IN;
#pragma unroll
            for (int j = 0; j < 4; ++j)
                if (c + j < F_IN) o[j] = (_Float16)xr[c + j];
        }
        *(h4*)&xh[(size_t)r * KP + c] = o;
    }
}

// ---------------- scans / CSR ----------------

__global__ void k_scan1(const int* __restrict__ counts, int* __restrict__ part,
                        int* __restrict__ bsums) {
    __shared__ int sh[4];
    int tid = threadIdx.x;
    int base = blockIdx.x * 2048 + tid * 8;
    int v[8]; int run = 0;
#pragma unroll
    for (int j = 0; j < 8; j++) {
        int idx = base + j;
        int c = (idx < N_NODES) ? counts[idx] : 0;
        v[j] = run; run += c;
    }
    int lane = tid & 63, wid = tid >> 6;
    int x = run;
#pragma unroll
    for (int off = 1; off < 64; off <<= 1) {
        int y = __shfl_up(x, off);
        if (lane >= off) x += y;
    }
    if (lane == 63) sh[wid] = x;
    __syncthreads();
    int woff = 0;
    for (int w = 0; w < wid; w++) woff += sh[w];
    int excl = woff + x - run;
#pragma unroll
    for (int j = 0; j < 8; j++) {
        int idx = base + j;
        if (idx < N_NODES) part[idx] = excl + v[j];
    }
    if (tid == 255) bsums[blockIdx.x] = woff + x;
}

__global__ void k_scan2(int* bsums, int nb) {
    int tid = threadIdx.x;
    int x = (tid < nb) ? bsums[tid] : 0;
    int orig = x;
    for (int off = 1; off < 64; off <<= 1) {
        int y = __shfl_up(x, off);
        if (tid >= off) x += y;
    }
    if (tid < nb) bsums[tid] = x - orig;
}

__global__ void k_scan3(const int* __restrict__ part, const int* __restrict__ bsums,
                        const int* __restrict__ counts,
                        int* __restrict__ rowp, int* __restrict__ cursor,
                        float* __restrict__ dinv) {
    int i = blockIdx.x * 256 + threadIdx.x;
    if (i < N_NODES) {
        int rp = part[i] + bsums[i >> 11];
        rowp[i] = rp;
        cursor[i] = rp;
        dinv[i] = rsqrtf((float)(counts[i] + 1));
    }
    if (i == 0) rowp[N_NODES] = N_EDGES;
}

__global__ void k_fill(const int* __restrict__ ei, int* __restrict__ cursor,
                       int* __restrict__ csr) {
    int e = blockIdx.x * 256 + threadIdx.x;
    if (e < N_EDGES) {
        int pos = atomicAdd(&cursor[ei[N_EDGES + e]], 1);
        csr[pos] = ei[e];
    }
}

// ---------------- weight swizzle + param folding ----------------
// wsw[mat][tile][kc][lane] = h8 B-fragment (mats 3,4: BN scale folded in).
// bfold[2][128]: head bias' = b*s + t. aggp[3][3][128]: GCN agg (b, s, t).

__global__ __launch_bounds__(128) void k_swz(
    const float* __restrict__ W1, const float* __restrict__ W2,
    const float* __restrict__ W3, const float* __restrict__ fW1,
    const float* __restrict__ fW2,
    const float* __restrict__ b1, const float* __restrict__ g1,
    const float* __restrict__ be1, const float* __restrict__ m1,
    const float* __restrict__ v1,
    const float* __restrict__ b2, const float* __restrict__ g2,
    const float* __restrict__ be2, const float* __restrict__ m2,
    const float* __restrict__ v2,
    const float* __restrict__ b3, const float* __restrict__ g3,
    const float* __restrict__ be3, const float* __restrict__ m3,
    const float* __restrict__ v3,
    const float* __restrict__ fb1, const float* __restrict__ fg1,
    const float* __restrict__ fbe1, const float* __restrict__ fm1,
    const float* __restrict__ fv1,
    const float* __restrict__ fb2, const float* __restrict__ fg2,
    const float* __restrict__ fbe2, const float* __restrict__ fm2,
    const float* __restrict__ fv2,
    h8* __restrict__ wsw, float* __restrict__ bfold, float* __restrict__ aggp) {
    int mat = blockIdx.x >> 3, tile = blockIdx.x & 7;
    int tid = threadIdx.x;

    if (mat == 5) {                       // agg param blocks: tile = layer 0..2
        const float *bb, *gg, *be, *mm, *vv;
        if (tile == 0) { bb = b1; gg = g1; be = be1; mm = m1; vv = v1; }
        else if (tile == 1) { bb = b2; gg = g2; be = be2; mm = m2; vv = v2; }
        else { bb = b3; gg = g3; be = be3; mm = m3; vv = v3; }
        int c = tid;
        float b = 0.f, s = 0.f, t = 0.f;
        if (c < HID) {
            b = bb[c];
            s = gg[c] * rsqrtf(vv[c] + BN_EPS);
            t = be[c] - mm[c] * s;
        }
        aggp[tile * 384 + c] = b;
        aggp[tile * 384 + 128 + c] = s;
        aggp[tile * 384 + 256 + c] = t;
        return;
    }

    const float* W; int K;
    const float *bb = nullptr, *gg = nullptr, *be = nullptr, *mm = nullptr, *vv = nullptr;
    switch (mat) {
        case 0: W = W1; K = F_IN; break;
        case 1: W = W2; K = HID; break;
        case 2: W = W3; K = HID; break;
        case 3: W = fW1; K = HID; bb = fb1; gg = fg1; be = fbe1; mm = fm1; vv = fv1; break;
        default: W = fW2; K = HID; bb = fb2; gg = fg2; be = fbe2; mm = fm2; vv = fv2; break;
    }
    if (tid < 64) {
        int m16 = tid & 15, q = tid >> 4;
        int n = tile * 16 + m16;
        float sn = 1.f;
        if (mat >= 3 && n < HID) sn = gg[n] * rsqrtf(vv[n] + BN_EPS);
        for (int kc = 0; kc < 4; ++kc) {
            h8 b;
#pragma unroll
            for (int j = 0; j < 8; ++j) {
                int k = kc * 32 + q * 8 + j;
                float v = (k < K && n < HID) ? W[k * HID + n] * sn : 0.f;
                b[j] = (_Float16)v;
            }
            wsw[((size_t)mat * 8 + tile) * 256 + kc * 64 + tid] = b;
        }
    }
    if (mat >= 3 && tile == 0) {
        int c = tid;
        float v = 0.f;
        if (c < HID) {
            float s = gg[c] * rsqrtf(vv[c] + BN_EPS);
            float t = be[c] - mm[c] * s;
            v = bb[c] * s + t;
        }
        bfold[(mat - 3) * 128 + c] = v;
    }
}

// ---------------- MFMA GEMM (GCN layers): out = (A @ W) * dinv[row] ----------------

template <int KC>
__global__ __launch_bounds__(256) void k_gemm(
    const _Float16* __restrict__ A, const h8* __restrict__ Bsw,
    const float* __restrict__ dinv, _Float16* __restrict__ out) {
    const int tid = threadIdx.x;
    const int w = tid >> 6, l = tid & 63;
    const int m16 = l & 15, q = l >> 4;
    const int rowbase = blockIdx.x * 128;

    h8 Bf[2][KC];
#pragma unroll
    for (int ti = 0; ti < 2; ++ti)
#pragma unroll
        for (int kc = 0; kc < KC; ++kc)
            Bf[ti][kc] = Bsw[((w + ti * 4) * 4 + kc) * 64 + l];

    f4 acc[8][2];
#pragma unroll
    for (int mt = 0; mt < 8; ++mt) {
        acc[mt][0] = (f4){0.f, 0.f, 0.f, 0.f};
        acc[mt][1] = (f4){0.f, 0.f, 0.f, 0.f};
    }

#pragma unroll
    for (int kc = 0; kc < KC; ++kc) {
#pragma unroll
        for (int mt = 0; mt < 8; ++mt) {
            h8 a = *(const h8*)&A[(size_t)(rowbase + mt * 16 + m16) * KP + kc * 32 + q * 8];
            acc[mt][0] = __builtin_amdgcn_mfma_f32_16x16x32_f16(a, Bf[0][kc], acc[mt][0], 0, 0, 0);
            if (w != 3)
                acc[mt][1] = __builtin_amdgcn_mfma_f32_16x16x32_f16(a, Bf[1][kc], acc[mt][1], 0, 0, 0);
        }
    }

    const int col0 = w * 16 + m16;
    const int col1 = col0 + 64;
#pragma unroll
    for (int mt = 0; mt < 8; ++mt) {
#pragma unroll
        for (int r = 0; r < 4; ++r) {
            int row = rowbase + mt * 16 + q * 4 + r;
            int dr = row < N_NODES ? row : N_NODES - 1;
            float dv = dinv[dr];
            out[(size_t)row * KP + col0] = (_Float16)(acc[mt][0][r] * dv);
            out[(size_t)row * KP + col1] = (_Float16)(acc[mt][1][r] * dv);
        }
    }
}

// ---------------- aggregation: wave/node, 16 lanes x h8 per edge, 4 edges/iter ------
// out[n,c] = BN(relu(dinv[n]*(hs[n,c] + sum_src hs[src,c]) + b[c]))  (b,s,t in aggp)

__global__ __launch_bounds__(256) void k_agg(
    const _Float16* __restrict__ hs, const int* __restrict__ rowp,
    const int* __restrict__ csr, const float* __restrict__ dinv,
    const float* __restrict__ prm, _Float16* __restrict__ out) {
    int n = blockIdx.x * 4 + threadIdx.y;
    int l = threadIdx.x;
    int p = l >> 4, sub = l & 15;
    int co = sub * 8;                                   // this lane's 8 columns
    int beg = rowp[n], end = rowp[n + 1];

    float a0 = 0.f, a1 = 0.f, a2 = 0.f, a3 = 0.f;
    float a4 = 0.f, a5 = 0.f, a6 = 0.f, a7 = 0.f;
    if (p == 0) {                                       // self-loop term
        h8 v = *(const h8*)&hs[(size_t)n * KP + co];
        a0 = (float)v[0]; a1 = (float)v[1]; a2 = (float)v[2]; a3 = (float)v[3];
        a4 = (float)v[4]; a5 = (float)v[5]; a6 = (float)v[6]; a7 = (float)v[7];
    }

    int e = beg + p;
    for (; e + 4 < end; e += 8) {                       // 2-edge ILP per quarter
        int s0 = csr[e], s1 = csr[e + 4];
        h8 v0 = *(const h8*)&hs[(size_t)s0 * KP + co];
        h8 v1 = *(const h8*)&hs[(size_t)s1 * KP + co];
        a0 += (float)v0[0] + (float)v1[0]; a1 += (float)v0[1] + (float)v1[1];
        a2 += (float)v0[2] + (float)v1[2]; a3 += (float)v0[3] + (float)v1[3];
        a4 += (float)v0[4] + (float)v1[4]; a5 += (float)v0[5] + (float)v1[5];
        a6 += (float)v0[6] + (float)v1[6]; a7 += (float)v0[7] + (float)v1[7];
    }
    if (e < end) {
        int s0 = csr[e];
        h8 v0 = *(const h8*)&hs[(size_t)s0 * KP + co];
        a0 += (float)v0[0]; a1 += (float)v0[1]; a2 += (float)v0[2]; a3 += (float)v0[3];
        a4 += (float)v0[4]; a5 += (float)v0[5]; a6 += (float)v0[6]; a7 += (float)v0[7];
    }

#pragma unroll
    for (int mask = 16; mask <= 32; mask <<= 1) {
        a0 += __shfl_xor(a0, mask); a1 += __shfl_xor(a1, mask);
        a2 += __shfl_xor(a2, mask); a3 += __shfl_xor(a3, mask);
        a4 += __shfl_xor(a4, mask); a5 += __shfl_xor(a5, mask);
        a6 += __shfl_xor(a6, mask); a7 += __shfl_xor(a7, mask);
    }

    if (p == 0) {
        float dv = dinv[n];
        f4 bl0 = *(const f4*)&prm[co],        bl1 = *(const f4*)&prm[co + 4];
        f4 sl0 = *(const f4*)&prm[128 + co],  sl1 = *(const f4*)&prm[128 + co + 4];
        f4 tl0 = *(const f4*)&prm[256 + co],  tl1 = *(const f4*)&prm[256 + co + 4];
        h8 o;
        o[0] = (_Float16)(fmaxf(a0 * dv + bl0[0], 0.f) * sl0[0] + tl0[0]);
        o[1] = (_Float16)(fmaxf(a1 * dv + bl0[1], 0.f) * sl0[1] + tl0[1]);
        o[2] = (_Float16)(fmaxf(a2 * dv + bl0[2], 0.f) * sl0[2] + tl0[2]);
        o[3] = (_Float16)(fmaxf(a3 * dv + bl0[3], 0.f) * sl0[3] + tl0[3]);
        o[4] = (_Float16)(fmaxf(a4 * dv + bl1[0], 0.f) * sl1[0] + tl1[0]);
        o[5] = (_Float16)(fmaxf(a5 * dv + bl1[1], 0.f) * sl1[1] + tl1[1]);
        o[6] = (_Float16)(fmaxf(a6 * dv + bl1[2], 0.f) * sl1[2] + tl1[2]);
        o[7] = (_Float16)(fmaxf(a7 * dv + bl1[3], 0.f) * sl1[3] + tl1[3]);
        *(h8*)&out[(size_t)n * KP + co] = o;
    }
}

// ---------------- fused dense head: relu(BN(h@fW1)) @ fW2 -> BN,relu -> @fW3 -> out --
// GEMM1 global->acc->LDS(fp16), GEMM2 LDS->acc->LDS, head3 LDS->out. BN pre-folded.

__global__ __launch_bounds__(256) void k_head(
    const _Float16* __restrict__ A, const h8* __restrict__ Bsw3,
    const h8* __restrict__ Bsw4, const float* __restrict__ bfold1,
    const float* __restrict__ bfold2, const float* __restrict__ fW3,
    const float* __restrict__ fb3, float* __restrict__ out) {
    __shared__ _Float16 sh[128 * LSTR];
    __shared__ float part[128 * 3];
    const int tid = threadIdx.x;
    const int w = tid >> 6, l = tid & 63;
    const int m16 = l & 15, q = l >> 4;
    const int rowbase = blockIdx.x * 128;
    const int col0 = w * 16 + m16, col1 = col0 + 64;

    h8 Bf[2][4];
    f4 acc[8][2];

    // ---- GEMM1: A (global) @ fW1' ----
#pragma unroll
    for (int ti = 0; ti < 2; ++ti)
#pragma unroll
        for (int kc = 0; kc < 4; ++kc)
            Bf[ti][kc] = Bsw3[((w + ti * 4) * 4 + kc) * 64 + l];
#pragma unroll
    for (int mt = 0; mt < 8; ++mt) {
        acc[mt][0] = (f4){0.f, 0.f, 0.f, 0.f};
        acc[mt][1] = (f4){0.f, 0.f, 0.f, 0.f};
    }
#pragma unroll
    for (int kc = 0; kc < 4; ++kc) {
#pragma unroll
        for (int mt = 0; mt < 8; ++mt) {
            h8 a = *(const h8*)&A[(size_t)(rowbase + mt * 16 + m16) * KP + kc * 32 + q * 8];
            acc[mt][0] = __builtin_amdgcn_mfma_f32_16x16x32_f16(a, Bf[0][kc], acc[mt][0], 0, 0, 0);
            if (w != 3)
                acc[mt][1] = __builtin_amdgcn_mfma_f32_16x16x32_f16(a, Bf[1][kc], acc[mt][1], 0, 0, 0);
        }
    }
    {
        float bf0 = bfold1[col0], bf1 = bfold1[col1];
#pragma unroll
        for (int mt = 0; mt < 8; ++mt)
#pragma unroll
            for (int r = 0; r < 4; ++r) {
                int rl = mt * 16 + q * 4 + r;
                sh[rl * LSTR + col0] = (_Float16)fmaxf(acc[mt][0][r] + bf0, 0.f);
                sh[rl * LSTR + col1] = (_Float16)fmaxf(acc[mt][1][r] + bf1, 0.f);
            }
    }
    __syncthreads();

    // ---- GEMM2: h1 (LDS) @ fW2' ----
#pragma unroll
    for (int ti = 0; ti < 2; ++ti)
#pragma unroll
        for (int kc = 0; kc < 4; ++kc)
            Bf[ti][kc] = Bsw4[((w + ti * 4) * 4 + kc) * 64 + l];
#pragma unroll
    for (int mt = 0; mt < 8; ++mt) {
        acc[mt][0] = (f4){0.f, 0.f, 0.f, 0.f};
        acc[mt][1] = (f4){0.f, 0.f, 0.f, 0.f};
    }
#pragma unroll
    for (int kc = 0; kc < 4; ++kc) {
#pragma unroll
        for (int mt = 0; mt < 8; ++mt) {
            h8 a = *(const h8*)&sh[(mt * 16 + m16) * LSTR + kc * 32 + q * 8];
            acc[mt][0] = __builtin_amdgcn_mfma_f32_16x16x32_f16(a, Bf[0][kc], acc[mt][0], 0, 0, 0);
            if (w != 3)
                acc[mt][1] = __builtin_amdgcn_mfma_f32_16x16x32_f16(a, Bf[1][kc], acc[mt][1], 0, 0, 0);
        }
    }
    __syncthreads();            // all LDS reads done before overwrite
    {
        float bf0 = bfold2[col0], bf1 = bfold2[col1];
#pragma unroll
        for (int mt = 0; mt < 8; ++mt)
#pragma unroll
            for (int r = 0; r < 4; ++r) {
                int rl = mt * 16 + q * 4 + r;
                sh[rl * LSTR + col0] = (_Float16)fmaxf(acc[mt][0][r] + bf0, 0.f);
                sh[rl * LSTR + col1] = (_Float16)fmaxf(acc[mt][1][r] + bf1, 0.f);
            }
    }
    __syncthreads();

    // ---- head3: h2 (LDS) @ fW3 ----
    {
        int half = tid >> 7;            // wave-uniform
        int row = tid & 127;
        int cbase = half * 64;
        float p0 = 0.f, p1 = 0.f, p2 = 0.f;
#pragma unroll
        for (int j = 0; j < 8; ++j) {
            h8 v = *(const h8*)&sh[row * LSTR + cbase + j * 8];
#pragma unroll
            for (int jj = 0; jj < 8; ++jj) {
                int c = cbase + j * 8 + jj;
                if (c < HID) {
                    float a = (float)v[jj];
                    p0 = fmaf(a, fW3[c * 3 + 0], p0);
                    p1 = fmaf(a, fW3[c * 3 + 1], p1);
                    p2 = fmaf(a, fW3[c * 3 + 2], p2);
                }
            }
        }
        if (half == 1) {
            part[row * 3 + 0] = p0; part[row * 3 + 1] = p1; part[row * 3 + 2] = p2;
        }
        __syncthreads();
        if (half == 0) {
            int grow = rowbase + row;
            if (grow < N_NODES) {
                out[grow * 3 + 0] = fmaxf(p0 + part[row * 3 + 0] + fb3[0], 0.f);
                out[grow * 3 + 1] = fmaxf(p1 + part[row * 3 + 1] + fb3[1], 0.f);
                out[grow * 3 + 2] = fmaxf(p2 + part[row * 3 + 2] + fb3[2], 0.f);
            }
        }
    }
}

// ---------------- launcher ----------------

extern "C" void kernel_launch(void* const* d_in, const int* in_sizes, int n_in,
                              void* d_out, int out_size, void* d_ws, size_t ws_size,
                              hipStream_t stream) {
    const float* x  = (const float*)d_in[0];
    const int*   ei = (const int*)d_in[1];
    const float* W1 = (const float*)d_in[2];  const float* b1 = (const float*)d_in[3];
    const float* g1 = (const float*)d_in[4];  const float* be1 = (const float*)d_in[5];
    const float* m1 = (const float*)d_in[6];  const float* v1 = (const float*)d_in[7];
    const float* W2 = (const float*)d_in[8];  const float* b2 = (const float*)d_in[9];
    const float* g2 = (const float*)d_in[10]; const float* be2 = (const float*)d_in[11];
    const float* m2 = (const float*)d_in[12]; const float* v2 = (const float*)d_in[13];
    const float* W3 = (const float*)d_in[14]; const float* b3 = (const float*)d_in[15];
    const float* g3 = (const float*)d_in[16]; const float* be3 = (const float*)d_in[17];
    const float* m3 = (const float*)d_in[18]; const float* v3 = (const float*)d_in[19];
    const float* fW1 = (const float*)d_in[20]; const float* fb1 = (const float*)d_in[21];
    const float* fg1 = (const float*)d_in[22]; const float* fbe1 = (const float*)d_in[23];
    const float* fm1 = (const float*)d_in[24]; const float* fv1 = (const float*)d_in[25];
    const float* fW2 = (const float*)d_in[26]; const float* fb2 = (const float*)d_in[27];
    const float* fg2 = (const float*)d_in[28]; const float* fbe2 = (const float*)d_in[29];
    const float* fm2 = (const float*)d_in[30]; const float* fv2 = (const float*)d_in[31];
    const float* fW3 = (const float*)d_in[32]; const float* fb3 = (const float*)d_in[33];
    float* out = (float*)d_out;

    char* w = (char*)d_ws;
    const size_t BUF = (size_t)NROWS * KP * 2;          // 25,624,576 B
    _Float16* bufA = (_Float16*)(w);
    _Float16* bufB = (_Float16*)(w + BUF);
    _Float16* xh   = (_Float16*)(w + 2 * BUF);
    h8*    wsw   = (h8*)   (w + 3 * BUF);               // 163,840 B
    float* bfold = (float*)(w + 3 * BUF + 163840);      // 1,024 B
    float* aggp  = (float*)(w + 3 * BUF + 164864);      // 4,608 B
    int*   cnts  = (int*)  (w + 3 * BUF + 169472);      // 400,000
    int*   part  = (int*)  (w + 3 * BUF + 569472);      // 400,000
    int*   rowp  = (int*)  (w + 3 * BUF + 969472);      // 400,128
    int*   curs  = (int*)  (w + 3 * BUF + 1369600);     // 400,000
    int*   bsums = (int*)  (w + 3 * BUF + 1769600);     // 256
    float* dinv  = (float*)(w + 3 * BUF + 1769856);     // 400,000
    int*   csr   = (int*)  (w + 3 * BUF + 2169856);     // 3,200,000 (end ~82.2 MB)

    const int SCAN_NB = (N_NODES + 2047) / 2048;        // 49

    hipMemsetAsync(cnts, 0, N_NODES * sizeof(int), stream);
    k_pre<<<CNT_B + NROWS / 8, 256, 0, stream>>>(ei, cnts, x, xh);
    k_scan1<<<SCAN_NB, 256, 0, stream>>>(cnts, part, bsums);
    k_scan2<<<1, 64, 0, stream>>>(bsums, SCAN_NB);
    k_scan3<<<(N_NODES + 255) / 256, 256, 0, stream>>>(part, bsums, cnts, rowp, curs, dinv);
    k_fill<<<(N_EDGES + 255) / 256, 256, 0, stream>>>(ei, curs, csr);
    k_swz<<<43, 128, 0, stream>>>(W1, W2, W3, fW1, fW2,
                                  b1, g1, be1, m1, v1,
                                  b2, g2, be2, m2, v2,
                                  b3, g3, be3, m3, v3,
                                  fb1, fg1, fbe1, fm1, fv1,
                                  fb2, fg2, fbe2, fm2, fv2, wsw, bfold, aggp);

    const int ggrid = NROWS / 128;                      // 782
    dim3 ablk(64, 4);
    const int agrid = N_NODES / 4;                      // 25000

    k_gemm<3><<<ggrid, 256, 0, stream>>>(xh,   wsw + 0 * 2048, dinv, bufA);
    k_agg<<<agrid, ablk, 0, stream>>>(bufA, rowp, csr, dinv, aggp + 0 * 384, bufB);
    k_gemm<4><<<ggrid, 256, 0, stream>>>(bufB, wsw + 1 * 2048, dinv, bufA);
    k_agg<<<agrid, ablk, 0, stream>>>(bufA, rowp, csr, dinv, aggp + 1 * 384, bufB);
    k_gemm<4><<<ggrid, 256, 0, stream>>>(bufB, wsw + 2 * 2048, dinv, bufA);
    k_agg<<<agrid, ablk, 0, stream>>>(bufA, rowp, csr, dinv, aggp + 2 * 384, bufB);
    k_head<<<ggrid, 256, 0, stream>>>(bufB, wsw + 3 * 2048, wsw + 4 * 2048,
                                      bfold, bfold + 128, fW3, fb3, out);
}

// Round 6
// 441.752 us; speedup vs baseline: 1.9588x; 1.1042x over previous
//
#include <hip/hip_runtime.h>

#define N_NODES 100000
#define N_EDGES 800000
#define F_IN    75
#define HID     100
#define KP      128            // padded fp16 row stride
#define NROWS   100096         // rows padded to multiple of 128
#define BN_EPS  1e-5f
#define LSTR    136            // LDS row stride (halves): conflict-free MFMA reads

typedef _Float16 h2 __attribute__((ext_vector_type(2)));
typedef _Float16 h4 __attribute__((ext_vector_type(4)));
typedef _Float16 h8 __attribute__((ext_vector_type(8)));
typedef float    f4 __attribute__((ext_vector_type(4)));

// ---------------- count: 4 edges/thread, fire-and-forget atomics ----------------

__global__ __launch_bounds__(256) void k_cnt(const int* __restrict__ ei,
                                             int* __restrict__ counts) {
    int e = (blockIdx.x * 256 + threadIdx.x) * 4;
    if (e + 3 < N_EDGES) {
        int4 d = *(const int4*)&ei[N_EDGES + e];
        atomicAdd(&counts[d.x], 1);
        atomicAdd(&counts[d.y], 1);
        atomicAdd(&counts[d.z], 1);
        atomicAdd(&counts[d.w], 1);
    } else {
        for (int k = e; k < N_EDGES; ++k) atomicAdd(&counts[ei[N_EDGES + k]], 1);
    }
}

// ---------------- scans / CSR ----------------

__global__ void k_scan1(const int* __restrict__ counts, int* __restrict__ part,
                        int* __restrict__ bsums) {
    __shared__ int sh[4];
    int tid = threadIdx.x;
    int base = blockIdx.x * 2048 + tid * 8;
    int v[8]; int run = 0;
#pragma unroll
    for (int j = 0; j < 8; j++) {
        int idx = base + j;
        int c = (idx < N_NODES) ? counts[idx] : 0;
        v[j] = run; run += c;
    }
    int lane = tid & 63, wid = tid >> 6;
    int x = run;
#pragma unroll
    for (int off = 1; off < 64; off <<= 1) {
        int y = __shfl_up(x, off);
        if (lane >= off) x += y;
    }
    if (lane == 63) sh[wid] = x;
    __syncthreads();
    int woff = 0;
    for (int w = 0; w < wid; w++) woff += sh[w];
    int excl = woff + x - run;
#pragma unroll
    for (int j = 0; j < 8; j++) {
        int idx = base + j;
        if (idx < N_NODES) part[idx] = excl + v[j];
    }
    if (tid == 255) bsums[blockIdx.x] = woff + x;
}

__global__ void k_scan2(int* bsums, int nb) {
    int tid = threadIdx.x;
    int x = (tid < nb) ? bsums[tid] : 0;
    int orig = x;
    for (int off = 1; off < 64; off <<= 1) {
        int y = __shfl_up(x, off);
        if (tid >= off) x += y;
    }
    if (tid < nb) bsums[tid] = x - orig;
}

__global__ void k_scan3(const int* __restrict__ part, const int* __restrict__ bsums,
                        const int* __restrict__ counts,
                        int* __restrict__ rowp, int* __restrict__ cursor,
                        float* __restrict__ dinv) {
    int i = blockIdx.x * 256 + threadIdx.x;
    if (i < N_NODES) {
        int rp = part[i] + bsums[i >> 11];
        rowp[i] = rp;
        cursor[i] = rp;
        dinv[i] = rsqrtf((float)(counts[i] + 1));
    }
    if (i == 0) rowp[N_NODES] = N_EDGES;
}

// ---------------- fill: 4 edges/thread, 4 independent atomic chains ----------------

__global__ __launch_bounds__(256) void k_fill(const int* __restrict__ ei,
                                              int* __restrict__ cursor,
                                              int* __restrict__ csr) {
    int e = (blockIdx.x * 256 + threadIdx.x) * 4;
    if (e + 3 < N_EDGES) {
        int4 d = *(const int4*)&ei[N_EDGES + e];
        int4 s = *(const int4*)&ei[e];
        int p0 = atomicAdd(&cursor[d.x], 1);
        int p1 = atomicAdd(&cursor[d.y], 1);
        int p2 = atomicAdd(&cursor[d.z], 1);
        int p3 = atomicAdd(&cursor[d.w], 1);
        csr[p0] = s.x; csr[p1] = s.y; csr[p2] = s.z; csr[p3] = s.w;
    } else {
        for (int k = e; k < N_EDGES; ++k) {
            int pos = atomicAdd(&cursor[ei[N_EDGES + k]], 1);
            csr[pos] = ei[k];
        }
    }
}

// ---------------- weight swizzle + param folding ----------------

__global__ __launch_bounds__(128) void k_swz(
    const float* __restrict__ W1, const float* __restrict__ W2,
    const float* __restrict__ W3, const float* __restrict__ fW1,
    const float* __restrict__ fW2,
    const float* __restrict__ b1, const float* __restrict__ g1,
    const float* __restrict__ be1, const float* __restrict__ m1,
    const float* __restrict__ v1,
    const float* __restrict__ b2, const float* __restrict__ g2,
    const float* __restrict__ be2, const float* __restrict__ m2,
    const float* __restrict__ v2,
    const float* __restrict__ b3, const float* __restrict__ g3,
    const float* __restrict__ be3, const float* __restrict__ m3,
    const float* __restrict__ v3,
    const float* __restrict__ fb1, const float* __restrict__ fg1,
    const float* __restrict__ fbe1, const float* __restrict__ fm1,
    const float* __restrict__ fv1,
    const float* __restrict__ fb2, const float* __restrict__ fg2,
    const float* __restrict__ fbe2, const float* __restrict__ fm2,
    const float* __restrict__ fv2,
    h8* __restrict__ wsw, float* __restrict__ bfold, float* __restrict__ aggp) {
    int mat = blockIdx.x >> 3, tile = blockIdx.x & 7;
    int tid = threadIdx.x;

    if (mat == 5) {                       // agg param blocks: tile = layer 0..2
        const float *bb, *gg, *be, *mm, *vv;
        if (tile == 0) { bb = b1; gg = g1; be = be1; mm = m1; vv = v1; }
        else if (tile == 1) { bb = b2; gg = g2; be = be2; mm = m2; vv = v2; }
        else { bb = b3; gg = g3; be = be3; mm = m3; vv = v3; }
        int c = tid;
        float b = 0.f, s = 0.f, t = 0.f;
        if (c < HID) {
            b = bb[c];
            s = gg[c] * rsqrtf(vv[c] + BN_EPS);
            t = be[c] - mm[c] * s;
        }
        aggp[tile * 384 + c] = b;
        aggp[tile * 384 + 128 + c] = s;
        aggp[tile * 384 + 256 + c] = t;
        return;
    }

    const float* W; int K;
    const float *bb = nullptr, *gg = nullptr, *be = nullptr, *mm = nullptr, *vv = nullptr;
    switch (mat) {
        case 0: W = W1; K = F_IN; break;
        case 1: W = W2; K = HID; break;
        case 2: W = W3; K = HID; break;
        case 3: W = fW1; K = HID; bb = fb1; gg = fg1; be = fbe1; mm = fm1; vv = fv1; break;
        default: W = fW2; K = HID; bb = fb2; gg = fg2; be = fbe2; mm = fm2; vv = fv2; break;
    }
    if (tid < 64) {
        int m16 = tid & 15, q = tid >> 4;
        int n = tile * 16 + m16;
        float sn = 1.f;
        if (mat >= 3 && n < HID) sn = gg[n] * rsqrtf(vv[n] + BN_EPS);
        for (int kc = 0; kc < 4; ++kc) {
            h8 b;
#pragma unroll
            for (int j = 0; j < 8; ++j) {
                int k = kc * 32 + q * 8 + j;
                float v = (k < K && n < HID) ? W[k * HID + n] * sn : 0.f;
                b[j] = (_Float16)v;
            }
            wsw[((size_t)mat * 8 + tile) * 256 + kc * 64 + tid] = b;
        }
    }
    if (mat >= 3 && tile == 0) {
        int c = tid;
        float v = 0.f;
        if (c < HID) {
            float s = gg[c] * rsqrtf(vv[c] + BN_EPS);
            float t = be[c] - mm[c] * s;
            v = bb[c] * s + t;
        }
        bfold[(mat - 3) * 128 + c] = v;
    }
}

// ---------------- MFMA GEMM (GCN layers): out = (A @ W) * dinv[row] ----------------
// A staged in LDS (fp32 input converted in-stage for layer 1). Stride 136 halves
// => MFMA fragment ds_read_b128 pattern is 2-way-conflict max (free).

template <int KC, bool AF32>
__global__ __launch_bounds__(256) void k_gemm(
    const void* __restrict__ Av, const h8* __restrict__ Bsw,
    const float* __restrict__ dinv, _Float16* __restrict__ out) {
    __shared__ _Float16 As[128 * LSTR];
    const int tid = threadIdx.x;
    const int w = tid >> 6, l = tid & 63;
    const int m16 = l & 15, q = l >> 4;
    const int rowbase = blockIdx.x * 128;

    h8 Bf[2][KC];
#pragma unroll
    for (int ti = 0; ti < 2; ++ti)
#pragma unroll
        for (int kc = 0; kc < KC; ++kc)
            Bf[ti][kc] = Bsw[((w + ti * 4) * 4 + kc) * 64 + l];

    if (AF32) {
        const float* x = (const float*)Av;
        for (int i = tid; i < 128 * 80; i += 256) {       // cols 0..79
            int r = i / 80, c = i - r * 80;
            int grow = rowbase + r;
            float v = (c < F_IN && grow < N_NODES) ? x[(size_t)grow * F_IN + c] : 0.f;
            As[r * LSTR + c] = (_Float16)v;
        }
        for (int i = tid; i < 128 * 16; i += 256) {       // cols 80..95 zero (KC=3)
            int r = i >> 4, c = 80 + (i & 15);
            As[r * LSTR + c] = (_Float16)0.f;
        }
    } else {
        const _Float16* A = (const _Float16*)Av;
        for (int i = tid; i < 128 * 16; i += 256) {       // 16 h8 chunks/row
            int r = i >> 4, c = i & 15;
            *(h8*)&As[r * LSTR + c * 8] = *(const h8*)&A[(size_t)(rowbase + r) * KP + c * 8];
        }
    }
    __syncthreads();

    f4 acc[8][2];
#pragma unroll
    for (int mt = 0; mt < 8; ++mt) {
        acc[mt][0] = (f4){0.f, 0.f, 0.f, 0.f};
        acc[mt][1] = (f4){0.f, 0.f, 0.f, 0.f};
    }

#pragma unroll
    for (int kc = 0; kc < KC; ++kc) {
#pragma unroll
        for (int mt = 0; mt < 8; ++mt) {
            h8 a = *(const h8*)&As[(mt * 16 + m16) * LSTR + kc * 32 + q * 8];
            acc[mt][0] = __builtin_amdgcn_mfma_f32_16x16x32_f16(a, Bf[0][kc], acc[mt][0], 0, 0, 0);
            if (w != 3)
                acc[mt][1] = __builtin_amdgcn_mfma_f32_16x16x32_f16(a, Bf[1][kc], acc[mt][1], 0, 0, 0);
        }
    }

    const int col0 = w * 16 + m16;
    const int col1 = col0 + 64;
#pragma unroll
    for (int mt = 0; mt < 8; ++mt) {
#pragma unroll
        for (int r = 0; r < 4; ++r) {
            int row = rowbase + mt * 16 + q * 4 + r;
            int dr = row < N_NODES ? row : N_NODES - 1;
            float dv = dinv[dr];
            out[(size_t)row * KP + col0] = (_Float16)(acc[mt][0][r] * dv);
            out[(size_t)row * KP + col1] = (_Float16)(acc[mt][1][r] * dv);
        }
    }
}

// ---------------- aggregation: quarter-wave (16 lanes x h8) per node ----------------
// 4 nodes/wave, 16 nodes/block. ILP-4 edge loop, no cross-lane reduce.

__global__ __launch_bounds__(256) void k_agg(
    const _Float16* __restrict__ hs, const int* __restrict__ rowp,
    const int* __restrict__ csr, const float* __restrict__ dinv,
    const float* __restrict__ prm, _Float16* __restrict__ out) {
    int l = threadIdx.x;
    int q = l >> 4, sub = l & 15;
    int n = blockIdx.x * 16 + threadIdx.y * 4 + q;
    int co = sub * 8;
    int beg = rowp[n], end = rowp[n + 1];

    float acc[8];
    {
        h8 v = *(const h8*)&hs[(size_t)n * KP + co];      // self-loop term
#pragma unroll
        for (int j = 0; j < 8; ++j) acc[j] = (float)v[j];
    }

    int e = beg;
    for (; e + 3 < end; e += 4) {
        int s0 = csr[e], s1 = csr[e + 1], s2 = csr[e + 2], s3 = csr[e + 3];
        h8 v0 = *(const h8*)&hs[(size_t)s0 * KP + co];
        h8 v1 = *(const h8*)&hs[(size_t)s1 * KP + co];
        h8 v2 = *(const h8*)&hs[(size_t)s2 * KP + co];
        h8 v3 = *(const h8*)&hs[(size_t)s3 * KP + co];
#pragma unroll
        for (int j = 0; j < 8; ++j)
            acc[j] += ((float)v0[j] + (float)v1[j]) + ((float)v2[j] + (float)v3[j]);
    }
    for (; e < end; ++e) {
        int s = csr[e];
        h8 v = *(const h8*)&hs[(size_t)s * KP + co];
#pragma unroll
        for (int j = 0; j < 8; ++j) acc[j] += (float)v[j];
    }

    float dv = dinv[n];
    f4 bl0 = *(const f4*)&prm[co],       bl1 = *(const f4*)&prm[co + 4];
    f4 sl0 = *(const f4*)&prm[128 + co], sl1 = *(const f4*)&prm[128 + co + 4];
    f4 tl0 = *(const f4*)&prm[256 + co], tl1 = *(const f4*)&prm[256 + co + 4];
    h8 o;
    o[0] = (_Float16)(fmaxf(acc[0] * dv + bl0[0], 0.f) * sl0[0] + tl0[0]);
    o[1] = (_Float16)(fmaxf(acc[1] * dv + bl0[1], 0.f) * sl0[1] + tl0[1]);
    o[2] = (_Float16)(fmaxf(acc[2] * dv + bl0[2], 0.f) * sl0[2] + tl0[2]);
    o[3] = (_Float16)(fmaxf(acc[3] * dv + bl0[3], 0.f) * sl0[3] + tl0[3]);
    o[4] = (_Float16)(fmaxf(acc[4] * dv + bl1[0], 0.f) * sl1[0] + tl1[0]);
    o[5] = (_Float16)(fmaxf(acc[5] * dv + bl1[1], 0.f) * sl1[1] + tl1[1]);
    o[6] = (_Float16)(fmaxf(acc[6] * dv + bl1[2], 0.f) * sl1[2] + tl1[2]);
    o[7] = (_Float16)(fmaxf(acc[7] * dv + bl1[3], 0.f) * sl1[3] + tl1[3]);
    *(h8*)&out[(size_t)n * KP + co] = o;
}

// ---------------- fused dense head ----------------
// stage A in LDS -> GEMM1 -> h1 in LDS -> GEMM2 -> h2 in LDS -> 100->3 reduce.

__global__ __launch_bounds__(256) void k_head(
    const _Float16* __restrict__ A, const h8* __restrict__ Bsw3,
    const h8* __restrict__ Bsw4, const float* __restrict__ bfold1,
    const float* __restrict__ bfold2, const float* __restrict__ fW3,
    const float* __restrict__ fb3, float* __restrict__ out) {
    __shared__ _Float16 sh[128 * LSTR];
    __shared__ float part[128 * 3];
    const int tid = threadIdx.x;
    const int w = tid >> 6, l = tid & 63;
    const int m16 = l & 15, q = l >> 4;
    const int rowbase = blockIdx.x * 128;
    const int col0 = w * 16 + m16, col1 = col0 + 64;

    h8 Bf[2][4];
    f4 acc[8][2];

    // stage A
    for (int i = tid; i < 128 * 16; i += 256) {
        int r = i >> 4, c = i & 15;
        *(h8*)&sh[r * LSTR + c * 8] = *(const h8*)&A[(size_t)(rowbase + r) * KP + c * 8];
    }
    __syncthreads();

    // ---- GEMM1 ----
#pragma unroll
    for (int ti = 0; ti < 2; ++ti)
#pragma unroll
        for (int kc = 0; kc < 4; ++kc)
            Bf[ti][kc] = Bsw3[((w + ti * 4) * 4 + kc) * 64 + l];
#pragma unroll
    for (int mt = 0; mt < 8; ++mt) {
        acc[mt][0] = (f4){0.f, 0.f, 0.f, 0.f};
        acc[mt][1] = (f4){0.f, 0.f, 0.f, 0.f};
    }
#pragma unroll
    for (int kc = 0; kc < 4; ++kc) {
#pragma unroll
        for (int mt = 0; mt < 8; ++mt) {
            h8 a = *(const h8*)&sh[(mt * 16 + m16) * LSTR + kc * 32 + q * 8];
            acc[mt][0] = __builtin_amdgcn_mfma_f32_16x16x32_f16(a, Bf[0][kc], acc[mt][0], 0, 0, 0);
            if (w != 3)
                acc[mt][1] = __builtin_amdgcn_mfma_f32_16x16x32_f16(a, Bf[1][kc], acc[mt][1], 0, 0, 0);
        }
    }
    __syncthreads();
    {
        float bf0 = bfold1[col0], bf1 = bfold1[col1];
#pragma unroll
        for (int mt = 0; mt < 8; ++mt)
#pragma unroll
            for (int r = 0; r < 4; ++r) {
                int rl = mt * 16 + q * 4 + r;
                sh[rl * LSTR + col0] = (_Float16)fmaxf(acc[mt][0][r] + bf0, 0.f);
                sh[rl * LSTR + col1] = (_Float16)fmaxf(acc[mt][1][r] + bf1, 0.f);
            }
    }
    __syncthreads();

    // ---- GEMM2 ----
#pragma unroll
    for (int ti = 0; ti < 2; ++ti)
#pragma unroll
        for (int kc = 0; kc < 4; ++kc)
            Bf[ti][kc] = Bsw4[((w + ti * 4) * 4 + kc) * 64 + l];
#pragma unroll
    for (int mt = 0; mt < 8; ++mt) {
        acc[mt][0] = (f4){0.f, 0.f, 0.f, 0.f};
        acc[mt][1] = (f4){0.f, 0.f, 0.f, 0.f};
    }
#pragma unroll
    for (int kc = 0; kc < 4; ++kc) {
#pragma unroll
        for (int mt = 0; mt < 8; ++mt) {
            h8 a = *(const h8*)&sh[(mt * 16 + m16) * LSTR + kc * 32 + q * 8];
            acc[mt][0] = __builtin_amdgcn_mfma_f32_16x16x32_f16(a, Bf[0][kc], acc[mt][0], 0, 0, 0);
            if (w != 3)
                acc[mt][1] = __builtin_amdgcn_mfma_f32_16x16x32_f16(a, Bf[1][kc], acc[mt][1], 0, 0, 0);
        }
    }
    __syncthreads();
    {
        float bf0 = bfold2[col0], bf1 = bfold2[col1];
#pragma unroll
        for (int mt = 0; mt < 8; ++mt)
#pragma unroll
            for (int r = 0; r < 4; ++r) {
                int rl = mt * 16 + q * 4 + r;
                sh[rl * LSTR + col0] = (_Float16)fmaxf(acc[mt][0][r] + bf0, 0.f);
                sh[rl * LSTR + col1] = (_Float16)fmaxf(acc[mt][1][r] + bf1, 0.f);
            }
    }
    __syncthreads();

    // ---- 100 -> 3 ----
    {
        int half = tid >> 7;
        int row = tid & 127;
        int cbase = half * 64;
        float p0 = 0.f, p1 = 0.f, p2 = 0.f;
#pragma unroll
        for (int j = 0; j < 8; ++j) {
            h8 v = *(const h8*)&sh[row * LSTR + cbase + j * 8];
#pragma unroll
            for (int jj = 0; jj < 8; ++jj) {
                int c = cbase + j * 8 + jj;
                if (c < HID) {
                    float a = (float)v[jj];
                    p0 = fmaf(a, fW3[c * 3 + 0], p0);
                    p1 = fmaf(a, fW3[c * 3 + 1], p1);
                    p2 = fmaf(a, fW3[c * 3 + 2], p2);
                }
            }
        }
        if (half == 1) {
            part[row * 3 + 0] = p0; part[row * 3 + 1] = p1; part[row * 3 + 2] = p2;
        }
        __syncthreads();
        if (half == 0) {
            int grow = rowbase + row;
            if (grow < N_NODES) {
                out[grow * 3 + 0] = fmaxf(p0 + part[row * 3 + 0] + fb3[0], 0.f);
                out[grow * 3 + 1] = fmaxf(p1 + part[row * 3 + 1] + fb3[1], 0.f);
                out[grow * 3 + 2] = fmaxf(p2 + part[row * 3 + 2] + fb3[2], 0.f);
            }
        }
    }
}

// ---------------- launcher ----------------

extern "C" void kernel_launch(void* const* d_in, const int* in_sizes, int n_in,
                              void* d_out, int out_size, void* d_ws, size_t ws_size,
                              hipStream_t stream) {
    const float* x  = (const float*)d_in[0];
    const int*   ei = (const int*)d_in[1];
    const float* W1 = (const float*)d_in[2];  const float* b1 = (const float*)d_in[3];
    const float* g1 = (const float*)d_in[4];  const float* be1 = (const float*)d_in[5];
    const float* m1 = (const float*)d_in[6];  const float* v1 = (const float*)d_in[7];
    const float* W2 = (const float*)d_in[8];  const float* b2 = (const float*)d_in[9];
    const float* g2 = (const float*)d_in[10]; const float* be2 = (const float*)d_in[11];
    const float* m2 = (const float*)d_in[12]; const float* v2 = (const float*)d_in[13];
    const float* W3 = (const float*)d_in[14]; const float* b3 = (const float*)d_in[15];
    const float* g3 = (const float*)d_in[16]; const float* be3 = (const float*)d_in[17];
    const float* m3 = (const float*)d_in[18]; const float* v3 = (const float*)d_in[19];
    const float* fW1 = (const float*)d_in[20]; const float* fb1 = (const float*)d_in[21];
    const float* fg1 = (const float*)d_in[22]; const float* fbe1 = (const float*)d_in[23];
    const float* fm1 = (const float*)d_in[24]; const float* fv1 = (const float*)d_in[25];
    const float* fW2 = (const float*)d_in[26]; const float* fb2 = (const float*)d_in[27];
    const float* fg2 = (const float*)d_in[28]; const float* fbe2 = (const float*)d_in[29];
    const float* fm2 = (const float*)d_in[30]; const float* fv2 = (const float*)d_in[31];
    const float* fW3 = (const float*)d_in[32]; const float* fb3 = (const float*)d_in[33];
    float* out = (float*)d_out;

    char* w = (char*)d_ws;
    const size_t BUF = (size_t)NROWS * KP * 2;          // 25,624,576 B
    _Float16* bufA = (_Float16*)(w);
    _Float16* bufB = (_Float16*)(w + BUF);
    h8*    wsw   = (h8*)   (w + 2 * BUF);               // 163,840 B
    float* bfold = (float*)(w + 2 * BUF + 163840);      // 1,024 B
    float* aggp  = (float*)(w + 2 * BUF + 164864);      // 4,608 B
    int*   cnts  = (int*)  (w + 2 * BUF + 169472);      // 400,000
    int*   part  = (int*)  (w + 2 * BUF + 569472);      // 400,000
    int*   rowp  = (int*)  (w + 2 * BUF + 969472);      // 400,128
    int*   curs  = (int*)  (w + 2 * BUF + 1369600);     // 400,000
    int*   bsums = (int*)  (w + 2 * BUF + 1769600);     // 256
    float* dinv  = (float*)(w + 2 * BUF + 1769856);     // 400,000
    int*   csr   = (int*)  (w + 2 * BUF + 2169856);     // 3,200,000 (end ~56.6 MB)

    const int SCAN_NB = (N_NODES + 2047) / 2048;        // 49
    const int E4_B = (N_EDGES / 4 + 255) / 256;         // 782

    hipMemsetAsync(cnts, 0, N_NODES * sizeof(int), stream);
    k_cnt<<<E4_B, 256, 0, stream>>>(ei, cnts);
    k_scan1<<<SCAN_NB, 256, 0, stream>>>(cnts, part, bsums);
    k_scan2<<<1, 64, 0, stream>>>(bsums, SCAN_NB);
    k_scan3<<<(N_NODES + 255) / 256, 256, 0, stream>>>(part, bsums, cnts, rowp, curs, dinv);
    k_fill<<<E4_B, 256, 0, stream>>>(ei, curs, csr);
    k_swz<<<43, 128, 0, stream>>>(W1, W2, W3, fW1, fW2,
                                  b1, g1, be1, m1, v1,
                                  b2, g2, be2, m2, v2,
                                  b3, g3, be3, m3, v3,
                                  fb1, fg1, fbe1, fm1, fv1,
                                  fb2, fg2, fbe2, fm2, fv2, wsw, bfold, aggp);

    const int ggrid = NROWS / 128;                      // 782
    dim3 ablk(64, 4);
    const int agrid = N_NODES / 16;                     // 6250

    k_gemm<3, true ><<<ggrid, 256, 0, stream>>>(x,    wsw + 0 * 2048, dinv, bufA);
    k_agg<<<agrid, ablk, 0, stream>>>(bufA, rowp, csr, dinv, aggp + 0 * 384, bufB);
    k_gemm<4, false><<<ggrid, 256, 0, stream>>>(bufB, wsw + 1 * 2048, dinv, bufA);
    k_agg<<<agrid, ablk, 0, stream>>>(bufA, rowp, csr, dinv, aggp + 1 * 384, bufB);
    k_gemm<4, false><<<ggrid, 256, 0, stream>>>(bufB, wsw + 2 * 2048, dinv, bufA);
    k_agg<<<agrid, ablk, 0, stream>>>(bufA, rowp, csr, dinv, aggp + 2 * 384, bufB);
    k_head<<<ggrid, 256, 0, stream>>>(bufB, wsw + 3 * 2048, wsw + 4 * 2048,
                                      bfold, bfold + 128, fW3, fb3, out);
}

// Round 7
// 432.297 us; speedup vs baseline: 2.0017x; 1.0219x over previous
//
#include <hip/hip_runtime.h>

#define N_NODES 100000
#define N_EDGES 800000
#define F_IN    75
#define HID     100
#define SP      112            // padded fp16 row stride (halves) for intermediates
#define XSTR    80             // fp16 row stride for converted input
#define NROWS   100096         // rows padded to multiple of 128
#define BN_EPS  1e-5f
#define LSTR    136            // LDS row stride (halves)
#define E4_B    782            // blocks for edge counting (4 edges/thread)
#define BIN_CAP 131072         // per-bucket global capacity (edges)
#define SB_CAP  768            // per-bucket LDS capacity in k_bin

typedef _Float16 h2 __attribute__((ext_vector_type(2)));
typedef _Float16 h8 __attribute__((ext_vector_type(8)));
typedef float    f4 __attribute__((ext_vector_type(4)));

// ------------- merged: in-degree count (blocks 0..781) + x->fp16 (rest) -------------

__global__ __launch_bounds__(256) void k_pre(const int* __restrict__ ei,
                                             int* __restrict__ counts,
                                             const float* __restrict__ x,
                                             _Float16* __restrict__ xh) {
    int tid = threadIdx.x;
    if (blockIdx.x < E4_B) {
        int e = (blockIdx.x * 256 + tid) * 4;
        if (e + 3 < N_EDGES) {
            int4 d = *(const int4*)&ei[N_EDGES + e];
            atomicAdd(&counts[d.x], 1);
            atomicAdd(&counts[d.y], 1);
            atomicAdd(&counts[d.z], 1);
            atomicAdd(&counts[d.w], 1);
        } else {
            for (int k = e; k < N_EDGES; ++k) atomicAdd(&counts[ei[N_EDGES + k]], 1);
        }
    } else {
        int id = (blockIdx.x - E4_B) * 256 + tid;     // exactly NROWS*10 chunks
        int r = id / 10, c0 = (id - r * 10) * 8;
        h8 o;
#pragma unroll
        for (int j = 0; j < 8; ++j) o[j] = (_Float16)0.f;
        if (r < N_NODES) {
            const float* xr = x + (size_t)r * F_IN;
#pragma unroll
            for (int j = 0; j < 8; ++j) {
                int c = c0 + j;
                if (c < F_IN) o[j] = (_Float16)xr[c];
            }
        }
        *(h8*)&xh[(size_t)r * XSTR + c0] = o;
    }
}

// ------------- binning: edges -> 8 dst-range buckets (coalesced appends) -------------

__global__ __launch_bounds__(256) void k_bin(const int* __restrict__ ei,
                                             int* __restrict__ bcur,
                                             int2* __restrict__ bkt) {
    __shared__ int2 sb[8 * SB_CAP];
    __shared__ int scur[8], sbase[8];
    int tid = threadIdx.x;
    if (tid < 8) scur[tid] = 0;
    __syncthreads();
    int base = blockIdx.x * 4096;
#pragma unroll 4
    for (int j = 0; j < 16; ++j) {
        int e = base + j * 256 + tid;
        if (e < N_EDGES) {
            int s = ei[e], d = ei[N_EDGES + e];
            int b = d / 12500;                         // 8 even buckets
            int p = atomicAdd(&scur[b], 1);
            if (p < SB_CAP) sb[b * SB_CAP + p] = make_int2(s, d);
            else {                                     // overflow: direct global append
                int gp = atomicAdd(&bcur[b], 1);
                bkt[(size_t)b * BIN_CAP + gp] = make_int2(s, d);
            }
        }
    }
    __syncthreads();
    if (tid < 8) {
        int c = scur[tid]; if (c > SB_CAP) c = SB_CAP;
        scur[tid] = c;
        sbase[tid] = atomicAdd(&bcur[tid], c);
    }
    __syncthreads();
    for (int b = 0; b < 8; ++b) {
        int c = scur[b], g0 = sbase[b];
        for (int i = tid; i < c; i += 256)
            bkt[(size_t)b * BIN_CAP + g0 + i] = sb[b * SB_CAP + i];
    }
}

// ---------------- scans ----------------

__global__ void k_scan1(const int* __restrict__ counts, int* __restrict__ part,
                        int* __restrict__ bsums) {
    __shared__ int sh[4];
    int tid = threadIdx.x;
    int base = blockIdx.x * 2048 + tid * 8;
    int v[8]; int run = 0;
#pragma unroll
    for (int j = 0; j < 8; j++) {
        int idx = base + j;
        int c = (idx < N_NODES) ? counts[idx] : 0;
        v[j] = run; run += c;
    }
    int lane = tid & 63, wid = tid >> 6;
    int x = run;
#pragma unroll
    for (int off = 1; off < 64; off <<= 1) {
        int y = __shfl_up(x, off);
        if (lane >= off) x += y;
    }
    if (lane == 63) sh[wid] = x;
    __syncthreads();
    int woff = 0;
    for (int w = 0; w < wid; w++) woff += sh[w];
    int excl = woff + x - run;
#pragma unroll
    for (int j = 0; j < 8; j++) {
        int idx = base + j;
        if (idx < N_NODES) part[idx] = excl + v[j];
    }
    if (tid == 255) bsums[blockIdx.x] = woff + x;
}

__global__ void k_scan2(int* bsums, int nb) {
    int tid = threadIdx.x;
    int x = (tid < nb) ? bsums[tid] : 0;
    int orig = x;
    for (int off = 1; off < 64; off <<= 1) {
        int y = __shfl_up(x, off);
        if (tid >= off) x += y;
    }
    if (tid < nb) bsums[tid] = x - orig;
}

__global__ void k_scan3(const int* __restrict__ part, const int* __restrict__ bsums,
                        const int* __restrict__ counts,
                        int* __restrict__ rowp, int* __restrict__ cursor,
                        float* __restrict__ dinv) {
    int i = blockIdx.x * 256 + threadIdx.x;
    if (i < N_NODES) {
        int rp = part[i] + bsums[i >> 11];
        rowp[i] = rp;
        cursor[i] = rp;
        dinv[i] = rsqrtf((float)(counts[i] + 1));
    }
    if (i == 0) rowp[N_NODES] = N_EDGES;
}

// ------------- fill from buckets: bucket = blockIdx%8 (XCD-affine regions) -------------

__global__ __launch_bounds__(256) void k_fill2(const int2* __restrict__ bkt,
                                               const int* __restrict__ bcur,
                                               int* __restrict__ cursor,
                                               int* __restrict__ csr) {
    int b = blockIdx.x & 7;
    int chunk = blockIdx.x >> 3;                        // 0..55
    int cnt = bcur[b];
    const int2* bp = bkt + (size_t)b * BIN_CAP;
    const int S = 56 * 256;
    for (int i0 = chunk * 256 + threadIdx.x; i0 < cnt; i0 += 4 * S) {
        int i1 = i0 + S, i2 = i0 + 2 * S, i3 = i0 + 3 * S;
        int2 p0 = bp[i0];
        int2 p1 = (i1 < cnt) ? bp[i1] : make_int2(0, -1);
        int2 p2 = (i2 < cnt) ? bp[i2] : make_int2(0, -1);
        int2 p3 = (i3 < cnt) ? bp[i3] : make_int2(0, -1);
        int q0 = atomicAdd(&cursor[p0.y], 1);
        int q1 = (p1.y >= 0) ? atomicAdd(&cursor[p1.y], 1) : 0;
        int q2 = (p2.y >= 0) ? atomicAdd(&cursor[p2.y], 1) : 0;
        int q3 = (p3.y >= 0) ? atomicAdd(&cursor[p3.y], 1) : 0;
        csr[q0] = p0.x;
        if (p1.y >= 0) csr[q1] = p1.x;
        if (p2.y >= 0) csr[q2] = p2.x;
        if (p3.y >= 0) csr[q3] = p3.x;
    }
}

// ---------------- weight swizzle + param folding ----------------

__global__ __launch_bounds__(128) void k_swz(
    const float* __restrict__ W1, const float* __restrict__ W2,
    const float* __restrict__ W3, const float* __restrict__ fW1,
    const float* __restrict__ fW2,
    const float* __restrict__ b1, const float* __restrict__ g1,
    const float* __restrict__ be1, const float* __restrict__ m1,
    const float* __restrict__ v1,
    const float* __restrict__ b2, const float* __restrict__ g2,
    const float* __restrict__ be2, const float* __restrict__ m2,
    const float* __restrict__ v2,
    const float* __restrict__ b3, const float* __restrict__ g3,
    const float* __restrict__ be3, const float* __restrict__ m3,
    const float* __restrict__ v3,
    const float* __restrict__ fb1, const float* __restrict__ fg1,
    const float* __restrict__ fbe1, const float* __restrict__ fm1,
    const float* __restrict__ fv1,
    const float* __restrict__ fb2, const float* __restrict__ fg2,
    const float* __restrict__ fbe2, const float* __restrict__ fm2,
    const float* __restrict__ fv2,
    h8* __restrict__ wsw, float* __restrict__ bfold, float* __restrict__ aggp) {
    int mat = blockIdx.x >> 3, tile = blockIdx.x & 7;
    int tid = threadIdx.x;

    if (mat == 5) {
        const float *bb, *gg, *be, *mm, *vv;
        if (tile == 0) { bb = b1; gg = g1; be = be1; mm = m1; vv = v1; }
        else if (tile == 1) { bb = b2; gg = g2; be = be2; mm = m2; vv = v2; }
        else { bb = b3; gg = g3; be = be3; mm = m3; vv = v3; }
        int c = tid;
        float b = 0.f, s = 0.f, t = 0.f;
        if (c < HID) {
            b = bb[c];
            s = gg[c] * rsqrtf(vv[c] + BN_EPS);
            t = be[c] - mm[c] * s;
        }
        aggp[tile * 384 + c] = b;
        aggp[tile * 384 + 128 + c] = s;
        aggp[tile * 384 + 256 + c] = t;
        return;
    }

    const float* W; int K;
    const float *bb = nullptr, *gg = nullptr, *be = nullptr, *mm = nullptr, *vv = nullptr;
    switch (mat) {
        case 0: W = W1; K = F_IN; break;
        case 1: W = W2; K = HID; break;
        case 2: W = W3; K = HID; break;
        case 3: W = fW1; K = HID; bb = fb1; gg = fg1; be = fbe1; mm = fm1; vv = fv1; break;
        default: W = fW2; K = HID; bb = fb2; gg = fg2; be = fbe2; mm = fm2; vv = fv2; break;
    }
    if (tid < 64) {
        int m16 = tid & 15, q = tid >> 4;
        int n = tile * 16 + m16;
        float sn = 1.f;
        if (mat >= 3 && n < HID) sn = gg[n] * rsqrtf(vv[n] + BN_EPS);
        for (int kc = 0; kc < 4; ++kc) {
            h8 b;
#pragma unroll
            for (int j = 0; j < 8; ++j) {
                int k = kc * 32 + q * 8 + j;
                float v = (k < K && n < HID) ? W[k * HID + n] * sn : 0.f;
                b[j] = (_Float16)v;
            }
            wsw[((size_t)mat * 8 + tile) * 256 + kc * 64 + tid] = b;
        }
    }
    if (mat >= 3 && tile == 0) {
        int c = tid;
        float v = 0.f;
        if (c < HID) {
            float s = gg[c] * rsqrtf(vv[c] + BN_EPS);
            float t = be[c] - mm[c] * s;
            v = bb[c] * s + t;
        }
        bfold[(mat - 3) * 128 + c] = v;
    }
}

// ---------------- MFMA GEMM (GCN layers): out = (A @ W) * dinv[row] ----------------
// A (stride ASTR halves) staged to LDS (stride LSTR), zero-fill cols ASTR..KC*32.

template <int KC, int ASTR>
__global__ __launch_bounds__(256) void k_gemm(
    const _Float16* __restrict__ A, const h8* __restrict__ Bsw,
    const float* __restrict__ dinv, _Float16* __restrict__ out) {
    __shared__ _Float16 As[128 * LSTR];
    const int tid = threadIdx.x;
    const int w = tid >> 6, l = tid & 63;
    const int m16 = l & 15, q = l >> 4;
    const int rowbase = blockIdx.x * 128;

    h8 Bf[2][KC];
#pragma unroll
    for (int ti = 0; ti < 2; ++ti)
#pragma unroll
        for (int kc = 0; kc < KC; ++kc)
            Bf[ti][kc] = Bsw[((w + ti * 4) * 4 + kc) * 64 + l];

    constexpr int NCH = ASTR / 8;
    for (int i = tid; i < 128 * NCH; i += 256) {
        int r = i / NCH, c = i - r * NCH;
        *(h8*)&As[r * LSTR + c * 8] = *(const h8*)&A[(size_t)(rowbase + r) * ASTR + c * 8];
    }
    {
        constexpr int ZCH = (KC * 32 - ASTR) / 8;      // 2 in both configs
        h8 z;
#pragma unroll
        for (int j = 0; j < 8; ++j) z[j] = (_Float16)0.f;
        for (int i = tid; i < 128 * ZCH; i += 256) {
            int r = i / ZCH, c = NCH + (i - r * ZCH);
            *(h8*)&As[r * LSTR + c * 8] = z;
        }
    }
    __syncthreads();

    f4 acc[8][2];
#pragma unroll
    for (int mt = 0; mt < 8; ++mt) {
        acc[mt][0] = (f4){0.f, 0.f, 0.f, 0.f};
        acc[mt][1] = (f4){0.f, 0.f, 0.f, 0.f};
    }

#pragma unroll
    for (int kc = 0; kc < KC; ++kc) {
#pragma unroll
        for (int mt = 0; mt < 8; ++mt) {
            h8 a = *(const h8*)&As[(mt * 16 + m16) * LSTR + kc * 32 + q * 8];
            acc[mt][0] = __builtin_amdgcn_mfma_f32_16x16x32_f16(a, Bf[0][kc], acc[mt][0], 0, 0, 0);
            if (w != 3)
                acc[mt][1] = __builtin_amdgcn_mfma_f32_16x16x32_f16(a, Bf[1][kc], acc[mt][1], 0, 0, 0);
        }
    }

    const int col0 = w * 16 + m16;
    const int col1 = col0 + 64;
#pragma unroll
    for (int mt = 0; mt < 8; ++mt) {
#pragma unroll
        for (int r = 0; r < 4; ++r) {
            int row = rowbase + mt * 16 + q * 4 + r;
            int dr = row < N_NODES ? row : N_NODES - 1;
            float dv = dinv[dr];
            out[(size_t)row * SP + col0] = (_Float16)(acc[mt][0][r] * dv);
            if (col1 < SP)
                out[(size_t)row * SP + col1] = (_Float16)(acc[mt][1][r] * dv);
        }
    }
}

// ---------------- aggregation: quarter-wave (14 active lanes x h8) per node --------

__global__ __launch_bounds__(256) void k_agg(
    const _Float16* __restrict__ hs, const int* __restrict__ rowp,
    const int* __restrict__ csr, const float* __restrict__ dinv,
    const float* __restrict__ prm, _Float16* __restrict__ out) {
    int l = threadIdx.x;
    int q = l >> 4, sub = l & 15;
    if (sub >= 14) return;                              // cols 0..111 only
    int n = blockIdx.x * 16 + threadIdx.y * 4 + q;
    int co = sub * 8;
    int beg = rowp[n], end = rowp[n + 1];

    float acc[8];
    {
        h8 v = *(const h8*)&hs[(size_t)n * SP + co];
#pragma unroll
        for (int j = 0; j < 8; ++j) acc[j] = (float)v[j];
    }

    int e = beg;
    for (; e + 3 < end; e += 4) {
        int s0 = csr[e], s1 = csr[e + 1], s2 = csr[e + 2], s3 = csr[e + 3];
        h8 v0 = *(const h8*)&hs[(size_t)s0 * SP + co];
        h8 v1 = *(const h8*)&hs[(size_t)s1 * SP + co];
        h8 v2 = *(const h8*)&hs[(size_t)s2 * SP + co];
        h8 v3 = *(const h8*)&hs[(size_t)s3 * SP + co];
#pragma unroll
        for (int j = 0; j < 8; ++j)
            acc[j] += ((float)v0[j] + (float)v1[j]) + ((float)v2[j] + (float)v3[j]);
    }
    for (; e < end; ++e) {
        int s = csr[e];
        h8 v = *(const h8*)&hs[(size_t)s * SP + co];
#pragma unroll
        for (int j = 0; j < 8; ++j) acc[j] += (float)v[j];
    }

    float dv = dinv[n];
    f4 bl0 = *(const f4*)&prm[co],       bl1 = *(const f4*)&prm[co + 4];
    f4 sl0 = *(const f4*)&prm[128 + co], sl1 = *(const f4*)&prm[128 + co + 4];
    f4 tl0 = *(const f4*)&prm[256 + co], tl1 = *(const f4*)&prm[256 + co + 4];
    h8 o;
    o[0] = (_Float16)(fmaxf(acc[0] * dv + bl0[0], 0.f) * sl0[0] + tl0[0]);
    o[1] = (_Float16)(fmaxf(acc[1] * dv + bl0[1], 0.f) * sl0[1] + tl0[1]);
    o[2] = (_Float16)(fmaxf(acc[2] * dv + bl0[2], 0.f) * sl0[2] + tl0[2]);
    o[3] = (_Float16)(fmaxf(acc[3] * dv + bl0[3], 0.f) * sl0[3] + tl0[3]);
    o[4] = (_Float16)(fmaxf(acc[4] * dv + bl1[0], 0.f) * sl1[0] + tl1[0]);
    o[5] = (_Float16)(fmaxf(acc[5] * dv + bl1[1], 0.f) * sl1[1] + tl1[1]);
    o[6] = (_Float16)(fmaxf(acc[6] * dv + bl1[2], 0.f) * sl1[2] + tl1[2]);
    o[7] = (_Float16)(fmaxf(acc[7] * dv + bl1[3], 0.f) * sl1[3] + tl1[3]);
    *(h8*)&out[(size_t)n * SP + co] = o;
}

// ---------------- fused dense head ----------------

__global__ __launch_bounds__(256) void k_head(
    const _Float16* __restrict__ A, const h8* __restrict__ Bsw3,
    const h8* __restrict__ Bsw4, const float* __restrict__ bfold1,
    const float* __restrict__ bfold2, const float* __restrict__ fW3,
    const float* __restrict__ fb3, float* __restrict__ out) {
    __shared__ _Float16 sh[128 * LSTR];
    __shared__ float part[128 * 3];
    const int tid = threadIdx.x;
    const int w = tid >> 6, l = tid & 63;
    const int m16 = l & 15, q = l >> 4;
    const int rowbase = blockIdx.x * 128;
    const int col0 = w * 16 + m16, col1 = col0 + 64;

    h8 Bf[2][4];
    f4 acc[8][2];

    // stage A (stride SP), zero cols 112..127
    for (int i = tid; i < 128 * 14; i += 256) {
        int r = i / 14, c = i - r * 14;
        *(h8*)&sh[r * LSTR + c * 8] = *(const h8*)&A[(size_t)(rowbase + r) * SP + c * 8];
    }
    {
        h8 z;
#pragma unroll
        for (int j = 0; j < 8; ++j) z[j] = (_Float16)0.f;
        for (int i = tid; i < 128 * 2; i += 256) {
            int r = i >> 1, c = 14 + (i & 1);
            *(h8*)&sh[r * LSTR + c * 8] = z;
        }
    }
    __syncthreads();

    // ---- GEMM1 ----
#pragma unroll
    for (int ti = 0; ti < 2; ++ti)
#pragma unroll
        for (int kc = 0; kc < 4; ++kc)
            Bf[ti][kc] = Bsw3[((w + ti * 4) * 4 + kc) * 64 + l];
#pragma unroll
    for (int mt = 0; mt < 8; ++mt) {
        acc[mt][0] = (f4){0.f, 0.f, 0.f, 0.f};
        acc[mt][1] = (f4){0.f, 0.f, 0.f, 0.f};
    }
#pragma unroll
    for (int kc = 0; kc < 4; ++kc) {
#pragma unroll
        for (int mt = 0; mt < 8; ++mt) {
            h8 a = *(const h8*)&sh[(mt * 16 + m16) * LSTR + kc * 32 + q * 8];
            acc[mt][0] = __builtin_amdgcn_mfma_f32_16x16x32_f16(a, Bf[0][kc], acc[mt][0], 0, 0, 0);
            if (w != 3)
                acc[mt][1] = __builtin_amdgcn_mfma_f32_16x16x32_f16(a, Bf[1][kc], acc[mt][1], 0, 0, 0);
        }
    }
    __syncthreads();
    {
        float bf0 = bfold1[col0], bf1 = bfold1[col1];
#pragma unroll
        for (int mt = 0; mt < 8; ++mt)
#pragma unroll
            for (int r = 0; r < 4; ++r) {
                int rl = mt * 16 + q * 4 + r;
                sh[rl * LSTR + col0] = (_Float16)fmaxf(acc[mt][0][r] + bf0, 0.f);
                sh[rl * LSTR + col1] = (_Float16)fmaxf(acc[mt][1][r] + bf1, 0.f);
            }
    }
    __syncthreads();

    // ---- GEMM2 ----
#pragma unroll
    for (int ti = 0; ti < 2; ++ti)
#pragma unroll
        for (int kc = 0; kc < 4; ++kc)
            Bf[ti][kc] = Bsw4[((w + ti * 4) * 4 + kc) * 64 + l];
#pragma unroll
    for (int mt = 0; mt < 8; ++mt) {
        acc[mt][0] = (f4){0.f, 0.f, 0.f, 0.f};
        acc[mt][1] = (f4){0.f, 0.f, 0.f, 0.f};
    }
#pragma unroll
    for (int kc = 0; kc < 4; ++kc) {
#pragma unroll
        for (int mt = 0; mt < 8; ++mt) {
            h8 a = *(const h8*)&sh[(mt * 16 + m16) * LSTR + kc * 32 + q * 8];
            acc[mt][0] = __builtin_amdgcn_mfma_f32_16x16x32_f16(a, Bf[0][kc], acc[mt][0], 0, 0, 0);
            if (w != 3)
                acc[mt][1] = __builtin_amdgcn_mfma_f32_16x16x32_f16(a, Bf[1][kc], acc[mt][1], 0, 0, 0);
        }
    }
    __syncthreads();
    {
        float bf0 = bfold2[col0], bf1 = bfold2[col1];
#pragma unroll
        for (int mt = 0; mt < 8; ++mt)
#pragma unroll
            for (int r = 0; r < 4; ++r) {
                int rl = mt * 16 + q * 4 + r;
                sh[rl * LSTR + col0] = (_Float16)fmaxf(acc[mt][0][r] + bf0, 0.f);
                sh[rl * LSTR + col1] = (_Float16)fmaxf(acc[mt][1][r] + bf1, 0.f);
            }
    }
    __syncthreads();

    // ---- 100 -> 3 ----
    {
        int half = tid >> 7;
        int row = tid & 127;
        int cbase = half * 64;
        float p0 = 0.f, p1 = 0.f, p2 = 0.f;
#pragma unroll
        for (int j = 0; j < 8; ++j) {
            h8 v = *(const h8*)&sh[row * LSTR + cbase + j * 8];
#pragma unroll
            for (int jj = 0; jj < 8; ++jj) {
                int c = cbase + j * 8 + jj;
                if (c < HID) {
                    float a = (float)v[jj];
                    p0 = fmaf(a, fW3[c * 3 + 0], p0);
                    p1 = fmaf(a, fW3[c * 3 + 1], p1);
                    p2 = fmaf(a, fW3[c * 3 + 2], p2);
                }
            }
        }
        if (half == 1) {
            part[row * 3 + 0] = p0; part[row * 3 + 1] = p1; part[row * 3 + 2] = p2;
        }
        __syncthreads();
        if (half == 0) {
            int grow = rowbase + row;
            if (grow < N_NODES) {
                out[grow * 3 + 0] = fmaxf(p0 + part[row * 3 + 0] + fb3[0], 0.f);
                out[grow * 3 + 1] = fmaxf(p1 + part[row * 3 + 1] + fb3[1], 0.f);
                out[grow * 3 + 2] = fmaxf(p2 + part[row * 3 + 2] + fb3[2], 0.f);
            }
        }
    }
}

// ---------------- launcher ----------------

extern "C" void kernel_launch(void* const* d_in, const int* in_sizes, int n_in,
                              void* d_out, int out_size, void* d_ws, size_t ws_size,
                              hipStream_t stream) {
    const float* x  = (const float*)d_in[0];
    const int*   ei = (const int*)d_in[1];
    const float* W1 = (const float*)d_in[2];  const float* b1 = (const float*)d_in[3];
    const float* g1 = (const float*)d_in[4];  const float* be1 = (const float*)d_in[5];
    const float* m1 = (const float*)d_in[6];  const float* v1 = (const float*)d_in[7];
    const float* W2 = (const float*)d_in[8];  const float* b2 = (const float*)d_in[9];
    const float* g2 = (const float*)d_in[10]; const float* be2 = (const float*)d_in[11];
    const float* m2 = (const float*)d_in[12]; const float* v2 = (const float*)d_in[13];
    const float* W3 = (const float*)d_in[14]; const float* b3 = (const float*)d_in[15];
    const float* g3 = (const float*)d_in[16]; const float* be3 = (const float*)d_in[17];
    const float* m3 = (const float*)d_in[18]; const float* v3 = (const float*)d_in[19];
    const float* fW1 = (const float*)d_in[20]; const float* fb1 = (const float*)d_in[21];
    const float* fg1 = (const float*)d_in[22]; const float* fbe1 = (const float*)d_in[23];
    const float* fm1 = (const float*)d_in[24]; const float* fv1 = (const float*)d_in[25];
    const float* fW2 = (const float*)d_in[26]; const float* fb2 = (const float*)d_in[27];
    const float* fg2 = (const float*)d_in[28]; const float* fbe2 = (const float*)d_in[29];
    const float* fm2 = (const float*)d_in[30]; const float* fv2 = (const float*)d_in[31];
    const float* fW3 = (const float*)d_in[32]; const float* fb3 = (const float*)d_in[33];
    float* out = (float*)d_out;

    char* w = (char*)d_ws;
    const size_t BUFS = (size_t)NROWS * SP * 2;         // 22,421,504 B
    _Float16* bufA = (_Float16*)(w);
    _Float16* bufB = (_Float16*)(w + BUFS);
    _Float16* xh   = (_Float16*)(w + 2 * BUFS);         // NROWS*80*2 = 16,015,360
    h8*    wsw   = (h8*)   (w + 60858368);              // 163,840
    float* bfold = (float*)(w + 61022208);              // 1,024
    float* aggp  = (float*)(w + 61023232);              // 4,608
    int*   cnts  = (int*)  (w + 61027840);              // 400,000
    int*   bcur  = (int*)  (w + 61427840);              // 32 (memset with cnts)
    int*   part  = (int*)  (w + 61427872);              // 400,000
    int*   rowp  = (int*)  (w + 61827872);              // 400,128
    int*   curs  = (int*)  (w + 62228000);              // 400,000
    int*   bsums = (int*)  (w + 62628000);              // 256
    float* dinv  = (float*)(w + 62628256);              // 400,000
    int*   csr   = (int*)  (w + 63028256);              // 3,200,000
    int2*  bkt   = (int2*) (w + 66228256);              // 8,388,608 (end ~74.6 MB)

    const int SCAN_NB = (N_NODES + 2047) / 2048;        // 49
    const int CVT_B = NROWS * 10 / 256;                 // 3910

    hipMemsetAsync(cnts, 0, 400032, stream);            // cnts + bcur
    k_pre<<<E4_B + CVT_B, 256, 0, stream>>>(ei, cnts, x, xh);
    k_bin<<<(N_EDGES + 4095) / 4096, 256, 0, stream>>>(ei, bcur, bkt);
    k_scan1<<<SCAN_NB, 256, 0, stream>>>(cnts, part, bsums);
    k_scan2<<<1, 64, 0, stream>>>(bsums, SCAN_NB);
    k_scan3<<<(N_NODES + 255) / 256, 256, 0, stream>>>(part, bsums, cnts, rowp, curs, dinv);
    k_fill2<<<448, 256, 0, stream>>>(bkt, bcur, curs, csr);
    k_swz<<<43, 128, 0, stream>>>(W1, W2, W3, fW1, fW2,
                                  b1, g1, be1, m1, v1,
                                  b2, g2, be2, m2, v2,
                                  b3, g3, be3, m3, v3,
                                  fb1, fg1, fbe1, fm1, fv1,
                                  fb2, fg2, fbe2, fm2, fv2, wsw, bfold, aggp);

    const int ggrid = NROWS / 128;                      // 782
    dim3 ablk(64, 4);
    const int agrid = N_NODES / 16;                     // 6250

    k_gemm<3, XSTR><<<ggrid, 256, 0, stream>>>(xh,   wsw + 0 * 2048, dinv, bufA);
    k_agg<<<agrid, ablk, 0, stream>>>(bufA, rowp, csr, dinv, aggp + 0 * 384, bufB);
    k_gemm<4, SP  ><<<ggrid, 256, 0, stream>>>(bufB, wsw + 1 * 2048, dinv, bufA);
    k_agg<<<agrid, ablk, 0, stream>>>(bufA, rowp, csr, dinv, aggp + 1 * 384, bufB);
    k_gemm<4, SP  ><<<ggrid, 256, 0, stream>>>(bufB, wsw + 2 * 2048, dinv, bufA);
    k_agg<<<agrid, ablk, 0, stream>>>(bufA, rowp, csr, dinv, aggp + 2 * 384, bufB);
    k_head<<<ggrid, 256, 0, stream>>>(bufB, wsw + 3 * 2048, wsw + 4 * 2048,
                                      bfold, bfold + 128, fW3, fb3, out);
}

// Round 9
// 409.884 us; speedup vs baseline: 2.1111x; 1.0547x over previous
//
#include <hip/hip_runtime.h>

#define N_NODES 100000
#define N_EDGES 800000
#define F_IN    75
#define HID     100
#define SP      112            // padded fp16 row stride (halves) for intermediates
#define XSTR    80             // fp16 row stride for converted input
#define NROWS   100096         // rows padded to multiple of 128
#define BN_EPS  1e-5f
#define LSTR    136            // LDS row stride (halves)
#define NBKT    128            // dst-range buckets
#define NPB     782            // nodes per bucket (128*782 >= 100000)
#define BIN_CAP 8192           // per-bucket global capacity (avg 6250)
#define SBCAP   64             // per-bucket LDS staging capacity in k_bin

typedef _Float16 h8 __attribute__((ext_vector_type(8)));
typedef float    f4 __attribute__((ext_vector_type(4)));
typedef int      i4 __attribute__((ext_vector_type(4)));

__device__ inline void nt_store16(void* p, h8 v) {
    __builtin_nontemporal_store(*(const i4*)&v, (i4*)p);
}
__device__ inline h8 nt_load16(const void* p) {
    i4 t = __builtin_nontemporal_load((const i4*)p);
    return *(const h8*)&t;
}

// ---------------- x -> fp16 (stride 80, zero-padded cols 75..79) ----------------

__global__ __launch_bounds__(256) void k_cvt(const float* __restrict__ x,
                                             _Float16* __restrict__ xh) {
    int id = blockIdx.x * 256 + threadIdx.x;        // NROWS*10 chunks
    int r = id / 10, c0 = (id - r * 10) * 8;
    h8 o;
#pragma unroll
    for (int j = 0; j < 8; ++j) o[j] = (_Float16)0.f;
    if (r < N_NODES) {
        const float* xr = x + (size_t)r * F_IN;
#pragma unroll
        for (int j = 0; j < 8; ++j) {
            int c = c0 + j;
            if (c < F_IN) o[j] = (_Float16)__builtin_nontemporal_load(&xr[c]);
        }
    }
    nt_store16(&xh[(size_t)r * XSTR + c0], o);
}

// ------------- binning: edges -> 128 dst-range buckets (coalesced appends) -----------

__global__ __launch_bounds__(256) void k_bin(const int* __restrict__ ei,
                                             int* __restrict__ bcur,
                                             int2* __restrict__ bkt) {
    __shared__ int2 sb[NBKT * SBCAP];               // 64 KB
    __shared__ int scur[NBKT], sbase[NBKT], spre[NBKT];
    int tid = threadIdx.x;
    for (int i = tid; i < NBKT; i += 256) scur[i] = 0;
    __syncthreads();
    int base = blockIdx.x * 2048;
#pragma unroll
    for (int j = 0; j < 8; ++j) {
        int e = base + j * 256 + tid;
        if (e < N_EDGES) {
            int s = __builtin_nontemporal_load(&ei[e]);
            int d = __builtin_nontemporal_load(&ei[N_EDGES + e]);
            int b = d / NPB;
            int p = atomicAdd(&scur[b], 1);
            if (p < SBCAP) sb[b * SBCAP + p] = make_int2(s, d);
            else {                                  // rare overflow: direct append
                int gp = atomicAdd(&bcur[b], 1);
                bkt[(size_t)b * BIN_CAP + gp] = make_int2(s, d);
            }
        }
    }
    __syncthreads();
    if (tid < NBKT) {
        int c = scur[tid]; if (c > SBCAP) c = SBCAP;
        scur[tid] = c;
        sbase[tid] = atomicAdd(&bcur[tid], c);
    }
    __syncthreads();
    if (tid < NBKT) {                               // inclusive prefix (2 waves)
        int lane = tid & 63;
        int x = scur[tid];
#pragma unroll
        for (int off = 1; off < 64; off <<= 1) {
            int y = __shfl_up(x, off);
            if (lane >= off) x += y;
        }
        spre[tid] = x;
    }
    __syncthreads();
    if (tid >= 64 && tid < NBKT) spre[tid] += spre[63];
    __syncthreads();
    int total = spre[NBKT - 1];
    for (int t = tid; t < total; t += 256) {
        int lo = 0, hi = NBKT - 1;
        while (lo < hi) { int mid = (lo + hi) >> 1; if (spre[mid] > t) hi = mid; else lo = mid + 1; }
        int bb = lo;
        int local = t - (spre[bb] - scur[bb]);
        bkt[(size_t)bb * BIN_CAP + sbase[bb] + local] = sb[bb * SBCAP + local];
    }
}

// ------------- per-bucket: LDS count + scan + rowp/dinv + csr scatter ---------------

__global__ __launch_bounds__(256) void k_local(const int* __restrict__ bcur,
                                               const int2* __restrict__ bkt,
                                               int* __restrict__ rowp,
                                               float* __restrict__ dinv,
                                               int* __restrict__ csr) {
    __shared__ int lcnt[1024];                      // NPB=782, padded
    __shared__ int lofs[1024];
    __shared__ int sbc[NBKT];
    __shared__ int swt[4];
    __shared__ int gbase_s;
    int b = blockIdx.x, tid = threadIdx.x;
    for (int i = tid; i < 1024; i += 256) lcnt[i] = 0;
    if (tid < NBKT) sbc[tid] = bcur[tid];
    __syncthreads();
    if (tid == 0) { int s = 0; for (int j = 0; j < b; ++j) s += sbc[j]; gbase_s = s; }
    int cnt = sbc[b];
    const int2* bp = bkt + (size_t)b * BIN_CAP;
    int base_node = b * NPB;
    // pass 1: count
    for (int i = tid; i < cnt; i += 256)
        atomicAdd(&lcnt[bp[i].y - base_node], 1);
    __syncthreads();
    // block scan of 1024 counters (4/thread)
    int i0 = tid * 4;
    int c0 = lcnt[i0], c1 = lcnt[i0 + 1], c2 = lcnt[i0 + 2], c3 = lcnt[i0 + 3];
    int s = c0 + c1 + c2 + c3;
    int lane = tid & 63, wid = tid >> 6;
    int x = s;
#pragma unroll
    for (int off = 1; off < 64; off <<= 1) {
        int y = __shfl_up(x, off);
        if (lane >= off) x += y;
    }
    if (lane == 63) swt[wid] = x;
    __syncthreads();
    int woff = 0;
    for (int wv = 0; wv < wid; ++wv) woff += swt[wv];
    int excl = woff + x - s;
    lofs[i0] = excl;
    lofs[i0 + 1] = excl + c0;
    lofs[i0 + 2] = excl + c0 + c1;
    lofs[i0 + 3] = excl + c0 + c1 + c2;
    __syncthreads();
    int gbase = gbase_s;
    for (int i = tid; i < NPB; i += 256) {
        int node = base_node + i;
        if (node < N_NODES) {
            rowp[node] = gbase + lofs[i];
            dinv[node] = rsqrtf((float)(lcnt[i] + 1));
        }
    }
    if (b == NBKT - 1 && tid == 0) rowp[N_NODES] = N_EDGES;
    __syncthreads();
    // pass 2: scatter into private contiguous csr region (L2-local)
    for (int i = tid; i < cnt; i += 256) {
        int2 p = bp[i];
        int pos = atomicAdd(&lofs[p.y - base_node], 1);
        csr[gbase + pos] = p.x;
    }
}

// ---------------- weight swizzle + param folding ----------------

__global__ __launch_bounds__(128) void k_swz(
    const float* __restrict__ W1, const float* __restrict__ W2,
    const float* __restrict__ W3, const float* __restrict__ fW1,
    const float* __restrict__ fW2,
    const float* __restrict__ b1, const float* __restrict__ g1,
    const float* __restrict__ be1, const float* __restrict__ m1,
    const float* __restrict__ v1,
    const float* __restrict__ b2, const float* __restrict__ g2,
    const float* __restrict__ be2, const float* __restrict__ m2,
    const float* __restrict__ v2,
    const float* __restrict__ b3, const float* __restrict__ g3,
    const float* __restrict__ be3, const float* __restrict__ m3,
    const float* __restrict__ v3,
    const float* __restrict__ fb1, const float* __restrict__ fg1,
    const float* __restrict__ fbe1, const float* __restrict__ fm1,
    const float* __restrict__ fv1,
    const float* __restrict__ fb2, const float* __restrict__ fg2,
    const float* __restrict__ fbe2, const float* __restrict__ fm2,
    const float* __restrict__ fv2,
    h8* __restrict__ wsw, float* __restrict__ bfold, float* __restrict__ aggp) {
    int mat = blockIdx.x >> 3, tile = blockIdx.x & 7;
    int tid = threadIdx.x;

    if (mat == 5) {
        const float *bb, *gg, *be, *mm, *vv;
        if (tile == 0) { bb = b1; gg = g1; be = be1; mm = m1; vv = v1; }
        else if (tile == 1) { bb = b2; gg = g2; be = be2; mm = m2; vv = v2; }
        else { bb = b3; gg = g3; be = be3; mm = m3; vv = v3; }
        int c = tid;
        float b = 0.f, s = 0.f, t = 0.f;
        if (c < HID) {
            b = bb[c];
            s = gg[c] * rsqrtf(vv[c] + BN_EPS);
            t = be[c] - mm[c] * s;
        }
        aggp[tile * 384 + c] = b;
        aggp[tile * 384 + 128 + c] = s;
        aggp[tile * 384 + 256 + c] = t;
        return;
    }

    const float* W; int K;
    const float *bb = nullptr, *gg = nullptr, *be = nullptr, *mm = nullptr, *vv = nullptr;
    switch (mat) {
        case 0: W = W1; K = F_IN; break;
        case 1: W = W2; K = HID; break;
        case 2: W = W3; K = HID; break;
        case 3: W = fW1; K = HID; bb = fb1; gg = fg1; be = fbe1; mm = fm1; vv = fv1; break;
        default: W = fW2; K = HID; bb = fb2; gg = fg2; be = fbe2; mm = fm2; vv = fv2; break;
    }
    if (tid < 64) {
        int m16 = tid & 15, q = tid >> 4;
        int n = tile * 16 + m16;
        float sn = 1.f;
        if (mat >= 3 && n < HID) sn = gg[n] * rsqrtf(vv[n] + BN_EPS);
        for (int kc = 0; kc < 4; ++kc) {
            h8 b;
#pragma unroll
            for (int j = 0; j < 8; ++j) {
                int k = kc * 32 + q * 8 + j;
                float v = (k < K && n < HID) ? W[k * HID + n] * sn : 0.f;
                b[j] = (_Float16)v;
            }
            wsw[((size_t)mat * 8 + tile) * 256 + kc * 64 + tid] = b;
        }
    }
    if (mat >= 3 && tile == 0) {
        int c = tid;
        float v = 0.f;
        if (c < HID) {
            float s = gg[c] * rsqrtf(vv[c] + BN_EPS);
            float t = be[c] - mm[c] * s;
            v = bb[c] * s + t;
        }
        bfold[(mat - 3) * 128 + c] = v;
    }
}

// ---------------- MFMA GEMM (GCN layers): out = (A @ W) * dinv[row] ----------------

template <int KC, int ASTR>
__global__ __launch_bounds__(256) void k_gemm(
    const _Float16* __restrict__ A, const h8* __restrict__ Bsw,
    const float* __restrict__ dinv, _Float16* __restrict__ out) {
    __shared__ _Float16 As[128 * LSTR];
    const int tid = threadIdx.x;
    const int w = tid >> 6, l = tid & 63;
    const int m16 = l & 15, q = l >> 4;
    const int rowbase = blockIdx.x * 128;

    h8 Bf[2][KC];
#pragma unroll
    for (int ti = 0; ti < 2; ++ti)
#pragma unroll
        for (int kc = 0; kc < KC; ++kc)
            Bf[ti][kc] = Bsw[((w + ti * 4) * 4 + kc) * 64 + l];

    constexpr int NCH = ASTR / 8;
    for (int i = tid; i < 128 * NCH; i += 256) {
        int r = i / NCH, c = i - r * NCH;
        *(h8*)&As[r * LSTR + c * 8] = nt_load16(&A[(size_t)(rowbase + r) * ASTR + c * 8]);
    }
    {
        constexpr int ZCH = (KC * 32 - ASTR) / 8;      // 2 in both configs
        h8 z;
#pragma unroll
        for (int j = 0; j < 8; ++j) z[j] = (_Float16)0.f;
        for (int i = tid; i < 128 * ZCH; i += 256) {
            int r = i / ZCH, c = NCH + (i - r * ZCH);
            *(h8*)&As[r * LSTR + c * 8] = z;
        }
    }
    __syncthreads();

    f4 acc[8][2];
#pragma unroll
    for (int mt = 0; mt < 8; ++mt) {
        acc[mt][0] = (f4){0.f, 0.f, 0.f, 0.f};
        acc[mt][1] = (f4){0.f, 0.f, 0.f, 0.f};
    }

#pragma unroll
    for (int kc = 0; kc < KC; ++kc) {
#pragma unroll
        for (int mt = 0; mt < 8; ++mt) {
            h8 a = *(const h8*)&As[(mt * 16 + m16) * LSTR + kc * 32 + q * 8];
            acc[mt][0] = __builtin_amdgcn_mfma_f32_16x16x32_f16(a, Bf[0][kc], acc[mt][0], 0, 0, 0);
            if (w != 3)
                acc[mt][1] = __builtin_amdgcn_mfma_f32_16x16x32_f16(a, Bf[1][kc], acc[mt][1], 0, 0, 0);
        }
    }

    const int col0 = w * 16 + m16;
    const int col1 = col0 + 64;
#pragma unroll
    for (int mt = 0; mt < 8; ++mt) {
#pragma unroll
        for (int r = 0; r < 4; ++r) {
            int row = rowbase + mt * 16 + q * 4 + r;
            int dr = row < N_NODES ? row : N_NODES - 1;
            float dv = dinv[dr];
            _Float16 v0 = (_Float16)(acc[mt][0][r] * dv);
            __builtin_nontemporal_store(*(short*)&v0, (short*)&out[(size_t)row * SP + col0]);
            if (col1 < SP) {
                _Float16 v1 = (_Float16)(acc[mt][1][r] * dv);
                __builtin_nontemporal_store(*(short*)&v1, (short*)&out[(size_t)row * SP + col1]);
            }
        }
    }
}

// ---------------- aggregation: quarter-wave (14 active lanes x h8) per node --------

__global__ __launch_bounds__(256) void k_agg(
    const _Float16* __restrict__ hs, const int* __restrict__ rowp,
    const int* __restrict__ csr, const float* __restrict__ dinv,
    const float* __restrict__ prm, _Float16* __restrict__ out) {
    int l = threadIdx.x;
    int q = l >> 4, sub = l & 15;
    if (sub >= 14) return;                              // cols 0..111 only
    int n = blockIdx.x * 16 + threadIdx.y * 4 + q;
    int co = sub * 8;
    int beg = rowp[n], end = rowp[n + 1];

    float acc[8];
    {
        h8 v = *(const h8*)&hs[(size_t)n * SP + co];
#pragma unroll
        for (int j = 0; j < 8; ++j) acc[j] = (float)v[j];
    }

    int e = beg;
    for (; e + 3 < end; e += 4) {
        int s0 = __builtin_nontemporal_load(&csr[e]);
        int s1 = __builtin_nontemporal_load(&csr[e + 1]);
        int s2 = __builtin_nontemporal_load(&csr[e + 2]);
        int s3 = __builtin_nontemporal_load(&csr[e + 3]);
        h8 v0 = *(const h8*)&hs[(size_t)s0 * SP + co];
        h8 v1 = *(const h8*)&hs[(size_t)s1 * SP + co];
        h8 v2 = *(const h8*)&hs[(size_t)s2 * SP + co];
        h8 v3 = *(const h8*)&hs[(size_t)s3 * SP + co];
#pragma unroll
        for (int j = 0; j < 8; ++j)
            acc[j] += ((float)v0[j] + (float)v1[j]) + ((float)v2[j] + (float)v3[j]);
    }
    for (; e < end; ++e) {
        int s = csr[e];
        h8 v = *(const h8*)&hs[(size_t)s * SP + co];
#pragma unroll
        for (int j = 0; j < 8; ++j) acc[j] += (float)v[j];
    }

    float dv = dinv[n];
    f4 bl0 = *(const f4*)&prm[co],       bl1 = *(const f4*)&prm[co + 4];
    f4 sl0 = *(const f4*)&prm[128 + co], sl1 = *(const f4*)&prm[128 + co + 4];
    f4 tl0 = *(const f4*)&prm[256 + co], tl1 = *(const f4*)&prm[256 + co + 4];
    h8 o;
    o[0] = (_Float16)(fmaxf(acc[0] * dv + bl0[0], 0.f) * sl0[0] + tl0[0]);
    o[1] = (_Float16)(fmaxf(acc[1] * dv + bl0[1], 0.f) * sl0[1] + tl0[1]);
    o[2] = (_Float16)(fmaxf(acc[2] * dv + bl0[2], 0.f) * sl0[2] + tl0[2]);
    o[3] = (_Float16)(fmaxf(acc[3] * dv + bl0[3], 0.f) * sl0[3] + tl0[3]);
    o[4] = (_Float16)(fmaxf(acc[4] * dv + bl1[0], 0.f) * sl1[0] + tl1[0]);
    o[5] = (_Float16)(fmaxf(acc[5] * dv + bl1[1], 0.f) * sl1[1] + tl1[1]);
    o[6] = (_Float16)(fmaxf(acc[6] * dv + bl1[2], 0.f) * sl1[2] + tl1[2]);
    o[7] = (_Float16)(fmaxf(acc[7] * dv + bl1[3], 0.f) * sl1[3] + tl1[3]);
    nt_store16(&out[(size_t)n * SP + co], o);
}

// ---------------- fused dense head ----------------

__global__ __launch_bounds__(256) void k_head(
    const _Float16* __restrict__ A, const h8* __restrict__ Bsw3,
    const h8* __restrict__ Bsw4, const float* __restrict__ bfold1,
    const float* __restrict__ bfold2, const float* __restrict__ fW3,
    const float* __restrict__ fb3, float* __restrict__ out) {
    __shared__ _Float16 sh[128 * LSTR];
    __shared__ float part[128 * 3];
    const int tid = threadIdx.x;
    const int w = tid >> 6, l = tid & 63;
    const int m16 = l & 15, q = l >> 4;
    const int rowbase = blockIdx.x * 128;
    const int col0 = w * 16 + m16, col1 = col0 + 64;

    h8 Bf[2][4];
    f4 acc[8][2];

    // stage A (stride SP), zero cols 112..127
    for (int i = tid; i < 128 * 14; i += 256) {
        int r = i / 14, c = i - r * 14;
        *(h8*)&sh[r * LSTR + c * 8] = nt_load16(&A[(size_t)(rowbase + r) * SP + c * 8]);
    }
    {
        h8 z;
#pragma unroll
        for (int j = 0; j < 8; ++j) z[j] = (_Float16)0.f;
        for (int i = tid; i < 128 * 2; i += 256) {
            int r = i >> 1, c = 14 + (i & 1);
            *(h8*)&sh[r * LSTR + c * 8] = z;
        }
    }
    __syncthreads();

    // ---- GEMM1 ----
#pragma unroll
    for (int ti = 0; ti < 2; ++ti)
#pragma unroll
        for (int kc = 0; kc < 4; ++kc)
            Bf[ti][kc] = Bsw3[((w + ti * 4) * 4 + kc) * 64 + l];
#pragma unroll
    for (int mt = 0; mt < 8; ++mt) {
        acc[mt][0] = (f4){0.f, 0.f, 0.f, 0.f};
        acc[mt][1] = (f4){0.f, 0.f, 0.f, 0.f};
    }
#pragma unroll
    for (int kc = 0; kc < 4; ++kc) {
#pragma unroll
        for (int mt = 0; mt < 8; ++mt) {
            h8 a = *(const h8*)&sh[(mt * 16 + m16) * LSTR + kc * 32 + q * 8];
            acc[mt][0] = __builtin_amdgcn_mfma_f32_16x16x32_f16(a, Bf[0][kc], acc[mt][0], 0, 0, 0);
            if (w != 3)
                acc[mt][1] = __builtin_amdgcn_mfma_f32_16x16x32_f16(a, Bf[1][kc], acc[mt][1], 0, 0, 0);
        }
    }
    __syncthreads();
    {
        float bf0 = bfold1[col0], bf1 = bfold1[col1];
#pragma unroll
        for (int mt = 0; mt < 8; ++mt)
#pragma unroll
            for (int r = 0; r < 4; ++r) {
                int rl = mt * 16 + q * 4 + r;
                sh[rl * LSTR + col0] = (_Float16)fmaxf(acc[mt][0][r] + bf0, 0.f);
                sh[rl * LSTR + col1] = (_Float16)fmaxf(acc[mt][1][r] + bf1, 0.f);
            }
    }
    __syncthreads();

    // ---- GEMM2 ----
#pragma unroll
    for (int ti = 0; ti < 2; ++ti)
#pragma unroll
        for (int kc = 0; kc < 4; ++kc)
            Bf[ti][kc] = Bsw4[((w + ti * 4) * 4 + kc) * 64 + l];
#pragma unroll
    for (int mt = 0; mt < 8; ++mt) {
        acc[mt][0] = (f4){0.f, 0.f, 0.f, 0.f};
        acc[mt][1] = (f4){0.f, 0.f, 0.f, 0.f};
    }
#pragma unroll
    for (int kc = 0; kc < 4; ++kc) {
#pragma unroll
        for (int mt = 0; mt < 8; ++mt) {
            h8 a = *(const h8*)&sh[(mt * 16 + m16) * LSTR + kc * 32 + q * 8];
            acc[mt][0] = __builtin_amdgcn_mfma_f32_16x16x32_f16(a, Bf[0][kc], acc[mt][0], 0, 0, 0);
            if (w != 3)
                acc[mt][1] = __builtin_amdgcn_mfma_f32_16x16x32_f16(a, Bf[1][kc], acc[mt][1], 0, 0, 0);
        }
    }
    __syncthreads();
    {
        float bf0 = bfold2[col0], bf1 = bfold2[col1];
#pragma unroll
        for (int mt = 0; mt < 8; ++mt)
#pragma unroll
            for (int r = 0; r < 4; ++r) {
                int rl = mt * 16 + q * 4 + r;
                sh[rl * LSTR + col0] = (_Float16)fmaxf(acc[mt][0][r] + bf0, 0.f);
                sh[rl * LSTR + col1] = (_Float16)fmaxf(acc[mt][1][r] + bf1, 0.f);
            }
    }
    __syncthreads();

    // ---- 100 -> 3 ----
    {
        int half = tid >> 7;
        int row = tid & 127;
        int cbase = half * 64;
        float p0 = 0.f, p1 = 0.f, p2 = 0.f;
#pragma unroll
        for (int j = 0; j < 8; ++j) {
            h8 v = *(const h8*)&sh[row * LSTR + cbase + j * 8];
#pragma unroll
            for (int jj = 0; jj < 8; ++jj) {
                int c = cbase + j * 8 + jj;
                if (c < HID) {
                    float a = (float)v[jj];
                    p0 = fmaf(a, fW3[c * 3 + 0], p0);
                    p1 = fmaf(a, fW3[c * 3 + 1], p1);
                    p2 = fmaf(a, fW3[c * 3 + 2], p2);
                }
            }
        }
        if (half == 1) {
            part[row * 3 + 0] = p0; part[row * 3 + 1] = p1; part[row * 3 + 2] = p2;
        }
        __syncthreads();
        if (half == 0) {
            int grow = rowbase + row;
            if (grow < N_NODES) {
                __builtin_nontemporal_store(fmaxf(p0 + part[row * 3 + 0] + fb3[0], 0.f), &out[grow * 3 + 0]);
                __builtin_nontemporal_store(fmaxf(p1 + part[row * 3 + 1] + fb3[1], 0.f), &out[grow * 3 + 1]);
                __builtin_nontemporal_store(fmaxf(p2 + part[row * 3 + 2] + fb3[2], 0.f), &out[grow * 3 + 2]);
            }
        }
    }
}

// ---------------- launcher ----------------

extern "C" void kernel_launch(void* const* d_in, const int* in_sizes, int n_in,
                              void* d_out, int out_size, void* d_ws, size_t ws_size,
                              hipStream_t stream) {
    const float* x  = (const float*)d_in[0];
    const int*   ei = (const int*)d_in[1];
    const float* W1 = (const float*)d_in[2];  const float* b1 = (const float*)d_in[3];
    const float* g1 = (const float*)d_in[4];  const float* be1 = (const float*)d_in[5];
    const float* m1 = (const float*)d_in[6];  const float* v1 = (const float*)d_in[7];
    const float* W2 = (const float*)d_in[8];  const float* b2 = (const float*)d_in[9];
    const float* g2 = (const float*)d_in[10]; const float* be2 = (const float*)d_in[11];
    const float* m2 = (const float*)d_in[12]; const float* v2 = (const float*)d_in[13];
    const float* W3 = (const float*)d_in[14]; const float* b3 = (const float*)d_in[15];
    const float* g3 = (const float*)d_in[16]; const float* be3 = (const float*)d_in[17];
    const float* m3 = (const float*)d_in[18]; const float* v3 = (const float*)d_in[19];
    const float* fW1 = (const float*)d_in[20]; const float* fb1 = (const float*)d_in[21];
    const float* fg1 = (const float*)d_in[22]; const float* fbe1 = (const float*)d_in[23];
    const float* fm1 = (const float*)d_in[24]; const float* fv1 = (const float*)d_in[25];
    const float* fW2 = (const float*)d_in[26]; const float* fb2 = (const float*)d_in[27];
    const float* fg2 = (const float*)d_in[28]; const float* fbe2 = (const float*)d_in[29];
    const float* fm2 = (const float*)d_in[30]; const float* fv2 = (const float*)d_in[31];
    const float* fW3 = (const float*)d_in[32]; const float* fb3 = (const float*)d_in[33];
    float* out = (float*)d_out;

    char* w = (char*)d_ws;
    const size_t BUFS = (size_t)NROWS * SP * 2;         // 22,421,504 B
    _Float16* bufA = (_Float16*)(w);
    _Float16* bufB = (_Float16*)(w + BUFS);
    _Float16* xh   = (_Float16*)(w + 2 * BUFS);         // 16,015,360
    h8*    wsw   = (h8*)   (w + 60858368);              // 163,840
    float* bfold = (float*)(w + 61022208);              // 1,024
    float* aggp  = (float*)(w + 61023232);              // 4,608
    int*   bcur  = (int*)  (w + 61027840);              // 512
    int*   rowp  = (int*)  (w + 61028352);              // 400,128
    float* dinv  = (float*)(w + 61428480);              // 400,000
    int*   csr   = (int*)  (w + 61828480);              // 3,200,000
    int2*  bkt   = (int2*) (w + 65028480);              // 8,388,608 (end ~73.4 MB)

    (void)hipMemsetAsync(bcur, 0, NBKT * sizeof(int), stream);
    k_cvt<<<NROWS * 10 / 256, 256, 0, stream>>>(x, xh);
    k_bin<<<(N_EDGES + 2047) / 2048, 256, 0, stream>>>(ei, bcur, bkt);
    k_local<<<NBKT, 256, 0, stream>>>(bcur, bkt, rowp, dinv, csr);
    k_swz<<<43, 128, 0, stream>>>(W1, W2, W3, fW1, fW2,
                                  b1, g1, be1, m1, v1,
                                  b2, g2, be2, m2, v2,
                                  b3, g3, be3, m3, v3,
                                  fb1, fg1, fbe1, fm1, fv1,
                                  fb2, fg2, fbe2, fm2, fv2, wsw, bfold, aggp);

    const int ggrid = NROWS / 128;                      // 782
    dim3 ablk(64, 4);
    const int agrid = N_NODES / 16;                     // 6250

    k_gemm<3, XSTR><<<ggrid, 256, 0, stream>>>(xh,   wsw + 0 * 2048, dinv, bufA);
    k_agg<<<agrid, ablk, 0, stream>>>(bufA, rowp, csr, dinv, aggp + 0 * 384, bufB);
    k_gemm<4, SP  ><<<ggrid, 256, 0, stream>>>(bufB, wsw + 1 * 2048, dinv, bufA);
    k_agg<<<agrid, ablk, 0, stream>>>(bufA, rowp, csr, dinv, aggp + 1 * 384, bufB);
    k_gemm<4, SP  ><<<ggrid, 256, 0, stream>>>(bufB, wsw + 2 * 2048, dinv, bufA);
    k_agg<<<agrid, ablk, 0, stream>>>(bufA, rowp, csr, dinv, aggp + 2 * 384, bufB);
    k_head<<<ggrid, 256, 0, stream>>>(bufB, wsw + 3 * 2048, wsw + 4 * 2048,
                                      bfold, bfold + 128, fW3, fb3, out);
}

// Round 11
// 399.634 us; speedup vs baseline: 2.1653x; 1.0257x over previous
//
#include <hip/hip_runtime.h>

#define N_NODES 100000
#define N_EDGES 800000
#define F_IN    75
#define HID     100
#define SP      112            // padded fp16 row stride (halves) for intermediates
#define XSTR    80             // fp16 row stride for converted input / aggregated x
#define NROWS   100096         // rows padded to multiple of 128
#define BN_EPS  1e-5f
#define LSTR    136            // LDS row stride (halves)
#define NBKT    128            // dst-range buckets
#define NPB     782            // nodes per bucket
#define BIN_CAP 8192           // per-bucket global capacity
#define SBCAP   64             // per-bucket LDS staging capacity in k_bin

typedef _Float16 h8 __attribute__((ext_vector_type(8)));
typedef float    f4 __attribute__((ext_vector_type(4)));

// ------------- binning: edges -> 128 dst-range buckets (coalesced appends) -----------

__global__ __launch_bounds__(256) void k_bin(const int* __restrict__ ei,
                                             int* __restrict__ bcur,
                                             int2* __restrict__ bkt) {
    __shared__ int2 sb[NBKT * SBCAP];               // 64 KB
    __shared__ int scur[NBKT], sbase[NBKT], spre[NBKT];
    int tid = threadIdx.x;
    for (int i = tid; i < NBKT; i += 256) scur[i] = 0;
    __syncthreads();
    int base = blockIdx.x * 2048;
#pragma unroll
    for (int j = 0; j < 8; ++j) {
        int e = base + j * 256 + tid;
        if (e < N_EDGES) {
            int s = __builtin_nontemporal_load(&ei[e]);
            int d = __builtin_nontemporal_load(&ei[N_EDGES + e]);
            int b = d / NPB;
            int p = atomicAdd(&scur[b], 1);
            if (p < SBCAP) sb[b * SBCAP + p] = make_int2(s, d);
            else {
                int gp = atomicAdd(&bcur[b], 1);
                bkt[(size_t)b * BIN_CAP + gp] = make_int2(s, d);
            }
        }
    }
    __syncthreads();
    if (tid < NBKT) {
        int c = scur[tid]; if (c > SBCAP) c = SBCAP;
        scur[tid] = c;
        sbase[tid] = atomicAdd(&bcur[tid], c);
    }
    __syncthreads();
    if (tid < NBKT) {
        int lane = tid & 63;
        int x = scur[tid];
#pragma unroll
        for (int off = 1; off < 64; off <<= 1) {
            int y = __shfl_up(x, off);
            if (lane >= off) x += y;
        }
        spre[tid] = x;
    }
    __syncthreads();
    if (tid >= 64 && tid < NBKT) spre[tid] += spre[63];
    __syncthreads();
    int total = spre[NBKT - 1];
    for (int t = tid; t < total; t += 256) {
        int lo = 0, hi = NBKT - 1;
        while (lo < hi) { int mid = (lo + hi) >> 1; if (spre[mid] > t) hi = mid; else lo = mid + 1; }
        int bb = lo;
        int local = t - (spre[bb] - scur[bb]);
        bkt[(size_t)bb * BIN_CAP + sbase[bb] + local] = sb[bb * SBCAP + local];
    }
}

// ------------- per-bucket: LDS count + scan + rowp/dinv + csr scatter ---------------

__global__ __launch_bounds__(256) void k_local(const int* __restrict__ bcur,
                                               const int2* __restrict__ bkt,
                                               int* __restrict__ rowp,
                                               float* __restrict__ dinv,
                                               int* __restrict__ csr) {
    __shared__ int lcnt[1024];
    __shared__ int lofs[1024];
    __shared__ int sbc[NBKT];
    __shared__ int swt[4];
    __shared__ int gbase_s;
    int b = blockIdx.x, tid = threadIdx.x;
    for (int i = tid; i < 1024; i += 256) lcnt[i] = 0;
    if (tid < NBKT) sbc[tid] = bcur[tid];
    __syncthreads();
    if (tid == 0) { int s = 0; for (int j = 0; j < b; ++j) s += sbc[j]; gbase_s = s; }
    int cnt = sbc[b];
    const int2* bp = bkt + (size_t)b * BIN_CAP;
    int base_node = b * NPB;
    for (int i = tid; i < cnt; i += 256)
        atomicAdd(&lcnt[bp[i].y - base_node], 1);
    __syncthreads();
    int i0 = tid * 4;
    int c0 = lcnt[i0], c1 = lcnt[i0 + 1], c2 = lcnt[i0 + 2], c3 = lcnt[i0 + 3];
    int s = c0 + c1 + c2 + c3;
    int lane = tid & 63, wid = tid >> 6;
    int x = s;
#pragma unroll
    for (int off = 1; off < 64; off <<= 1) {
        int y = __shfl_up(x, off);
        if (lane >= off) x += y;
    }
    if (lane == 63) swt[wid] = x;
    __syncthreads();
    int woff = 0;
    for (int wv = 0; wv < wid; ++wv) woff += swt[wv];
    int excl = woff + x - s;
    lofs[i0] = excl;
    lofs[i0 + 1] = excl + c0;
    lofs[i0 + 2] = excl + c0 + c1;
    lofs[i0 + 3] = excl + c0 + c1 + c2;
    __syncthreads();
    int gbase = gbase_s;
    for (int i = tid; i < NPB; i += 256) {
        int node = base_node + i;
        if (node < N_NODES) {
            rowp[node] = gbase + lofs[i];
            dinv[node] = rsqrtf((float)(lcnt[i] + 1));
        }
    }
    if (b == NBKT - 1 && tid == 0) rowp[N_NODES] = N_EDGES;
    __syncthreads();
    for (int i = tid; i < cnt; i += 256) {
        int2 p = bp[i];
        int pos = atomicAdd(&lofs[p.y - base_node], 1);
        csr[gbase + pos] = p.x;
    }
}

// -------- x -> fp16 * dinv[row] (stride 80, zero pad cols 75..79, rows >= N) --------

__global__ __launch_bounds__(256) void k_cvt(const float* __restrict__ x,
                                             const float* __restrict__ dinv,
                                             _Float16* __restrict__ xh) {
    int id = blockIdx.x * 256 + threadIdx.x;        // NROWS*10 chunks
    int r = id / 10, c0 = (id - r * 10) * 8;
    h8 o;
#pragma unroll
    for (int j = 0; j < 8; ++j) o[j] = (_Float16)0.f;
    if (r < N_NODES) {
        float dv = dinv[r];
        const float* xr = x + (size_t)r * F_IN;
#pragma unroll
        for (int j = 0; j < 8; ++j) {
            int c = c0 + j;
            if (c < F_IN) o[j] = (_Float16)(__builtin_nontemporal_load(&xr[c]) * dv);
        }
    }
    *(h8*)&xh[(size_t)r * XSTR + c0] = o;
}

// ---------------- weight swizzle + param folding ----------------
// mats 0,1,2 (GCN): plain swizzle (BN applied after relu, cannot fold into W).
// mats 3,4 (head): BN scale folded into W; bfold[0|128] = b*s + t.
// aggp[layer][3][128]: GCN (b, s, t) for layers 1,2,3 (slot 0,1,2).

__global__ __launch_bounds__(128) void k_swz(
    const float* __restrict__ W1, const float* __restrict__ W2,
    const float* __restrict__ W3, const float* __restrict__ fW1,
    const float* __restrict__ fW2,
    const float* __restrict__ b1, const float* __restrict__ g1,
    const float* __restrict__ be1, const float* __restrict__ m1,
    const float* __restrict__ v1,
    const float* __restrict__ b2, const float* __restrict__ g2,
    const float* __restrict__ be2, const float* __restrict__ m2,
    const float* __restrict__ v2,
    const float* __restrict__ b3, const float* __restrict__ g3,
    const float* __restrict__ be3, const float* __restrict__ m3,
    const float* __restrict__ v3,
    const float* __restrict__ fb1, const float* __restrict__ fg1,
    const float* __restrict__ fbe1, const float* __restrict__ fm1,
    const float* __restrict__ fv1,
    const float* __restrict__ fb2, const float* __restrict__ fg2,
    const float* __restrict__ fbe2, const float* __restrict__ fm2,
    const float* __restrict__ fv2,
    h8* __restrict__ wsw, float* __restrict__ bfold, float* __restrict__ aggp) {
    int mat = blockIdx.x >> 3, tile = blockIdx.x & 7;
    int tid = threadIdx.x;

    if (mat == 5) {                       // agg params: tile 0,1,2 -> GCN layers 1,2,3
        if (tile > 2) return;
        const float *bb, *gg, *be, *mm, *vv;
        if (tile == 0) { bb = b1; gg = g1; be = be1; mm = m1; vv = v1; }
        else if (tile == 1) { bb = b2; gg = g2; be = be2; mm = m2; vv = v2; }
        else { bb = b3; gg = g3; be = be3; mm = m3; vv = v3; }
        int c = tid;
        float b = 0.f, s = 0.f, t = 0.f;
        if (c < HID) {
            b = bb[c];
            s = gg[c] * rsqrtf(vv[c] + BN_EPS);
            t = be[c] - mm[c] * s;
        }
        aggp[tile * 384 + c] = b;
        aggp[tile * 384 + 128 + c] = s;
        aggp[tile * 384 + 256 + c] = t;
        return;
    }

    const float* W; int K;
    const float *bb = nullptr, *gg = nullptr, *be = nullptr, *mm = nullptr, *vv = nullptr;
    bool fold = false;
    switch (mat) {
        case 0: W = W1; K = F_IN; break;
        case 1: W = W2; K = HID; break;
        case 2: W = W3; K = HID; break;
        case 3: W = fW1; K = HID; fold = true; bb = fb1; gg = fg1; be = fbe1; mm = fm1; vv = fv1; break;
        default: W = fW2; K = HID; fold = true; bb = fb2; gg = fg2; be = fbe2; mm = fm2; vv = fv2; break;
    }
    if (tid < 64) {
        int m16 = tid & 15, q = tid >> 4;
        int n = tile * 16 + m16;
        float sn = 1.f;
        if (fold && n < HID) sn = gg[n] * rsqrtf(vv[n] + BN_EPS);
        for (int kc = 0; kc < 4; ++kc) {
            h8 b;
#pragma unroll
            for (int j = 0; j < 8; ++j) {
                int k = kc * 32 + q * 8 + j;
                float v = (k < K && n < HID) ? W[k * HID + n] * sn : 0.f;
                b[j] = (_Float16)v;
            }
            wsw[((size_t)mat * 8 + tile) * 256 + kc * 64 + tid] = b;
        }
    }
    if (fold && tile == 0) {
        int c = tid;
        float v = 0.f;
        if (c < HID) {
            float s = gg[c] * rsqrtf(vv[c] + BN_EPS);
            float t = be[c] - mm[c] * s;
            v = bb[c] * s + t;
        }
        bfold[(mat - 3) * 128 + c] = v;
    }
}

// ---------------- MFMA GEMM ----------------
// MODE 0: out = acc * dinv[row]
// MODE 1: out = relu(acc + prm[col])                      (head: BN folded in W)
// MODE 2: out = relu(acc + prm[col]) * prm[128+col] + prm[256+col]   (GCN layer 1)
// Epilogue: acc -> LDS (fp16) -> coalesced h8 stores.

template <int KC, int ASTR, int MODE, int OSTR>
__global__ __launch_bounds__(256) void k_gemm(
    const _Float16* __restrict__ A, const h8* __restrict__ Bsw,
    const float* __restrict__ dinv, const float* __restrict__ prm,
    _Float16* __restrict__ out) {
    __shared__ _Float16 As[128 * LSTR];
    const int tid = threadIdx.x;
    const int w = tid >> 6, l = tid & 63;
    const int m16 = l & 15, q = l >> 4;
    const int rowbase = blockIdx.x * 128;

    h8 Bf[2][KC];
#pragma unroll
    for (int ti = 0; ti < 2; ++ti)
#pragma unroll
        for (int kc = 0; kc < KC; ++kc)
            Bf[ti][kc] = Bsw[((w + ti * 4) * 4 + kc) * 64 + l];

    constexpr int NCH = ASTR / 8;
    for (int i = tid; i < 128 * NCH; i += 256) {
        int r = i / NCH, c = i - r * NCH;
        *(h8*)&As[r * LSTR + c * 8] = *(const h8*)&A[(size_t)(rowbase + r) * ASTR + c * 8];
    }
    {
        constexpr int ZCH = (KC * 32 - ASTR) / 8;      // 2 in both configs
        h8 z;
#pragma unroll
        for (int j = 0; j < 8; ++j) z[j] = (_Float16)0.f;
        for (int i = tid; i < 128 * ZCH; i += 256) {
            int r = i / ZCH, c = NCH + (i - r * ZCH);
            *(h8*)&As[r * LSTR + c * 8] = z;
        }
    }
    __syncthreads();

    f4 acc[8][2];
#pragma unroll
    for (int mt = 0; mt < 8; ++mt) {
        acc[mt][0] = (f4){0.f, 0.f, 0.f, 0.f};
        acc[mt][1] = (f4){0.f, 0.f, 0.f, 0.f};
    }

#pragma unroll
    for (int kc = 0; kc < KC; ++kc) {
#pragma unroll
        for (int mt = 0; mt < 8; ++mt) {
            h8 a = *(const h8*)&As[(mt * 16 + m16) * LSTR + kc * 32 + q * 8];
            acc[mt][0] = __builtin_amdgcn_mfma_f32_16x16x32_f16(a, Bf[0][kc], acc[mt][0], 0, 0, 0);
            if (w != 3)
                acc[mt][1] = __builtin_amdgcn_mfma_f32_16x16x32_f16(a, Bf[1][kc], acc[mt][1], 0, 0, 0);
        }
    }
    __syncthreads();                                   // all MFMA LDS reads done

    const int col0 = w * 16 + m16;
    const int col1 = col0 + 64;
    if (MODE == 1) {
        float bf0 = prm[col0], bf1 = prm[col1];
#pragma unroll
        for (int mt = 0; mt < 8; ++mt)
#pragma unroll
            for (int r = 0; r < 4; ++r) {
                int rl = mt * 16 + q * 4 + r;
                As[rl * LSTR + col0] = (_Float16)fmaxf(acc[mt][0][r] + bf0, 0.f);
                As[rl * LSTR + col1] = (_Float16)fmaxf(acc[mt][1][r] + bf1, 0.f);
            }
    } else if (MODE == 2) {
        float b0 = prm[col0],       b1 = prm[col1];
        float s0 = prm[128 + col0], s1 = prm[128 + col1];
        float t0 = prm[256 + col0], t1 = prm[256 + col1];
#pragma unroll
        for (int mt = 0; mt < 8; ++mt)
#pragma unroll
            for (int r = 0; r < 4; ++r) {
                int rl = mt * 16 + q * 4 + r;
                As[rl * LSTR + col0] = (_Float16)(fmaxf(acc[mt][0][r] + b0, 0.f) * s0 + t0);
                As[rl * LSTR + col1] = (_Float16)(fmaxf(acc[mt][1][r] + b1, 0.f) * s1 + t1);
            }
    } else {
#pragma unroll
        for (int mt = 0; mt < 8; ++mt)
#pragma unroll
            for (int r = 0; r < 4; ++r) {
                int rl = mt * 16 + q * 4 + r;
                int row = rowbase + rl;
                int dr = row < N_NODES ? row : N_NODES - 1;
                float dv = dinv[dr];
                As[rl * LSTR + col0] = (_Float16)(acc[mt][0][r] * dv);
                As[rl * LSTR + col1] = (_Float16)(acc[mt][1][r] * dv);
            }
    }
    __syncthreads();

    constexpr int OCH = OSTR / 8;                      // 14
    for (int i = tid; i < 128 * OCH; i += 256) {
        int r = i / OCH, c = i - r * OCH;
        *(h8*)&out[(size_t)(rowbase + r) * OSTR + c * 8] = *(const h8*)&As[r * LSTR + c * 8];
    }
}

// ------------- layer-1 aggregate on x (80 cols): ax = agg(xh)*dinv[n] ---------------

__global__ __launch_bounds__(256) void k_aggx(
    const _Float16* __restrict__ xh, const int* __restrict__ rowp,
    const int* __restrict__ csr, const float* __restrict__ dinv,
    _Float16* __restrict__ ax) {
    int l = threadIdx.x;
    int q = l >> 4, sub = l & 15;
    if (sub >= 10) return;                              // 80 cols
    int n = blockIdx.x * 16 + threadIdx.y * 4 + q;
    int co = sub * 8;
    int beg = rowp[n], end = rowp[n + 1];

    float acc[8];
    {
        h8 v = *(const h8*)&xh[(size_t)n * XSTR + co];  // self (already * dinv[n])
#pragma unroll
        for (int j = 0; j < 8; ++j) acc[j] = (float)v[j];
    }
    int e = beg;
    for (; e + 7 < end; e += 8) {
        int s0 = csr[e],     s1 = csr[e + 1], s2 = csr[e + 2], s3 = csr[e + 3];
        int s4 = csr[e + 4], s5 = csr[e + 5], s6 = csr[e + 6], s7 = csr[e + 7];
        h8 v0 = *(const h8*)&xh[(size_t)s0 * XSTR + co];
        h8 v1 = *(const h8*)&xh[(size_t)s1 * XSTR + co];
        h8 v2 = *(const h8*)&xh[(size_t)s2 * XSTR + co];
        h8 v3 = *(const h8*)&xh[(size_t)s3 * XSTR + co];
        h8 v4 = *(const h8*)&xh[(size_t)s4 * XSTR + co];
        h8 v5 = *(const h8*)&xh[(size_t)s5 * XSTR + co];
        h8 v6 = *(const h8*)&xh[(size_t)s6 * XSTR + co];
        h8 v7 = *(const h8*)&xh[(size_t)s7 * XSTR + co];
#pragma unroll
        for (int j = 0; j < 8; ++j)
            acc[j] += (((float)v0[j] + (float)v1[j]) + ((float)v2[j] + (float)v3[j]))
                    + (((float)v4[j] + (float)v5[j]) + ((float)v6[j] + (float)v7[j]));
    }
    for (; e + 3 < end; e += 4) {
        int s0 = csr[e], s1 = csr[e + 1], s2 = csr[e + 2], s3 = csr[e + 3];
        h8 v0 = *(const h8*)&xh[(size_t)s0 * XSTR + co];
        h8 v1 = *(const h8*)&xh[(size_t)s1 * XSTR + co];
        h8 v2 = *(const h8*)&xh[(size_t)s2 * XSTR + co];
        h8 v3 = *(const h8*)&xh[(size_t)s3 * XSTR + co];
#pragma unroll
        for (int j = 0; j < 8; ++j)
            acc[j] += ((float)v0[j] + (float)v1[j]) + ((float)v2[j] + (float)v3[j]);
    }
    for (; e < end; ++e) {
        int s = csr[e];
        h8 v = *(const h8*)&xh[(size_t)s * XSTR + co];
#pragma unroll
        for (int j = 0; j < 8; ++j) acc[j] += (float)v[j];
    }
    float dv = dinv[n];
    h8 o;
#pragma unroll
    for (int j = 0; j < 8; ++j) o[j] = (_Float16)(acc[j] * dv);
    *(h8*)&ax[(size_t)n * XSTR + co] = o;
}

// ---------------- aggregation (112 cols) + bias + relu + BN ----------------

__global__ __launch_bounds__(256) void k_agg(
    const _Float16* __restrict__ hs, const int* __restrict__ rowp,
    const int* __restrict__ csr, const float* __restrict__ dinv,
    const float* __restrict__ prm, _Float16* __restrict__ out) {
    int l = threadIdx.x;
    int q = l >> 4, sub = l & 15;
    if (sub >= 14) return;                              // cols 0..111
    int n = blockIdx.x * 16 + threadIdx.y * 4 + q;
    int co = sub * 8;
    int beg = rowp[n], end = rowp[n + 1];

    float acc[8];
    {
        h8 v = *(const h8*)&hs[(size_t)n * SP + co];
#pragma unroll
        for (int j = 0; j < 8; ++j) acc[j] = (float)v[j];
    }
    int e = beg;
    for (; e + 7 < end; e += 8) {
        int s0 = csr[e],     s1 = csr[e + 1], s2 = csr[e + 2], s3 = csr[e + 3];
        int s4 = csr[e + 4], s5 = csr[e + 5], s6 = csr[e + 6], s7 = csr[e + 7];
        h8 v0 = *(const h8*)&hs[(size_t)s0 * SP + co];
        h8 v1 = *(const h8*)&hs[(size_t)s1 * SP + co];
        h8 v2 = *(const h8*)&hs[(size_t)s2 * SP + co];
        h8 v3 = *(const h8*)&hs[(size_t)s3 * SP + co];
        h8 v4 = *(const h8*)&hs[(size_t)s4 * SP + co];
        h8 v5 = *(const h8*)&hs[(size_t)s5 * SP + co];
        h8 v6 = *(const h8*)&hs[(size_t)s6 * SP + co];
        h8 v7 = *(const h8*)&hs[(size_t)s7 * SP + co];
#pragma unroll
        for (int j = 0; j < 8; ++j)
            acc[j] += (((float)v0[j] + (float)v1[j]) + ((float)v2[j] + (float)v3[j]))
                    + (((float)v4[j] + (float)v5[j]) + ((float)v6[j] + (float)v7[j]));
    }
    for (; e + 3 < end; e += 4) {
        int s0 = csr[e], s1 = csr[e + 1], s2 = csr[e + 2], s3 = csr[e + 3];
        h8 v0 = *(const h8*)&hs[(size_t)s0 * SP + co];
        h8 v1 = *(const h8*)&hs[(size_t)s1 * SP + co];
        h8 v2 = *(const h8*)&hs[(size_t)s2 * SP + co];
        h8 v3 = *(const h8*)&hs[(size_t)s3 * SP + co];
#pragma unroll
        for (int j = 0; j < 8; ++j)
            acc[j] += ((float)v0[j] + (float)v1[j]) + ((float)v2[j] + (float)v3[j]);
    }
    for (; e < end; ++e) {
        int s = csr[e];
        h8 v = *(const h8*)&hs[(size_t)s * SP + co];
#pragma unroll
        for (int j = 0; j < 8; ++j) acc[j] += (float)v[j];
    }

    float dv = dinv[n];
    f4 bl0 = *(const f4*)&prm[co],       bl1 = *(const f4*)&prm[co + 4];
    f4 sl0 = *(const f4*)&prm[128 + co], sl1 = *(const f4*)&prm[128 + co + 4];
    f4 tl0 = *(const f4*)&prm[256 + co], tl1 = *(const f4*)&prm[256 + co + 4];
    h8 o;
    o[0] = (_Float16)(fmaxf(acc[0] * dv + bl0[0], 0.f) * sl0[0] + tl0[0]);
    o[1] = (_Float16)(fmaxf(acc[1] * dv + bl0[1], 0.f) * sl0[1] + tl0[1]);
    o[2] = (_Float16)(fmaxf(acc[2] * dv + bl0[2], 0.f) * sl0[2] + tl0[2]);
    o[3] = (_Float16)(fmaxf(acc[3] * dv + bl0[3], 0.f) * sl0[3] + tl0[3]);
    o[4] = (_Float16)(fmaxf(acc[4] * dv + bl1[0], 0.f) * sl1[0] + tl1[0]);
    o[5] = (_Float16)(fmaxf(acc[5] * dv + bl1[1], 0.f) * sl1[1] + tl1[1]);
    o[6] = (_Float16)(fmaxf(acc[6] * dv + bl1[2], 0.f) * sl1[2] + tl1[2]);
    o[7] = (_Float16)(fmaxf(acc[7] * dv + bl1[3], 0.f) * sl1[3] + tl1[3]);
    *(h8*)&out[(size_t)n * SP + co] = o;
}

// ---------------- fused dense head ----------------

__global__ __launch_bounds__(256) void k_head(
    const _Float16* __restrict__ A, const h8* __restrict__ Bsw3,
    const h8* __restrict__ Bsw4, const float* __restrict__ bfold1,
    const float* __restrict__ bfold2, const float* __restrict__ fW3,
    const float* __restrict__ fb3, float* __restrict__ out) {
    __shared__ _Float16 sh[128 * LSTR];
    __shared__ float part[128 * 3];
    const int tid = threadIdx.x;
    const int w = tid >> 6, l = tid & 63;
    const int m16 = l & 15, q = l >> 4;
    const int rowbase = blockIdx.x * 128;
    const int col0 = w * 16 + m16, col1 = col0 + 64;

    h8 Bf[2][4];
    f4 acc[8][2];

    for (int i = tid; i < 128 * 14; i += 256) {
        int r = i / 14, c = i - r * 14;
        *(h8*)&sh[r * LSTR + c * 8] = *(const h8*)&A[(size_t)(rowbase + r) * SP + c * 8];
    }
    {
        h8 z;
#pragma unroll
        for (int j = 0; j < 8; ++j) z[j] = (_Float16)0.f;
        for (int i = tid; i < 128 * 2; i += 256) {
            int r = i >> 1, c = 14 + (i & 1);
            *(h8*)&sh[r * LSTR + c * 8] = z;
        }
    }
    __syncthreads();

    // ---- GEMM1 ----
#pragma unroll
    for (int ti = 0; ti < 2; ++ti)
#pragma unroll
        for (int kc = 0; kc < 4; ++kc)
            Bf[ti][kc] = Bsw3[((w + ti * 4) * 4 + kc) * 64 + l];
#pragma unroll
    for (int mt = 0; mt < 8; ++mt) {
        acc[mt][0] = (f4){0.f, 0.f, 0.f, 0.f};
        acc[mt][1] = (f4){0.f, 0.f, 0.f, 0.f};
    }
#pragma unroll
    for (int kc = 0; kc < 4; ++kc) {
#pragma unroll
        for (int mt = 0; mt < 8; ++mt) {
            h8 a = *(const h8*)&sh[(mt * 16 + m16) * LSTR + kc * 32 + q * 8];
            acc[mt][0] = __builtin_amdgcn_mfma_f32_16x16x32_f16(a, Bf[0][kc], acc[mt][0], 0, 0, 0);
            if (w != 3)
                acc[mt][1] = __builtin_amdgcn_mfma_f32_16x16x32_f16(a, Bf[1][kc], acc[mt][1], 0, 0, 0);
        }
    }
    __syncthreads();
    {
        float bf0 = bfold1[col0], bf1 = bfold1[col1];
#pragma unroll
        for (int mt = 0; mt < 8; ++mt)
#pragma unroll
            for (int r = 0; r < 4; ++r) {
                int rl = mt * 16 + q * 4 + r;
                sh[rl * LSTR + col0] = (_Float16)fmaxf(acc[mt][0][r] + bf0, 0.f);
                sh[rl * LSTR + col1] = (_Float16)fmaxf(acc[mt][1][r] + bf1, 0.f);
            }
    }
    __syncthreads();

    // ---- GEMM2 ----
#pragma unroll
    for (int ti = 0; ti < 2; ++ti)
#pragma unroll
        for (int kc = 0; kc < 4; ++kc)
            Bf[ti][kc] = Bsw4[((w + ti * 4) * 4 + kc) * 64 + l];
#pragma unroll
    for (int mt = 0; mt < 8; ++mt) {
        acc[mt][0] = (f4){0.f, 0.f, 0.f, 0.f};
        acc[mt][1] = (f4){0.f, 0.f, 0.f, 0.f};
    }
#pragma unroll
    for (int kc = 0; kc < 4; ++kc) {
#pragma unroll
        for (int mt = 0; mt < 8; ++mt) {
            h8 a = *(const h8*)&sh[(mt * 16 + m16) * LSTR + kc * 32 + q * 8];
            acc[mt][0] = __builtin_amdgcn_mfma_f32_16x16x32_f16(a, Bf[0][kc], acc[mt][0], 0, 0, 0);
            if (w != 3)
                acc[mt][1] = __builtin_amdgcn_mfma_f32_16x16x32_f16(a, Bf[1][kc], acc[mt][1], 0, 0, 0);
        }
    }
    __syncthreads();
    {
        float bf0 = bfold2[col0], bf1 = bfold2[col1];
#pragma unroll
        for (int mt = 0; mt < 8; ++mt)
#pragma unroll
            for (int r = 0; r < 4; ++r) {
                int rl = mt * 16 + q * 4 + r;
                sh[rl * LSTR + col0] = (_Float16)fmaxf(acc[mt][0][r] + bf0, 0.f);
                sh[rl * LSTR + col1] = (_Float16)fmaxf(acc[mt][1][r] + bf1, 0.f);
            }
    }
    __syncthreads();

    // ---- 100 -> 3 ----
    {
        int half = tid >> 7;
        int row = tid & 127;
        int cbase = half * 64;
        float p0 = 0.f, p1 = 0.f, p2 = 0.f;
#pragma unroll
        for (int j = 0; j < 8; ++j) {
            h8 v = *(const h8*)&sh[row * LSTR + cbase + j * 8];
#pragma unroll
            for (int jj = 0; jj < 8; ++jj) {
                int c = cbase + j * 8 + jj;
                if (c < HID) {
                    float a = (float)v[jj];
                    p0 = fmaf(a, fW3[c * 3 + 0], p0);
                    p1 = fmaf(a, fW3[c * 3 + 1], p1);
                    p2 = fmaf(a, fW3[c * 3 + 2], p2);
                }
            }
        }
        if (half == 1) {
            part[row * 3 + 0] = p0; part[row * 3 + 1] = p1; part[row * 3 + 2] = p2;
        }
        __syncthreads();
        if (half == 0) {
            int grow = rowbase + row;
            if (grow < N_NODES) {
                __builtin_nontemporal_store(fmaxf(p0 + part[row * 3 + 0] + fb3[0], 0.f), &out[grow * 3 + 0]);
                __builtin_nontemporal_store(fmaxf(p1 + part[row * 3 + 1] + fb3[1], 0.f), &out[grow * 3 + 1]);
                __builtin_nontemporal_store(fmaxf(p2 + part[row * 3 + 2] + fb3[2], 0.f), &out[grow * 3 + 2]);
            }
        }
    }
}

// ---------------- launcher ----------------

extern "C" void kernel_launch(void* const* d_in, const int* in_sizes, int n_in,
                              void* d_out, int out_size, void* d_ws, size_t ws_size,
                              hipStream_t stream) {
    const float* x  = (const float*)d_in[0];
    const int*   ei = (const int*)d_in[1];
    const float* W1 = (const float*)d_in[2];  const float* b1 = (const float*)d_in[3];
    const float* g1 = (const float*)d_in[4];  const float* be1 = (const float*)d_in[5];
    const float* m1 = (const float*)d_in[6];  const float* v1 = (const float*)d_in[7];
    const float* W2 = (const float*)d_in[8];  const float* b2 = (const float*)d_in[9];
    const float* g2 = (const float*)d_in[10]; const float* be2 = (const float*)d_in[11];
    const float* m2 = (const float*)d_in[12]; const float* v2 = (const float*)d_in[13];
    const float* W3 = (const float*)d_in[14]; const float* b3 = (const float*)d_in[15];
    const float* g3 = (const float*)d_in[16]; const float* be3 = (const float*)d_in[17];
    const float* m3 = (const float*)d_in[18]; const float* v3 = (const float*)d_in[19];
    const float* fW1 = (const float*)d_in[20]; const float* fb1 = (const float*)d_in[21];
    const float* fg1 = (const float*)d_in[22]; const float* fbe1 = (const float*)d_in[23];
    const float* fm1 = (const float*)d_in[24]; const float* fv1 = (const float*)d_in[25];
    const float* fW2 = (const float*)d_in[26]; const float* fb2 = (const float*)d_in[27];
    const float* fg2 = (const float*)d_in[28]; const float* fbe2 = (const float*)d_in[29];
    const float* fm2 = (const float*)d_in[30]; const float* fv2 = (const float*)d_in[31];
    const float* fW3 = (const float*)d_in[32]; const float* fb3 = (const float*)d_in[33];
    float* out = (float*)d_out;

    char* w = (char*)d_ws;
    const size_t BUFS = (size_t)NROWS * SP * 2;         // 22,421,504 B
    _Float16* bufA = (_Float16*)(w);                    // also holds ax (stride 80)
    _Float16* bufB = (_Float16*)(w + BUFS);
    _Float16* xh   = (_Float16*)(w + 2 * BUFS);         // 16,015,360
    h8*    wsw   = (h8*)   (w + 60858368);              // 163,840
    float* bfold = (float*)(w + 61022208);              // 1,024
    float* aggp  = (float*)(w + 61023744);              // 4,608
    int*   bcur  = (int*)  (w + 61028352);              // 512
    int*   rowp  = (int*)  (w + 61028864);              // 400,128
    float* dinv  = (float*)(w + 61428992);              // 400,000
    int*   csr   = (int*)  (w + 61828992);              // 3,200,000
    int2*  bkt   = (int2*) (w + 65028992);              // 8,388,608 (end ~73.4 MB)

    (void)hipMemsetAsync(bcur, 0, NBKT * sizeof(int), stream);
    k_bin<<<(N_EDGES + 2047) / 2048, 256, 0, stream>>>(ei, bcur, bkt);
    k_local<<<NBKT, 256, 0, stream>>>(bcur, bkt, rowp, dinv, csr);
    k_cvt<<<NROWS * 10 / 256, 256, 0, stream>>>(x, dinv, xh);
    k_swz<<<48, 128, 0, stream>>>(W1, W2, W3, fW1, fW2,
                                  b1, g1, be1, m1, v1,
                                  b2, g2, be2, m2, v2,
                                  b3, g3, be3, m3, v3,
                                  fb1, fg1, fbe1, fm1, fv1,
                                  fb2, fg2, fbe2, fm2, fv2, wsw, bfold, aggp);

    const int ggrid = NROWS / 128;                      // 782
    dim3 ablk(64, 4);
    const int agrid = N_NODES / 16;                     // 6250

    // layer 1 reordered: ax = agg_norm(x), then h1 = BN1(relu(ax@W1 + b1))  (MODE 2)
    k_aggx<<<agrid, ablk, 0, stream>>>(xh, rowp, csr, dinv, bufA);
    k_gemm<3, XSTR, 2, SP><<<ggrid, 256, 0, stream>>>(bufA, wsw + 0 * 2048, nullptr, aggp + 0 * 384, bufB);
    // layer 2
    k_gemm<4, SP, 0, SP><<<ggrid, 256, 0, stream>>>(bufB, wsw + 1 * 2048, dinv, nullptr, bufA);
    k_agg<<<agrid, ablk, 0, stream>>>(bufA, rowp, csr, dinv, aggp + 1 * 384, bufB);
    // layer 3
    k_gemm<4, SP, 0, SP><<<ggrid, 256, 0, stream>>>(bufB, wsw + 2 * 2048, dinv, nullptr, bufA);
    k_agg<<<agrid, ablk, 0, stream>>>(bufA, rowp, csr, dinv, aggp + 2 * 384, bufB);
    // dense head
    k_head<<<ggrid, 256, 0, stream>>>(bufB, wsw + 3 * 2048, wsw + 4 * 2048,
                                      bfold, bfold + 128, fW3, fb3, out);
}